// Round 17
// baseline (325.718 us; speedup 1.0000x reference)
//
#include <hip/hip_runtime.h>
#include <math.h>

#define B_ 2
#define T_ 2048
#define D_ 1024
#define H_ 16
#define HS_ 64
#define BT_ (B_*T_)
#define EPS_ 1e-5f
#define SCALE_ 0.03125f  // D^-0.5 = 1/32
#define C2_ (0.03125f * 1.44269504088896f)   // SCALE * log2(e)

typedef __attribute__((ext_vector_type(4))) float f32x4;
typedef __attribute__((ext_vector_type(8))) __bf16 bf16x8;

__device__ __forceinline__ short f2bf(float f) {
    union { float f; unsigned u; } cv; cv.f = f;
    unsigned u = cv.u;
    return (short)((u + 0x7fffu + ((u >> 16) & 1u)) >> 16);  // RTNE
}

// ---------------- LayerNorm: one block per row; fp32 + bf16 outputs --------
__global__ __launch_bounds__(256) void ln_kernel(const float* __restrict__ x,
        const float* __restrict__ g, const float* __restrict__ b,
        float* __restrict__ out, short* __restrict__ outb) {
    int row = blockIdx.x;
    int tid = threadIdx.x;
    const float* xr = x + (size_t)row * D_;
    float4 v = *(const float4*)(xr + tid * 4);
    __shared__ float red[256];
    red[tid] = v.x + v.y + v.z + v.w;
    __syncthreads();
    for (int st = 128; st > 0; st >>= 1) {
        if (tid < st) red[tid] += red[tid + st];
        __syncthreads();
    }
    float mean = red[0] * (1.0f / D_);
    __syncthreads();
    float dx = v.x - mean, dy = v.y - mean, dz = v.z - mean, dw = v.w - mean;
    red[tid] = dx*dx + dy*dy + dz*dz + dw*dw;
    __syncthreads();
    for (int st = 128; st > 0; st >>= 1) {
        if (tid < st) red[tid] += red[tid + st];
        __syncthreads();
    }
    float rstd = rsqrtf(red[0] * (1.0f / D_) + EPS_);
    float4 gv = *(const float4*)(g + tid * 4);
    float4 bv = *(const float4*)(b + tid * 4);
    float4 o;
    o.x = dx * rstd * gv.x + bv.x;
    o.y = dy * rstd * gv.y + bv.y;
    o.z = dz * rstd * gv.z + bv.z;
    o.w = dw * rstd * gv.w + bv.w;
    *(float4*)(out + (size_t)row * D_ + tid * 4) = o;
    short4 ob = make_short4(f2bf(o.x), f2bf(o.y), f2bf(o.z), f2bf(o.w));
    *(short4*)(outb + (size_t)row * D_ + tid * 4) = ob;
}

// ---------------- fp32 [R][C] -> bf16 [C][R] transpose+convert (batched) ---
__global__ __launch_bounds__(256) void transpose_cvt(const float* __restrict__ in,
        short* __restrict__ out, int R, int C) {
    __shared__ float t[32][33];
    int c0 = blockIdx.x * 32, r0 = blockIdx.y * 32;
    const float* inb = in + (size_t)blockIdx.z * R * C;
    short* outb = out + (size_t)blockIdx.z * R * C;
    int tx = threadIdx.x & 31, ty = threadIdx.x >> 5;   // 32 x 8
    #pragma unroll
    for (int i = 0; i < 32; i += 8)
        t[ty + i][tx] = inb[(size_t)(r0 + ty + i) * C + c0 + tx];
    __syncthreads();
    #pragma unroll
    for (int i = 0; i < 32; i += 8)
        outb[(size_t)(c0 + ty + i) * R + r0 + tx] = f2bf(t[tx][ty + i]);
}

// ---------------- bf16 MFMA GEMM 128x64 (QKV) ------------------------------
__global__ __launch_bounds__(256) void gemm_qkv(
        const short* __restrict__ A, const short* __restrict__ Bt,
        short* __restrict__ qo, short* __restrict__ ko, short* __restrict__ vo,
        int M, int N, int K) {
    __shared__ char As[2][16384];   // [128 rows][128B], XOR-swizzled
    __shared__ char Bs[2][8192];    // [64 rows][128B]
    int tid = threadIdx.x, lane = tid & 63, w = tid >> 6;

    int orig = blockIdx.y * gridDim.x + blockIdx.x;
    int cpx = (gridDim.x * gridDim.y) >> 3;
    int wgid = (orig & 7) * cpx + (orig >> 3);
    int m0 = (wgid / gridDim.x) * 128;
    int n0 = (wgid % gridDim.x) * 64;

    const size_t Kb = (size_t)K * 2;
    int rowA[4], cbA[4], rowB[2], cbB[2];
    #pragma unroll
    for (int i = 0; i < 4; ++i) {
        int o = (w * 4 + i) * 1024 + lane * 16;
        rowA[i] = o >> 7;
        cbA[i] = (o & 127) ^ ((rowA[i] & 7) << 4);
    }
    #pragma unroll
    for (int i = 0; i < 2; ++i) {
        int o = (w * 2 + i) * 1024 + lane * 16;
        rowB[i] = o >> 7;
        cbB[i] = (o & 127) ^ ((rowB[i] & 7) << 4);
    }

    #define STAGE_Q(buf, kt) do {                                              \
        _Pragma("unroll")                                                      \
        for (int i_ = 0; i_ < 4; ++i_) {                                       \
            const char* ga_ = (const char*)A + (size_t)(m0 + rowA[i_]) * Kb    \
                              + (size_t)(kt) * 2 + cbA[i_];                    \
            __builtin_amdgcn_global_load_lds(                                  \
                (const __attribute__((address_space(1))) void*)ga_,            \
                (__attribute__((address_space(3))) void*)(As[buf] + (w * 4 + i_) * 1024),\
                16, 0, 0);                                                     \
        }                                                                      \
        _Pragma("unroll")                                                      \
        for (int i_ = 0; i_ < 2; ++i_) {                                       \
            const char* gb_ = (const char*)Bt + (size_t)(n0 + rowB[i_]) * Kb   \
                              + (size_t)(kt) * 2 + cbB[i_];                    \
            __builtin_amdgcn_global_load_lds(                                  \
                (const __attribute__((address_space(1))) void*)gb_,            \
                (__attribute__((address_space(3))) void*)(Bs[buf] + (w * 2 + i_) * 1024),\
                16, 0, 0);                                                     \
        }                                                                      \
    } while (0)

    f32x4 acc[2][4] = {};
    int nt = K >> 6;
    STAGE_Q(0, 0);
    for (int t = 0; t < nt; ++t) {
        int cur = t & 1;
        if (t + 1 < nt) {
            STAGE_Q(cur ^ 1, (t + 1) * 64);
            asm volatile("s_waitcnt vmcnt(6)" ::: "memory");
        } else {
            asm volatile("s_waitcnt vmcnt(0)" ::: "memory");
        }
        __builtin_amdgcn_s_barrier();
        __builtin_amdgcn_s_setprio(1);
        #pragma unroll
        for (int kk = 0; kk < 2; ++kk) {
            int kbyte = kk * 64 + (lane >> 4) * 16;
            bf16x8 bf[4], af[2];
            #pragma unroll
            for (int ni = 0; ni < 4; ++ni) {
                int row = ni * 16 + (lane & 15);
                bf[ni] = *(const bf16x8*)(Bs[cur] + row * 128 + (kbyte ^ ((row & 7) << 4)));
            }
            #pragma unroll
            for (int mi = 0; mi < 2; ++mi) {
                int row = w * 32 + mi * 16 + (lane & 15);
                af[mi] = *(const bf16x8*)(As[cur] + row * 128 + (kbyte ^ ((row & 7) << 4)));
            }
            #pragma unroll
            for (int mi = 0; mi < 2; ++mi)
                #pragma unroll
                for (int ni = 0; ni < 4; ++ni)
                    acc[mi][ni] = __builtin_amdgcn_mfma_f32_16x16x32_bf16(
                        af[mi], bf[ni], acc[mi][ni], 0, 0, 0);
        }
        __builtin_amdgcn_s_setprio(0);
        __builtin_amdgcn_s_barrier();
    }
    #undef STAGE_Q

    int sel = n0 >> 10, hh = (n0 & 1023) >> 6;
    #pragma unroll
    for (int mi = 0; mi < 2; ++mi) {
        #pragma unroll
        for (int j = 0; j < 4; ++j) {
            int row = m0 + w * 32 + mi * 16 + (lane >> 4) * 4 + j;
            int bb = row >> 11, tt = row & 2047;
            #pragma unroll
            for (int ni = 0; ni < 4; ++ni) {
                int e = ni * 16 + (lane & 15);
                short bv = f2bf(acc[mi][ni][j]);
                if (sel == 0)
                    qo[(((size_t)(bb * H_ + hh)) * T_ + tt) * HS_ + e] = bv;
                else if (sel == 1)
                    ko[(((size_t)(bb * H_ + hh)) * T_ + tt) * HS_ + e] = bv;
                else  // V stored TRANSPOSED: [bh][e][T]
                    vo[(((size_t)(bb * H_ + hh)) * HS_ + e) * T_ + tt] = bv;
            }
        }
    }
}

// ---------------- bf16 MFMA GEMM 128x128, SPLIT-K (FFN2) -------------------
__global__ __launch_bounds__(256) void gemm128_sk(
        const short* __restrict__ A, const short* __restrict__ Bt,
        float* __restrict__ P, int M, int N, int Ksl, int Ktot) {
    __shared__ char As[2][16384];
    __shared__ char Bs[2][16384];
    int tid = threadIdx.x;
    int lane = tid & 63, w = tid >> 6;
    int wr = w >> 1, wc = w & 1;

    int orig = blockIdx.y * gridDim.x + blockIdx.x;
    int cpx = (gridDim.x * gridDim.y) >> 3;
    int wgid = (orig & 7) * cpx + (orig >> 3);
    int m0 = (wgid / gridDim.x) * 128;
    int n0 = (wgid % gridDim.x) * 128;
    int k0 = blockIdx.z * Ksl;
    float* Pz = P + (size_t)blockIdx.z * M * N;

    f32x4 acc[4][4] = {};

    int rowS[4], kbS[4];
    #pragma unroll
    for (int i = 0; i < 4; ++i) {
        int o = (w * 4 + i) * 1024 + lane * 16;
        rowS[i] = o >> 7;
        kbS[i] = (o & 127) ^ ((rowS[i] & 7) << 4);
    }
    const size_t Kb = (size_t)Ktot * 2;

    #define STAGE_K(buf, kt) do {                                              \
        _Pragma("unroll")                                                      \
        for (int i_ = 0; i_ < 4; ++i_) {                                       \
            int c_ = w * 4 + i_;                                               \
            const char* ga_ = (const char*)A + (size_t)(m0 + rowS[i_]) * Kb    \
                              + (size_t)(k0 + (kt)) * 2 + kbS[i_];             \
            __builtin_amdgcn_global_load_lds(                                  \
                (const __attribute__((address_space(1))) void*)ga_,            \
                (__attribute__((address_space(3))) void*)(As[buf] + c_ * 1024),\
                16, 0, 0);                                                     \
            const char* gb_ = (const char*)Bt + (size_t)(n0 + rowS[i_]) * Kb   \
                              + (size_t)(k0 + (kt)) * 2 + kbS[i_];             \
            __builtin_amdgcn_global_load_lds(                                  \
                (const __attribute__((address_space(1))) void*)gb_,            \
                (__attribute__((address_space(3))) void*)(Bs[buf] + c_ * 1024),\
                16, 0, 0);                                                     \
        }                                                                      \
    } while (0)

    int nt = Ksl >> 6;
    STAGE_K(0, 0);
    for (int t = 0; t < nt; ++t) {
        int cur = t & 1;
        if (t + 1 < nt) {
            STAGE_K(cur ^ 1, (t + 1) * 64);
            asm volatile("s_waitcnt vmcnt(8)" ::: "memory");
        } else {
            asm volatile("s_waitcnt vmcnt(0)" ::: "memory");
        }
        __builtin_amdgcn_s_barrier();
        __builtin_amdgcn_s_setprio(1);
        #pragma unroll
        for (int kk = 0; kk < 2; ++kk) {
            int kbyte = kk * 64 + (lane >> 4) * 16;
            bf16x8 af[4], bf[4];
            #pragma unroll
            for (int mi = 0; mi < 4; ++mi) {
                int row = wr * 64 + mi * 16 + (lane & 15);
                af[mi] = *(const bf16x8*)(As[cur] + row * 128 + (kbyte ^ ((row & 7) << 4)));
            }
            #pragma unroll
            for (int ni = 0; ni < 4; ++ni) {
                int row = wc * 64 + ni * 16 + (lane & 15);
                bf[ni] = *(const bf16x8*)(Bs[cur] + row * 128 + (kbyte ^ ((row & 7) << 4)));
            }
            #pragma unroll
            for (int mi = 0; mi < 4; ++mi)
                #pragma unroll
                for (int ni = 0; ni < 4; ++ni)
                    acc[mi][ni] = __builtin_amdgcn_mfma_f32_16x16x32_bf16(
                        af[mi], bf[ni], acc[mi][ni], 0, 0, 0);
        }
        __builtin_amdgcn_s_setprio(0);
        __builtin_amdgcn_s_barrier();
    }
    #undef STAGE_K

    #pragma unroll
    for (int mi = 0; mi < 4; ++mi) {
        #pragma unroll
        for (int j = 0; j < 4; ++j) {
            int row = m0 + wr * 64 + mi * 16 + (lane >> 4) * 4 + j;
            #pragma unroll
            for (int ni = 0; ni < 4; ++ni) {
                int col = n0 + wc * 64 + ni * 16 + (lane & 15);
                Pz[(size_t)row * N + col] = acc[mi][ni][j];
            }
        }
    }
}

// ---------------- split-K reduce: out = p0 + p1 + bias + res ---------------
__global__ __launch_bounds__(256) void addreduce(const float* __restrict__ p0,
        const float* __restrict__ p1, const float* __restrict__ bias,
        const float* __restrict__ res, float* __restrict__ out) {
    int i = blockIdx.x * 256 + threadIdx.x;   // float4 index; N=1024 cols
    float4 a = ((const float4*)p0)[i];
    float4 b = ((const float4*)p1)[i];
    float4 r = ((const float4*)res)[i];
    float4 bs = ((const float4*)bias)[i & 255];
    float4 o;
    o.x = a.x + b.x + r.x + bs.x;
    o.y = a.y + b.y + r.y + bs.y;
    o.z = a.z + b.z + r.z + bs.z;
    o.w = a.w + b.w + r.w + bs.w;
    ((float4*)out)[i] = o;
}

// ---------------- bf16 MFMA GEMM 128x64 (proj) -----------------------------
template<bool BIAS, bool RES, bool RELU, bool BF16OUT>
__global__ __launch_bounds__(256) void gemm_12864(
        const short* __restrict__ A, const short* __restrict__ Bt,
        const float* __restrict__ bias, const float* __restrict__ res,
        float* __restrict__ C, short* __restrict__ Cb,
        int M, int N, int K) {
    __shared__ char As[2][16384];   // [128 rows][128B], XOR-swizzled
    __shared__ char Bs[2][8192];    // [64 rows][128B]
    int tid = threadIdx.x, lane = tid & 63, w = tid >> 6;

    int orig = blockIdx.y * gridDim.x + blockIdx.x;
    int cpx = (gridDim.x * gridDim.y) >> 3;
    int wgid = (orig & 7) * cpx + (orig >> 3);
    int m0 = (wgid / gridDim.x) * 128;
    int n0 = (wgid % gridDim.x) * 64;

    const size_t Kb = (size_t)K * 2;
    int rowA[4], cbA[4], rowB[2], cbB[2];
    #pragma unroll
    for (int i = 0; i < 4; ++i) {
        int o = (w * 4 + i) * 1024 + lane * 16;
        rowA[i] = o >> 7;
        cbA[i] = (o & 127) ^ ((rowA[i] & 7) << 4);
    }
    #pragma unroll
    for (int i = 0; i < 2; ++i) {
        int o = (w * 2 + i) * 1024 + lane * 16;
        rowB[i] = o >> 7;
        cbB[i] = (o & 127) ^ ((rowB[i] & 7) << 4);
    }

    #define STAGE_S(buf, kt) do {                                              \
        _Pragma("unroll")                                                      \
        for (int i_ = 0; i_ < 4; ++i_) {                                       \
            const char* ga_ = (const char*)A + (size_t)(m0 + rowA[i_]) * Kb    \
                              + (size_t)(kt) * 2 + cbA[i_];                    \
            __builtin_amdgcn_global_load_lds(                                  \
                (const __attribute__((address_space(1))) void*)ga_,            \
                (__attribute__((address_space(3))) void*)(As[buf] + (w * 4 + i_) * 1024),\
                16, 0, 0);                                                     \
        }                                                                      \
        _Pragma("unroll")                                                      \
        for (int i_ = 0; i_ < 2; ++i_) {                                       \
            const char* gb_ = (const char*)Bt + (size_t)(n0 + rowB[i_]) * Kb   \
                              + (size_t)(kt) * 2 + cbB[i_];                    \
            __builtin_amdgcn_global_load_lds(                                  \
                (const __attribute__((address_space(1))) void*)gb_,            \
                (__attribute__((address_space(3))) void*)(Bs[buf] + (w * 2 + i_) * 1024),\
                16, 0, 0);                                                     \
        }                                                                      \
    } while (0)

    f32x4 acc[2][4] = {};
    int nt = K >> 6;
    STAGE_S(0, 0);
    for (int t = 0; t < nt; ++t) {
        int cur = t & 1;
        if (t + 1 < nt) {
            STAGE_S(cur ^ 1, (t + 1) * 64);
            asm volatile("s_waitcnt vmcnt(6)" ::: "memory");
        } else {
            asm volatile("s_waitcnt vmcnt(0)" ::: "memory");
        }
        __builtin_amdgcn_s_barrier();
        __builtin_amdgcn_s_setprio(1);
        #pragma unroll
        for (int kk = 0; kk < 2; ++kk) {
            int kbyte = kk * 64 + (lane >> 4) * 16;
            bf16x8 bf[4], af[2];
            #pragma unroll
            for (int ni = 0; ni < 4; ++ni) {
                int row = ni * 16 + (lane & 15);
                bf[ni] = *(const bf16x8*)(Bs[cur] + row * 128 + (kbyte ^ ((row & 7) << 4)));
            }
            #pragma unroll
            for (int mi = 0; mi < 2; ++mi) {
                int row = w * 32 + mi * 16 + (lane & 15);
                af[mi] = *(const bf16x8*)(As[cur] + row * 128 + (kbyte ^ ((row & 7) << 4)));
            }
            #pragma unroll
            for (int mi = 0; mi < 2; ++mi)
                #pragma unroll
                for (int ni = 0; ni < 4; ++ni)
                    acc[mi][ni] = __builtin_amdgcn_mfma_f32_16x16x32_bf16(
                        af[mi], bf[ni], acc[mi][ni], 0, 0, 0);
        }
        __builtin_amdgcn_s_setprio(0);
        __builtin_amdgcn_s_barrier();
    }
    #undef STAGE_S

    #pragma unroll
    for (int mi = 0; mi < 2; ++mi) {
        #pragma unroll
        for (int j = 0; j < 4; ++j) {
            int row = m0 + w * 32 + mi * 16 + (lane >> 4) * 4 + j;
            #pragma unroll
            for (int ni = 0; ni < 4; ++ni) {
                int col = n0 + ni * 16 + (lane & 15);
                float vv = acc[mi][ni][j];
                if (BIAS) vv += bias[col];
                if (RES)  vv += res[(size_t)row * N + col];
                if (RELU) vv = fmaxf(vv, 0.0f);
                if (BF16OUT) Cb[(size_t)row * N + col] = f2bf(vv);
                else         C[(size_t)row * N + col] = vv;
            }
        }
    }
}

// ============ 256x256 coarse-dbuf MFMA GEMM (FFN1) =========================
template<bool BIAS, bool RELU, bool BF16OUT>
__global__ __launch_bounds__(512, 2) void gemm256_2p(
        const short* __restrict__ A, const short* __restrict__ Bt,
        const float* __restrict__ bias,
        float* __restrict__ C, short* __restrict__ Cb,
        int M, int N, int K) {
    __shared__ char As[2][32768];   // [256 rows][128B], XOR-swizzled
    __shared__ char Bs[2][32768];
    int tid = threadIdx.x, lane = tid & 63, w = tid >> 6;
    int wr = w >> 2, wc = w & 3;

    int nwg = gridDim.x * gridDim.y;
    int orig = blockIdx.y * gridDim.x + blockIdx.x;
    int cpx = nwg >> 3;
    int wgid = (orig & 7) * cpx + (orig >> 3);
    int m0 = (wgid / gridDim.x) * 256;
    int n0 = (wgid % gridDim.x) * 256;

    const size_t Kb = (size_t)K * 2;
    int rowS[4], cbS[4];
    #pragma unroll
    for (int i = 0; i < 4; ++i) {
        int o = (i * 8 + w) * 1024 + lane * 16;
        rowS[i] = o >> 7;                               // 0..255
        cbS[i] = (o & 127) ^ ((rowS[i] & 7) << 4);
    }

    #define STAGE_256(buf, kt) do {                                           \
        _Pragma("unroll")                                                     \
        for (int i_ = 0; i_ < 4; ++i_) {                                      \
            int c_ = i_ * 8 + w;                                              \
            const char* ga_ = (const char*)A + (size_t)(m0 + rowS[i_]) * Kb   \
                              + (size_t)(kt) * 2 + cbS[i_];                   \
            __builtin_amdgcn_global_load_lds(                                 \
                (const __attribute__((address_space(1))) void*)ga_,           \
                (__attribute__((address_space(3))) void*)(As[buf] + c_ * 1024),\
                16, 0, 0);                                                    \
            const char* gb_ = (const char*)Bt + (size_t)(n0 + rowS[i_]) * Kb  \
                              + (size_t)(kt) * 2 + cbS[i_];                   \
            __builtin_amdgcn_global_load_lds(                                 \
                (const __attribute__((address_space(1))) void*)gb_,           \
                (__attribute__((address_space(3))) void*)(Bs[buf] + c_ * 1024),\
                16, 0, 0);                                                    \
        }                                                                     \
    } while (0)

    f32x4 acc[8][4] = {};
    int nt = K >> 6;
    STAGE_256(0, 0);
    for (int t = 0; t < nt; ++t) {
        int cur = t & 1;
        if (t + 1 < nt) {
            STAGE_256(cur ^ 1, (t + 1) * 64);
            asm volatile("s_waitcnt vmcnt(8)" ::: "memory");
        } else {
            asm volatile("s_waitcnt vmcnt(0)" ::: "memory");
        }
        __builtin_amdgcn_s_barrier();
        __builtin_amdgcn_s_setprio(1);
        #pragma unroll
        for (int kk = 0; kk < 2; ++kk) {
            int kbyte = kk * 64 + (lane >> 4) * 16;
            bf16x8 bfr[4];
            #pragma unroll
            for (int ni = 0; ni < 4; ++ni) {
                int row = wc * 64 + ni * 16 + (lane & 15);
                bfr[ni] = *(const bf16x8*)(Bs[cur] + row * 128 + (kbyte ^ ((row & 7) << 4)));
            }
            #pragma unroll
            for (int mi = 0; mi < 8; ++mi) {
                int row = wr * 128 + mi * 16 + (lane & 15);
                bf16x8 afr = *(const bf16x8*)(As[cur] + row * 128 + (kbyte ^ ((row & 7) << 4)));
                #pragma unroll
                for (int ni = 0; ni < 4; ++ni)
                    acc[mi][ni] = __builtin_amdgcn_mfma_f32_16x16x32_bf16(
                        afr, bfr[ni], acc[mi][ni], 0, 0, 0);
            }
        }
        __builtin_amdgcn_s_setprio(0);
        __builtin_amdgcn_s_barrier();
    }
    #undef STAGE_256

    #pragma unroll
    for (int mi = 0; mi < 8; ++mi) {
        #pragma unroll
        for (int j = 0; j < 4; ++j) {
            int row = m0 + wr * 128 + mi * 16 + (lane >> 4) * 4 + j;
            #pragma unroll
            for (int ni = 0; ni < 4; ++ni) {
                int col = n0 + wc * 64 + ni * 16 + (lane & 15);
                float vv = acc[mi][ni][j];
                if (BIAS) vv += bias[col];
                if (RELU) vv = fmaxf(vv, 0.0f);
                if (BF16OUT) Cb[(size_t)row * N + col] = f2bf(vv);
                else         C[(size_t)row * N + col] = vv;
            }
        }
    }
}

// ---------------- pass 1: per-key column sums (NO max tracking) ------------
__global__ __launch_bounds__(256) void attn_pass1_mfma(
        const short* __restrict__ qg, const short* __restrict__ kg,
        float* __restrict__ lpart) {
    int kt = blockIdx.x;      // 128-key tile, 0..15
    int chunk = blockIdx.y;   // 0..3
    int bh = blockIdx.z;
    int tid = threadIdx.x, lane = tid & 63, w = tid >> 6;
    __shared__ char Qs[8192];
    const size_t base = (size_t)bh * T_ * HS_;
    int kb0 = kt * 128;
    bf16x8 af[2][2];
    #pragma unroll
    for (int s2 = 0; s2 < 2; ++s2) {
        const short* kr = kg + base
            + (size_t)(kb0 + s2 * 64 + w * 16 + (lane & 15)) * HS_ + (lane >> 4) * 8;
        af[s2][0] = *(const bf16x8*)kr;
        af[s2][1] = *(const bf16x8*)(kr + 32);
    }
    int baseT = kt * 2;
    int R = 32 - baseT;
    int cnt = (R + 3) >> 2;
    int qs = baseT + chunk * cnt;
    int qe = qs + cnt; if (qe > 32) qe = 32;
    float psum[2][4] = {};
    for (int qt = qs; qt < qe; ++qt) {
        __syncthreads();
        #pragma unroll
        for (int it = 0; it < 2; ++it) {
            int o = it * 4096 + w * 1024 + lane * 16;
            int row = o >> 7;
            int col = (o & 127) ^ ((row & 7) << 4);
            const char* src = (const char*)(qg + base + (size_t)(qt * 64 + row) * HS_) + col;
            __builtin_amdgcn_global_load_lds(
                (const __attribute__((address_space(1))) void*)src,
                (__attribute__((address_space(3))) void*)(Qs + it * 4096 + w * 1024), 16, 0, 0);
        }
        __syncthreads();
        #pragma unroll
        for (int sub = 0; sub < 4; ++sub) {
            int qrow = sub * 16 + (lane & 15);
            bf16x8 bq[2];
            #pragma unroll
            for (int kk = 0; kk < 2; ++kk) {
                int off = (kk * 64 + (lane >> 4) * 16) ^ ((qrow & 7) << 4);
                bq[kk] = *(const bf16x8*)(Qs + qrow * 128 + off);
            }
            int qglob = qt * 64 + qrow;
            #pragma unroll
            for (int s2 = 0; s2 < 2; ++s2) {
                f32x4 c = {0.f, 0.f, 0.f, 0.f};
                c = __builtin_amdgcn_mfma_f32_16x16x32_bf16(af[s2][0], bq[0], c, 0, 0, 0);
                c = __builtin_amdgcn_mfma_f32_16x16x32_bf16(af[s2][1], bq[1], c, 0, 0, 0);
                #pragma unroll
                for (int j = 0; j < 4; ++j) {
                    int kglob = kb0 + s2 * 64 + w * 16 + (lane >> 4) * 4 + j;
                    float pe = exp2f(c[j] * C2_);
                    psum[s2][j] += (qglob >= kglob) ? pe : 0.0f;
                }
            }
        }
    }
    #pragma unroll
    for (int s2 = 0; s2 < 2; ++s2)
        #pragma unroll
        for (int j = 0; j < 4; ++j) {
            float v = psum[s2][j];
            v += __shfl_xor(v, 1); v += __shfl_xor(v, 2);
            v += __shfl_xor(v, 4); v += __shfl_xor(v, 8);
            psum[s2][j] = v;
        }
    if ((lane & 15) == 0) {
        #pragma unroll
        for (int s2 = 0; s2 < 2; ++s2)
            #pragma unroll
            for (int j = 0; j < 4; ++j)
                lpart[((size_t)chunk * 32 + bh) * T_
                      + kb0 + s2 * 64 + w * 16 + (lane >> 4) * 4 + j] = psum[s2][j];
    }
}

// ---------------- reduce partials -> NEGATIVE LOG2 of column sum -----------
__global__ __launch_bounds__(256) void lreduce(const float* __restrict__ lpart,
        float* __restrict__ rl) {
    int i = blockIdx.x * 256 + threadIdx.x;   // i < 32*2048
    const int S = 32 * T_;
    float s = lpart[i] + lpart[S + i] + lpart[2 * S + i] + lpart[3 * S + i];
    rl[i] = -log2f(s);
}

// ---------------- pass 2: O = sum_k exp2(t + lg_k) * V[k] ------------------
// Unpaired LPT: block x handles qtile = 31 - x (longest first), 4 waves,
// 64-key dbuf steps, 41.5KB LDS -> 3 blocks/CU. Grid (32, 32) = 1024 blocks.
__global__ __launch_bounds__(256) void attn_pass2_mfma(
        const short* __restrict__ qg, const short* __restrict__ kg,
        const short* __restrict__ vt, const float* __restrict__ rl,
        short* __restrict__ attnb) {
    int qtile = 31 - blockIdx.x, bh = blockIdx.y;
    int bb = bh >> 4, hh = bh & 15;
    int tid = threadIdx.x, lane = tid & 63, w = tid >> 6;   // 4 waves
    __shared__ char Kb[2][8192];    // [64 keys][128B], swizzled
    __shared__ char Vb[2][8192];    // [64 e][128B = 64 keys], swizzled
    __shared__ char Ps[8192];       // [64 q][128B], wave-private rows
    __shared__ float rlds[2][64];
    const size_t qkbase = (size_t)bh * T_ * HS_;
    const size_t vtbase = (size_t)bh * HS_ * T_;

    int q0 = qtile * 64 + w * 16;
    bf16x8 aq[2];
    {
        const short* qr = qg + qkbase + (size_t)(q0 + (lane & 15)) * HS_ + (lane >> 4) * 8;
        aq[0] = *(const bf16x8*)qr;
        aq[1] = *(const bf16x8*)(qr + 32);
    }
    f32x4 oacc[4] = {};
    int nstep = qtile + 1;   // 64-key steps

    #define STAGE64(bufi, stepi) do {                                         \
        int k0_ = (stepi) * 64;                                               \
        _Pragma("unroll")                                                     \
        for (int i_ = 0; i_ < 2; ++i_) {                                      \
            int c_ = w * 2 + i_;                                              \
            int o_ = c_ * 1024 + lane * 16;                                   \
            int row_ = o_ >> 7;                                               \
            int col_ = (o_ & 127) ^ ((row_ & 7) << 4);                        \
            const char* srcK_ = (const char*)(kg + qkbase                     \
                + (size_t)(k0_ + row_) * HS_) + col_;                         \
            __builtin_amdgcn_global_load_lds(                                 \
                (const __attribute__((address_space(1))) void*)srcK_,         \
                (__attribute__((address_space(3))) void*)(Kb[bufi] + c_ * 1024), \
                16, 0, 0);                                                    \
            const char* srcV_ = (const char*)(vt + vtbase                     \
                + (size_t)row_ * T_ + k0_) + col_;                            \
            __builtin_amdgcn_global_load_lds(                                 \
                (const __attribute__((address_space(1))) void*)srcV_,         \
                (__attribute__((address_space(3))) void*)(Vb[bufi] + c_ * 1024), \
                16, 0, 0);                                                    \
        }                                                                     \
        if (tid < 64) rlds[bufi][tid] = rl[(size_t)bh * T_ + k0_ + tid];      \
    } while (0)

    STAGE64(0, 0);
    __syncthreads();
    for (int st = 0; st < nstep; ++st) {
        int cur = st & 1;
        if (st + 1 < nstep) STAGE64(cur ^ 1, st + 1);
        int kbase = st * 64;
        bool diag = (st == qtile);
        int qgl = q0 + (lane & 15);
        int ql = w * 16 + (lane & 15);
        int swz = (ql & 7) << 4;
        #pragma unroll
        for (int sub = 0; sub < 4; ++sub) {
            int krow = sub * 16 + (lane & 15);
            f32x4 c = {0.f, 0.f, 0.f, 0.f};
            #pragma unroll
            for (int kk = 0; kk < 2; ++kk) {
                int off = (kk * 64 + (lane >> 4) * 16) ^ ((krow & 7) << 4);
                bf16x8 bk = *(const bf16x8*)(Kb[cur] + krow * 128 + off);
                // SWAPPED: A = K fragment, B = Q fragment -> c = S^T
                c = __builtin_amdgcn_mfma_f32_16x16x32_bf16(bk, aq[kk], c, 0, 0, 0);
            }
            int kloc0 = sub * 16 + (lane >> 4) * 4;
            f32x4 lg4 = *(const f32x4*)&rlds[cur][kloc0];
            float wv[4];
            #pragma unroll
            for (int j = 0; j < 4; ++j) {
                float t = exp2f(fmaf(c[j], C2_, lg4[j]));
                int keyg = kbase + kloc0 + j;
                wv[j] = (diag && qgl < keyg) ? 0.0f : t;
            }
            unsigned p01, p23;
            asm("v_cvt_pk_bf16_f32 %0, %1, %2" : "=v"(p01) : "v"(wv[0]), "v"(wv[1]));
            asm("v_cvt_pk_bf16_f32 %0, %1, %2" : "=v"(p23) : "v"(wv[2]), "v"(wv[3]));
            *(unsigned*)(Ps + ql * 128 + ((kloc0 * 2) ^ swz)) = p01;
            *(unsigned*)(Ps + ql * 128 + ((kloc0 * 2 + 4) ^ swz)) = p23;
        }
        bf16x8 ap[2];
        #pragma unroll
        for (int kk = 0; kk < 2; ++kk) {
            int off = (kk * 64 + (lane >> 4) * 16) ^ swz;
            ap[kk] = *(const bf16x8*)(Ps + ql * 128 + off);
        }
        #pragma unroll
        for (int es = 0; es < 4; ++es) {
            int erow = es * 16 + (lane & 15);
            #pragma unroll
            for (int kk = 0; kk < 2; ++kk) {
                int vcol = (kk * 64 + (lane >> 4) * 16) ^ ((erow & 7) << 4);
                bf16x8 bv = *(const bf16x8*)(Vb[cur] + erow * 128 + vcol);
                oacc[es] = __builtin_amdgcn_mfma_f32_16x16x32_bf16(
                    ap[kk], bv, oacc[es], 0, 0, 0);
            }
        }
        __syncthreads();
    }
    #undef STAGE64
    #pragma unroll
    for (int es = 0; es < 4; ++es) {
        #pragma unroll
        for (int j = 0; j < 4; ++j) {
            int qgl = q0 + (lane >> 4) * 4 + j;
            int e = es * 16 + (lane & 15);
            attnb[((size_t)(bb * T_ + qgl)) * D_ + hh * HS_ + e] = f2bf(oacc[es][j]);
        }
    }
}

extern "C" void kernel_launch(void* const* d_in, const int* in_sizes, int n_in,
                              void* d_out, int out_size, void* d_ws, size_t ws_size,
                              hipStream_t stream) {
    const float* x     = (const float*)d_in[0];
    const float* Wq    = (const float*)d_in[1];
    const float* Wk    = (const float*)d_in[2];
    const float* Wv    = (const float*)d_in[3];
    const float* Wproj = (const float*)d_in[4];
    const float* bproj = (const float*)d_in[5];
    const float* W1    = (const float*)d_in[6];
    const float* b1    = (const float*)d_in[7];
    const float* W2    = (const float*)d_in[8];
    const float* b2    = (const float*)d_in[9];
    const float* ln1g  = (const float*)d_in[10];
    const float* ln1b  = (const float*)d_in[11];
    const float* ln2g  = (const float*)d_in[12];
    const float* ln2b  = (const float*)d_in[13];
    float* out = (float*)d_out;

    const size_t MB = 1u << 20;
    char* ws = (char*)d_ws;
    float* xn    = (float*)(ws + 0 * MB);     // 16MB
    short* xnb   = (short*)(ws + 16 * MB);    // 8MB
    short* qbh   = (short*)(ws + 24 * MB);    // 8MB  [bh][T][HS] bf16
    short* kbh   = (short*)(ws + 32 * MB);    // 8MB  [bh][T][HS] bf16
    short* vtb   = (short*)(ws + 40 * MB);    // 8MB  [bh][HS][T] bf16 (transposed)
    short* attnb = (short*)(ws + 48 * MB);    // 8MB
    float* x1    = (float*)(ws + 56 * MB);    // 16MB
    float* x1n   = (float*)(ws + 72 * MB);    // 16MB
    short* x1nb  = (short*)(ws + 88 * MB);    // 8MB
    short* hb    = (short*)(ws + 96 * MB);    // 32MB
    short* wqkv  = (short*)(ws + 128 * MB);   // 6MB  [3072][1024]
    short* wprjt = (short*)(ws + 134 * MB);   // 2MB  [1024][1024]
    short* w1t   = (short*)(ws + 136 * MB);   // 8MB  [4096][1024]
    short* w2t   = (short*)(ws + 144 * MB);   // 8MB  [1024][4096]
    float* lpart = (float*)(ws + 152 * MB);   // 1MB  [4][32][2048]
    float* rl    = (float*)(ws + 153 * MB);   // 256KB [32][2048]
    // Split-K partials: CONTIGUOUS 32MB (xn + xnb/qbh regions, dead by FFN2)
    float* partP = (float*)(ws + 0 * MB);
    float* part0 = (float*)(ws + 0 * MB);
    float* part1 = (float*)(ws + 16 * MB);

    // 0. weight transpose+convert
    transpose_cvt<<<dim3(2, 32, 16), 256, 0, stream>>>(Wq, wqkv + (size_t)0 * 1048576, 1024, 64);
    transpose_cvt<<<dim3(2, 32, 16), 256, 0, stream>>>(Wk, wqkv + (size_t)1 * 1048576, 1024, 64);
    transpose_cvt<<<dim3(2, 32, 16), 256, 0, stream>>>(Wv, wqkv + (size_t)2 * 1048576, 1024, 64);
    transpose_cvt<<<dim3(32, 32, 1), 256, 0, stream>>>(Wproj, wprjt, 1024, 1024);
    transpose_cvt<<<dim3(128, 32, 1), 256, 0, stream>>>(W1, w1t, 1024, 4096);
    transpose_cvt<<<dim3(32, 128, 1), 256, 0, stream>>>(W2, w2t, 4096, 1024);

    // 1. LN1 -> xn (fp32) + xnb (bf16)
    ln_kernel<<<dim3(BT_), 256, 0, stream>>>(x, ln1g, ln1b, xn, xnb);
    // 2. QKV fused GEMM (128x64, 1536 blocks) -> q,k bf16; v bf16 transposed
    gemm_qkv<<<dim3(48, 32), 256, 0, stream>>>(
        xnb, wqkv, qbh, kbh, vtb, BT_, 3072, 1024);
    // 3. column sums (no max): partials then -log2
    attn_pass1_mfma<<<dim3(16, 4, 32), 256, 0, stream>>>(qbh, kbh, lpart);
    lreduce<<<dim3(32 * T_ / 256), 256, 0, stream>>>(lpart, rl);
    // 4. attention output (MFMA, unpaired LPT, 64-key dbuf steps)
    attn_pass2_mfma<<<dim3(32, 32), 256, 0, stream>>>(qbh, kbh, vtb, rl, attnb);
    // 5. proj + bias + residual(xn) -> x1  (128x64, 512 blocks)
    gemm_12864<true, true, false, false><<<dim3(16, 32), 256, 0, stream>>>(
        attnb, wprjt, bproj, xn, x1, nullptr, BT_, 1024, 1024);
    // 6. LN2 -> x1n + x1nb
    ln_kernel<<<dim3(BT_), 256, 0, stream>>>(x1, ln2g, ln2b, x1n, x1nb);
    // 7. FFN1: relu(x1n @ W1 + b1) -> hb (bf16)  (256x256 coarse-dbuf)
    gemm256_2p<true, true, true><<<dim3(16, 16), 512, 0, stream>>>(
        x1nb, w1t, b1, nullptr, hb, BT_, 4096, 1024);
    // 8. FFN2 split-K=2: contiguous partials at ws+0 / ws+16MB
    gemm128_sk<<<dim3(8, 32, 2), 256, 0, stream>>>(
        hb, w2t, partP, BT_, 1024, 2048, 4096);
    // 9. out = part0 + part1 + b2 + x1n
    addreduce<<<dim3(BT_ * D_ / 4 / 256), 256, 0, stream>>>(
        part0, part1, b2, x1n, out);
    (void)in_sizes; (void)n_in; (void)out_size; (void)ws_size;
}

// Round 18
// 295.294 us; speedup vs baseline: 1.1030x; 1.1030x over previous
//
#include <hip/hip_runtime.h>
#include <math.h>

#define B_ 2
#define T_ 2048
#define D_ 1024
#define H_ 16
#define HS_ 64
#define BT_ (B_*T_)
#define EPS_ 1e-5f
#define SCALE_ 0.03125f  // D^-0.5 = 1/32
#define C2_ (0.03125f * 1.44269504088896f)   // SCALE * log2(e)

typedef __attribute__((ext_vector_type(4))) float f32x4;
typedef __attribute__((ext_vector_type(8))) __bf16 bf16x8;

__device__ __forceinline__ short f2bf(float f) {
    union { float f; unsigned u; } cv; cv.f = f;
    unsigned u = cv.u;
    return (short)((u + 0x7fffu + ((u >> 16) & 1u)) >> 16);  // RTNE
}

// ---------------- LayerNorm: one block per row; fp32 + bf16 outputs --------
__global__ __launch_bounds__(256) void ln_kernel(const float* __restrict__ x,
        const float* __restrict__ g, const float* __restrict__ b,
        float* __restrict__ out, short* __restrict__ outb) {
    int row = blockIdx.x;
    int tid = threadIdx.x;
    const float* xr = x + (size_t)row * D_;
    float4 v = *(const float4*)(xr + tid * 4);
    __shared__ float red[256];
    red[tid] = v.x + v.y + v.z + v.w;
    __syncthreads();
    for (int st = 128; st > 0; st >>= 1) {
        if (tid < st) red[tid] += red[tid + st];
        __syncthreads();
    }
    float mean = red[0] * (1.0f / D_);
    __syncthreads();
    float dx = v.x - mean, dy = v.y - mean, dz = v.z - mean, dw = v.w - mean;
    red[tid] = dx*dx + dy*dy + dz*dz + dw*dw;
    __syncthreads();
    for (int st = 128; st > 0; st >>= 1) {
        if (tid < st) red[tid] += red[tid + st];
        __syncthreads();
    }
    float rstd = rsqrtf(red[0] * (1.0f / D_) + EPS_);
    float4 gv = *(const float4*)(g + tid * 4);
    float4 bv = *(const float4*)(b + tid * 4);
    float4 o;
    o.x = dx * rstd * gv.x + bv.x;
    o.y = dy * rstd * gv.y + bv.y;
    o.z = dz * rstd * gv.z + bv.z;
    o.w = dw * rstd * gv.w + bv.w;
    *(float4*)(out + (size_t)row * D_ + tid * 4) = o;
    short4 ob = make_short4(f2bf(o.x), f2bf(o.y), f2bf(o.z), f2bf(o.w));
    *(short4*)(outb + (size_t)row * D_ + tid * 4) = ob;
}

// ---------------- fp32 [R][C] -> bf16 [C][R] transpose+convert (batched) ---
__global__ __launch_bounds__(256) void transpose_cvt(const float* __restrict__ in,
        short* __restrict__ out, int R, int C) {
    __shared__ float t[32][33];
    int c0 = blockIdx.x * 32, r0 = blockIdx.y * 32;
    const float* inb = in + (size_t)blockIdx.z * R * C;
    short* outb = out + (size_t)blockIdx.z * R * C;
    int tx = threadIdx.x & 31, ty = threadIdx.x >> 5;   // 32 x 8
    #pragma unroll
    for (int i = 0; i < 32; i += 8)
        t[ty + i][tx] = inb[(size_t)(r0 + ty + i) * C + c0 + tx];
    __syncthreads();
    #pragma unroll
    for (int i = 0; i < 32; i += 8)
        outb[(size_t)(c0 + ty + i) * R + r0 + tx] = f2bf(t[tx][ty + i]);
}

// ---------------- bf16 MFMA GEMM 128x64 (QKV) ------------------------------
__global__ __launch_bounds__(256) void gemm_qkv(
        const short* __restrict__ A, const short* __restrict__ Bt,
        short* __restrict__ qo, short* __restrict__ ko, short* __restrict__ vo,
        int M, int N, int K) {
    __shared__ char As[2][16384];   // [128 rows][128B], XOR-swizzled
    __shared__ char Bs[2][8192];    // [64 rows][128B]
    int tid = threadIdx.x, lane = tid & 63, w = tid >> 6;

    int orig = blockIdx.y * gridDim.x + blockIdx.x;
    int cpx = (gridDim.x * gridDim.y) >> 3;
    int wgid = (orig & 7) * cpx + (orig >> 3);
    int m0 = (wgid / gridDim.x) * 128;
    int n0 = (wgid % gridDim.x) * 64;

    const size_t Kb = (size_t)K * 2;
    int rowA[4], cbA[4], rowB[2], cbB[2];
    #pragma unroll
    for (int i = 0; i < 4; ++i) {
        int o = (w * 4 + i) * 1024 + lane * 16;
        rowA[i] = o >> 7;
        cbA[i] = (o & 127) ^ ((rowA[i] & 7) << 4);
    }
    #pragma unroll
    for (int i = 0; i < 2; ++i) {
        int o = (w * 2 + i) * 1024 + lane * 16;
        rowB[i] = o >> 7;
        cbB[i] = (o & 127) ^ ((rowB[i] & 7) << 4);
    }

    #define STAGE_Q(buf, kt) do {                                              \
        _Pragma("unroll")                                                      \
        for (int i_ = 0; i_ < 4; ++i_) {                                       \
            const char* ga_ = (const char*)A + (size_t)(m0 + rowA[i_]) * Kb    \
                              + (size_t)(kt) * 2 + cbA[i_];                    \
            __builtin_amdgcn_global_load_lds(                                  \
                (const __attribute__((address_space(1))) void*)ga_,            \
                (__attribute__((address_space(3))) void*)(As[buf] + (w * 4 + i_) * 1024),\
                16, 0, 0);                                                     \
        }                                                                      \
        _Pragma("unroll")                                                      \
        for (int i_ = 0; i_ < 2; ++i_) {                                       \
            const char* gb_ = (const char*)Bt + (size_t)(n0 + rowB[i_]) * Kb   \
                              + (size_t)(kt) * 2 + cbB[i_];                    \
            __builtin_amdgcn_global_load_lds(                                  \
                (const __attribute__((address_space(1))) void*)gb_,            \
                (__attribute__((address_space(3))) void*)(Bs[buf] + (w * 2 + i_) * 1024),\
                16, 0, 0);                                                     \
        }                                                                      \
    } while (0)

    f32x4 acc[2][4] = {};
    int nt = K >> 6;
    STAGE_Q(0, 0);
    for (int t = 0; t < nt; ++t) {
        int cur = t & 1;
        if (t + 1 < nt) {
            STAGE_Q(cur ^ 1, (t + 1) * 64);
            asm volatile("s_waitcnt vmcnt(6)" ::: "memory");
        } else {
            asm volatile("s_waitcnt vmcnt(0)" ::: "memory");
        }
        __builtin_amdgcn_s_barrier();
        __builtin_amdgcn_s_setprio(1);
        #pragma unroll
        for (int kk = 0; kk < 2; ++kk) {
            int kbyte = kk * 64 + (lane >> 4) * 16;
            bf16x8 bf[4], af[2];
            #pragma unroll
            for (int ni = 0; ni < 4; ++ni) {
                int row = ni * 16 + (lane & 15);
                bf[ni] = *(const bf16x8*)(Bs[cur] + row * 128 + (kbyte ^ ((row & 7) << 4)));
            }
            #pragma unroll
            for (int mi = 0; mi < 2; ++mi) {
                int row = w * 32 + mi * 16 + (lane & 15);
                af[mi] = *(const bf16x8*)(As[cur] + row * 128 + (kbyte ^ ((row & 7) << 4)));
            }
            #pragma unroll
            for (int mi = 0; mi < 2; ++mi)
                #pragma unroll
                for (int ni = 0; ni < 4; ++ni)
                    acc[mi][ni] = __builtin_amdgcn_mfma_f32_16x16x32_bf16(
                        af[mi], bf[ni], acc[mi][ni], 0, 0, 0);
        }
        __builtin_amdgcn_s_setprio(0);
        __builtin_amdgcn_s_barrier();
    }
    #undef STAGE_Q

    int sel = n0 >> 10, hh = (n0 & 1023) >> 6;
    #pragma unroll
    for (int mi = 0; mi < 2; ++mi) {
        #pragma unroll
        for (int j = 0; j < 4; ++j) {
            int row = m0 + w * 32 + mi * 16 + (lane >> 4) * 4 + j;
            int bb = row >> 11, tt = row & 2047;
            #pragma unroll
            for (int ni = 0; ni < 4; ++ni) {
                int e = ni * 16 + (lane & 15);
                short bv = f2bf(acc[mi][ni][j]);
                if (sel == 0)
                    qo[(((size_t)(bb * H_ + hh)) * T_ + tt) * HS_ + e] = bv;
                else if (sel == 1)
                    ko[(((size_t)(bb * H_ + hh)) * T_ + tt) * HS_ + e] = bv;
                else  // V stored TRANSPOSED: [bh][e][T]
                    vo[(((size_t)(bb * H_ + hh)) * HS_ + e) * T_ + tt] = bv;
            }
        }
    }
}

// ---------------- bf16 MFMA GEMM 128x128, SPLIT-K (FFN2) -------------------
__global__ __launch_bounds__(256) void gemm128_sk(
        const short* __restrict__ A, const short* __restrict__ Bt,
        float* __restrict__ P, int M, int N, int Ksl, int Ktot) {
    __shared__ char As[2][16384];
    __shared__ char Bs[2][16384];
    int tid = threadIdx.x;
    int lane = tid & 63, w = tid >> 6;
    int wr = w >> 1, wc = w & 1;

    int orig = blockIdx.y * gridDim.x + blockIdx.x;
    int cpx = (gridDim.x * gridDim.y) >> 3;
    int wgid = (orig & 7) * cpx + (orig >> 3);
    int m0 = (wgid / gridDim.x) * 128;
    int n0 = (wgid % gridDim.x) * 128;
    int k0 = blockIdx.z * Ksl;
    float* Pz = P + (size_t)blockIdx.z * M * N;

    f32x4 acc[4][4] = {};

    int rowS[4], kbS[4];
    #pragma unroll
    for (int i = 0; i < 4; ++i) {
        int o = (w * 4 + i) * 1024 + lane * 16;
        rowS[i] = o >> 7;
        kbS[i] = (o & 127) ^ ((rowS[i] & 7) << 4);
    }
    const size_t Kb = (size_t)Ktot * 2;

    #define STAGE_K(buf, kt) do {                                              \
        _Pragma("unroll")                                                      \
        for (int i_ = 0; i_ < 4; ++i_) {                                       \
            int c_ = w * 4 + i_;                                               \
            const char* ga_ = (const char*)A + (size_t)(m0 + rowS[i_]) * Kb    \
                              + (size_t)(k0 + (kt)) * 2 + kbS[i_];             \
            __builtin_amdgcn_global_load_lds(                                  \
                (const __attribute__((address_space(1))) void*)ga_,            \
                (__attribute__((address_space(3))) void*)(As[buf] + c_ * 1024),\
                16, 0, 0);                                                     \
            const char* gb_ = (const char*)Bt + (size_t)(n0 + rowS[i_]) * Kb   \
                              + (size_t)(k0 + (kt)) * 2 + kbS[i_];             \
            __builtin_amdgcn_global_load_lds(                                  \
                (const __attribute__((address_space(1))) void*)gb_,            \
                (__attribute__((address_space(3))) void*)(Bs[buf] + c_ * 1024),\
                16, 0, 0);                                                     \
        }                                                                      \
    } while (0)

    int nt = Ksl >> 6;
    STAGE_K(0, 0);
    for (int t = 0; t < nt; ++t) {
        int cur = t & 1;
        if (t + 1 < nt) {
            STAGE_K(cur ^ 1, (t + 1) * 64);
            asm volatile("s_waitcnt vmcnt(8)" ::: "memory");
        } else {
            asm volatile("s_waitcnt vmcnt(0)" ::: "memory");
        }
        __builtin_amdgcn_s_barrier();
        __builtin_amdgcn_s_setprio(1);
        #pragma unroll
        for (int kk = 0; kk < 2; ++kk) {
            int kbyte = kk * 64 + (lane >> 4) * 16;
            bf16x8 af[4], bf[4];
            #pragma unroll
            for (int mi = 0; mi < 4; ++mi) {
                int row = wr * 64 + mi * 16 + (lane & 15);
                af[mi] = *(const bf16x8*)(As[cur] + row * 128 + (kbyte ^ ((row & 7) << 4)));
            }
            #pragma unroll
            for (int ni = 0; ni < 4; ++ni) {
                int row = wc * 64 + ni * 16 + (lane & 15);
                bf[ni] = *(const bf16x8*)(Bs[cur] + row * 128 + (kbyte ^ ((row & 7) << 4)));
            }
            #pragma unroll
            for (int mi = 0; mi < 4; ++mi)
                #pragma unroll
                for (int ni = 0; ni < 4; ++ni)
                    acc[mi][ni] = __builtin_amdgcn_mfma_f32_16x16x32_bf16(
                        af[mi], bf[ni], acc[mi][ni], 0, 0, 0);
        }
        __builtin_amdgcn_s_setprio(0);
        __builtin_amdgcn_s_barrier();
    }
    #undef STAGE_K

    #pragma unroll
    for (int mi = 0; mi < 4; ++mi) {
        #pragma unroll
        for (int j = 0; j < 4; ++j) {
            int row = m0 + wr * 64 + mi * 16 + (lane >> 4) * 4 + j;
            #pragma unroll
            for (int ni = 0; ni < 4; ++ni) {
                int col = n0 + wc * 64 + ni * 16 + (lane & 15);
                Pz[(size_t)row * N + col] = acc[mi][ni][j];
            }
        }
    }
}

// ---------------- split-K reduce: out = p0 + p1 + bias + res ---------------
__global__ __launch_bounds__(256) void addreduce(const float* __restrict__ p0,
        const float* __restrict__ p1, const float* __restrict__ bias,
        const float* __restrict__ res, float* __restrict__ out) {
    int i = blockIdx.x * 256 + threadIdx.x;   // float4 index; N=1024 cols
    float4 a = ((const float4*)p0)[i];
    float4 b = ((const float4*)p1)[i];
    float4 r = ((const float4*)res)[i];
    float4 bs = ((const float4*)bias)[i & 255];
    float4 o;
    o.x = a.x + b.x + r.x + bs.x;
    o.y = a.y + b.y + r.y + bs.y;
    o.z = a.z + b.z + r.z + bs.z;
    o.w = a.w + b.w + r.w + bs.w;
    ((float4*)out)[i] = o;
}

// ---------------- bf16 MFMA GEMM 128x64 (proj) -----------------------------
template<bool BIAS, bool RES, bool RELU, bool BF16OUT>
__global__ __launch_bounds__(256) void gemm_12864(
        const short* __restrict__ A, const short* __restrict__ Bt,
        const float* __restrict__ bias, const float* __restrict__ res,
        float* __restrict__ C, short* __restrict__ Cb,
        int M, int N, int K) {
    __shared__ char As[2][16384];   // [128 rows][128B], XOR-swizzled
    __shared__ char Bs[2][8192];    // [64 rows][128B]
    int tid = threadIdx.x, lane = tid & 63, w = tid >> 6;

    int orig = blockIdx.y * gridDim.x + blockIdx.x;
    int cpx = (gridDim.x * gridDim.y) >> 3;
    int wgid = (orig & 7) * cpx + (orig >> 3);
    int m0 = (wgid / gridDim.x) * 128;
    int n0 = (wgid % gridDim.x) * 64;

    const size_t Kb = (size_t)K * 2;
    int rowA[4], cbA[4], rowB[2], cbB[2];
    #pragma unroll
    for (int i = 0; i < 4; ++i) {
        int o = (w * 4 + i) * 1024 + lane * 16;
        rowA[i] = o >> 7;
        cbA[i] = (o & 127) ^ ((rowA[i] & 7) << 4);
    }
    #pragma unroll
    for (int i = 0; i < 2; ++i) {
        int o = (w * 2 + i) * 1024 + lane * 16;
        rowB[i] = o >> 7;
        cbB[i] = (o & 127) ^ ((rowB[i] & 7) << 4);
    }

    #define STAGE_S(buf, kt) do {                                              \
        _Pragma("unroll")                                                      \
        for (int i_ = 0; i_ < 4; ++i_) {                                       \
            const char* ga_ = (const char*)A + (size_t)(m0 + rowA[i_]) * Kb    \
                              + (size_t)(kt) * 2 + cbA[i_];                    \
            __builtin_amdgcn_global_load_lds(                                  \
                (const __attribute__((address_space(1))) void*)ga_,            \
                (__attribute__((address_space(3))) void*)(As[buf] + (w * 4 + i_) * 1024),\
                16, 0, 0);                                                     \
        }                                                                      \
        _Pragma("unroll")                                                      \
        for (int i_ = 0; i_ < 2; ++i_) {                                       \
            const char* gb_ = (const char*)Bt + (size_t)(n0 + rowB[i_]) * Kb   \
                              + (size_t)(kt) * 2 + cbB[i_];                    \
            __builtin_amdgcn_global_load_lds(                                  \
                (const __attribute__((address_space(1))) void*)gb_,            \
                (__attribute__((address_space(3))) void*)(Bs[buf] + (w * 2 + i_) * 1024),\
                16, 0, 0);                                                     \
        }                                                                      \
    } while (0)

    f32x4 acc[2][4] = {};
    int nt = K >> 6;
    STAGE_S(0, 0);
    for (int t = 0; t < nt; ++t) {
        int cur = t & 1;
        if (t + 1 < nt) {
            STAGE_S(cur ^ 1, (t + 1) * 64);
            asm volatile("s_waitcnt vmcnt(6)" ::: "memory");
        } else {
            asm volatile("s_waitcnt vmcnt(0)" ::: "memory");
        }
        __builtin_amdgcn_s_barrier();
        __builtin_amdgcn_s_setprio(1);
        #pragma unroll
        for (int kk = 0; kk < 2; ++kk) {
            int kbyte = kk * 64 + (lane >> 4) * 16;
            bf16x8 bf[4], af[2];
            #pragma unroll
            for (int ni = 0; ni < 4; ++ni) {
                int row = ni * 16 + (lane & 15);
                bf[ni] = *(const bf16x8*)(Bs[cur] + row * 128 + (kbyte ^ ((row & 7) << 4)));
            }
            #pragma unroll
            for (int mi = 0; mi < 2; ++mi) {
                int row = w * 32 + mi * 16 + (lane & 15);
                af[mi] = *(const bf16x8*)(As[cur] + row * 128 + (kbyte ^ ((row & 7) << 4)));
            }
            #pragma unroll
            for (int mi = 0; mi < 2; ++mi)
                #pragma unroll
                for (int ni = 0; ni < 4; ++ni)
                    acc[mi][ni] = __builtin_amdgcn_mfma_f32_16x16x32_bf16(
                        af[mi], bf[ni], acc[mi][ni], 0, 0, 0);
        }
        __builtin_amdgcn_s_setprio(0);
        __builtin_amdgcn_s_barrier();
    }
    #undef STAGE_S

    #pragma unroll
    for (int mi = 0; mi < 2; ++mi) {
        #pragma unroll
        for (int j = 0; j < 4; ++j) {
            int row = m0 + w * 32 + mi * 16 + (lane >> 4) * 4 + j;
            #pragma unroll
            for (int ni = 0; ni < 4; ++ni) {
                int col = n0 + ni * 16 + (lane & 15);
                float vv = acc[mi][ni][j];
                if (BIAS) vv += bias[col];
                if (RES)  vv += res[(size_t)row * N + col];
                if (RELU) vv = fmaxf(vv, 0.0f);
                if (BF16OUT) Cb[(size_t)row * N + col] = f2bf(vv);
                else         C[(size_t)row * N + col] = vv;
            }
        }
    }
}

// ============ 256x256 coarse-dbuf MFMA GEMM (FFN1) =========================
template<bool BIAS, bool RELU, bool BF16OUT>
__global__ __launch_bounds__(512, 2) void gemm256_2p(
        const short* __restrict__ A, const short* __restrict__ Bt,
        const float* __restrict__ bias,
        float* __restrict__ C, short* __restrict__ Cb,
        int M, int N, int K) {
    __shared__ char As[2][32768];   // [256 rows][128B], XOR-swizzled
    __shared__ char Bs[2][32768];
    int tid = threadIdx.x, lane = tid & 63, w = tid >> 6;
    int wr = w >> 2, wc = w & 3;

    int nwg = gridDim.x * gridDim.y;
    int orig = blockIdx.y * gridDim.x + blockIdx.x;
    int cpx = nwg >> 3;
    int wgid = (orig & 7) * cpx + (orig >> 3);
    int m0 = (wgid / gridDim.x) * 256;
    int n0 = (wgid % gridDim.x) * 256;

    const size_t Kb = (size_t)K * 2;
    int rowS[4], cbS[4];
    #pragma unroll
    for (int i = 0; i < 4; ++i) {
        int o = (i * 8 + w) * 1024 + lane * 16;
        rowS[i] = o >> 7;                               // 0..255
        cbS[i] = (o & 127) ^ ((rowS[i] & 7) << 4);
    }

    #define STAGE_256(buf, kt) do {                                           \
        _Pragma("unroll")                                                     \
        for (int i_ = 0; i_ < 4; ++i_) {                                      \
            int c_ = i_ * 8 + w;                                              \
            const char* ga_ = (const char*)A + (size_t)(m0 + rowS[i_]) * Kb   \
                              + (size_t)(kt) * 2 + cbS[i_];                   \
            __builtin_amdgcn_global_load_lds(                                 \
                (const __attribute__((address_space(1))) void*)ga_,           \
                (__attribute__((address_space(3))) void*)(As[buf] + c_ * 1024),\
                16, 0, 0);                                                    \
            const char* gb_ = (const char*)Bt + (size_t)(n0 + rowS[i_]) * Kb  \
                              + (size_t)(kt) * 2 + cbS[i_];                   \
            __builtin_amdgcn_global_load_lds(                                 \
                (const __attribute__((address_space(1))) void*)gb_,           \
                (__attribute__((address_space(3))) void*)(Bs[buf] + c_ * 1024),\
                16, 0, 0);                                                    \
        }                                                                     \
    } while (0)

    f32x4 acc[8][4] = {};
    int nt = K >> 6;
    STAGE_256(0, 0);
    for (int t = 0; t < nt; ++t) {
        int cur = t & 1;
        if (t + 1 < nt) {
            STAGE_256(cur ^ 1, (t + 1) * 64);
            asm volatile("s_waitcnt vmcnt(8)" ::: "memory");
        } else {
            asm volatile("s_waitcnt vmcnt(0)" ::: "memory");
        }
        __builtin_amdgcn_s_barrier();
        __builtin_amdgcn_s_setprio(1);
        #pragma unroll
        for (int kk = 0; kk < 2; ++kk) {
            int kbyte = kk * 64 + (lane >> 4) * 16;
            bf16x8 bfr[4];
            #pragma unroll
            for (int ni = 0; ni < 4; ++ni) {
                int row = wc * 64 + ni * 16 + (lane & 15);
                bfr[ni] = *(const bf16x8*)(Bs[cur] + row * 128 + (kbyte ^ ((row & 7) << 4)));
            }
            #pragma unroll
            for (int mi = 0; mi < 8; ++mi) {
                int row = wr * 128 + mi * 16 + (lane & 15);
                bf16x8 afr = *(const bf16x8*)(As[cur] + row * 128 + (kbyte ^ ((row & 7) << 4)));
                #pragma unroll
                for (int ni = 0; ni < 4; ++ni)
                    acc[mi][ni] = __builtin_amdgcn_mfma_f32_16x16x32_bf16(
                        afr, bfr[ni], acc[mi][ni], 0, 0, 0);
            }
        }
        __builtin_amdgcn_s_setprio(0);
        __builtin_amdgcn_s_barrier();
    }
    #undef STAGE_256

    #pragma unroll
    for (int mi = 0; mi < 8; ++mi) {
        #pragma unroll
        for (int j = 0; j < 4; ++j) {
            int row = m0 + wr * 128 + mi * 16 + (lane >> 4) * 4 + j;
            #pragma unroll
            for (int ni = 0; ni < 4; ++ni) {
                int col = n0 + wc * 64 + ni * 16 + (lane & 15);
                float vv = acc[mi][ni][j];
                if (BIAS) vv += bias[col];
                if (RELU) vv = fmaxf(vv, 0.0f);
                if (BF16OUT) Cb[(size_t)row * N + col] = f2bf(vv);
                else         C[(size_t)row * N + col] = vv;
            }
        }
    }
}

// ---------------- pass 1: per-key column sums (NO max tracking) ------------
__global__ __launch_bounds__(256) void attn_pass1_mfma(
        const short* __restrict__ qg, const short* __restrict__ kg,
        float* __restrict__ lpart) {
    int kt = blockIdx.x;      // 128-key tile, 0..15
    int chunk = blockIdx.y;   // 0..3
    int bh = blockIdx.z;
    int tid = threadIdx.x, lane = tid & 63, w = tid >> 6;
    __shared__ char Qs[8192];
    const size_t base = (size_t)bh * T_ * HS_;
    int kb0 = kt * 128;
    bf16x8 af[2][2];
    #pragma unroll
    for (int s2 = 0; s2 < 2; ++s2) {
        const short* kr = kg + base
            + (size_t)(kb0 + s2 * 64 + w * 16 + (lane & 15)) * HS_ + (lane >> 4) * 8;
        af[s2][0] = *(const bf16x8*)kr;
        af[s2][1] = *(const bf16x8*)(kr + 32);
    }
    int baseT = kt * 2;
    int R = 32 - baseT;
    int cnt = (R + 3) >> 2;
    int qs = baseT + chunk * cnt;
    int qe = qs + cnt; if (qe > 32) qe = 32;
    float psum[2][4] = {};
    for (int qt = qs; qt < qe; ++qt) {
        __syncthreads();
        #pragma unroll
        for (int it = 0; it < 2; ++it) {
            int o = it * 4096 + w * 1024 + lane * 16;
            int row = o >> 7;
            int col = (o & 127) ^ ((row & 7) << 4);
            const char* src = (const char*)(qg + base + (size_t)(qt * 64 + row) * HS_) + col;
            __builtin_amdgcn_global_load_lds(
                (const __attribute__((address_space(1))) void*)src,
                (__attribute__((address_space(3))) void*)(Qs + it * 4096 + w * 1024), 16, 0, 0);
        }
        __syncthreads();
        #pragma unroll
        for (int sub = 0; sub < 4; ++sub) {
            int qrow = sub * 16 + (lane & 15);
            bf16x8 bq[2];
            #pragma unroll
            for (int kk = 0; kk < 2; ++kk) {
                int off = (kk * 64 + (lane >> 4) * 16) ^ ((qrow & 7) << 4);
                bq[kk] = *(const bf16x8*)(Qs + qrow * 128 + off);
            }
            int qglob = qt * 64 + qrow;
            #pragma unroll
            for (int s2 = 0; s2 < 2; ++s2) {
                f32x4 c = {0.f, 0.f, 0.f, 0.f};
                c = __builtin_amdgcn_mfma_f32_16x16x32_bf16(af[s2][0], bq[0], c, 0, 0, 0);
                c = __builtin_amdgcn_mfma_f32_16x16x32_bf16(af[s2][1], bq[1], c, 0, 0, 0);
                #pragma unroll
                for (int j = 0; j < 4; ++j) {
                    int kglob = kb0 + s2 * 64 + w * 16 + (lane >> 4) * 4 + j;
                    float pe = exp2f(c[j] * C2_);
                    psum[s2][j] += (qglob >= kglob) ? pe : 0.0f;
                }
            }
        }
    }
    #pragma unroll
    for (int s2 = 0; s2 < 2; ++s2)
        #pragma unroll
        for (int j = 0; j < 4; ++j) {
            float v = psum[s2][j];
            v += __shfl_xor(v, 1); v += __shfl_xor(v, 2);
            v += __shfl_xor(v, 4); v += __shfl_xor(v, 8);
            psum[s2][j] = v;
        }
    if ((lane & 15) == 0) {
        #pragma unroll
        for (int s2 = 0; s2 < 2; ++s2)
            #pragma unroll
            for (int j = 0; j < 4; ++j)
                lpart[((size_t)chunk * 32 + bh) * T_
                      + kb0 + s2 * 64 + w * 16 + (lane >> 4) * 4 + j] = psum[s2][j];
    }
}

// ---------------- reduce partials -> NEGATIVE LOG2 of column sum -----------
__global__ __launch_bounds__(256) void lreduce(const float* __restrict__ lpart,
        float* __restrict__ rl) {
    int i = blockIdx.x * 256 + threadIdx.x;   // i < 32*2048
    const int S = 32 * T_;
    float s = lpart[i] + lpart[S + i] + lpart[2 * S + i] + lpart[3 * S + i];
    rl[i] = -log2f(s);
}

// ---------------- pass 2: O = sum_k exp2(t + lg_k) * V[k] ------------------
// Triangle-paired halves (round-15 grid shape: 512 equal blocks, all resident)
// + raw s_barrier with COUNTED vmcnt(4) (true dbuf overlap, no drain)
// + rl preloaded once into LDS (stage = exactly 4 global_load_lds/thread).
__global__ __launch_bounds__(256) void attn_pass2_mfma(
        const short* __restrict__ qg, const short* __restrict__ kg,
        const short* __restrict__ vt, const float* __restrict__ rl,
        short* __restrict__ attnb) {
    int pair = blockIdx.x, bh = blockIdx.y;
    int bb = bh >> 4, hh = bh & 15;
    int tid = threadIdx.x, lane = tid & 63, w = tid >> 6;   // 4 waves
    __shared__ char Kb[2][8192];    // [64 keys][128B], swizzled
    __shared__ char Vb[2][8192];    // [64 e][128B = 64 keys], swizzled
    __shared__ char Ps[8192];       // [64 q][128B], wave-private rows
    __shared__ float rlAll[2048];   // full -log2(l) row for this bh (8KB)
    const size_t qkbase = (size_t)bh * T_ * HS_;
    const size_t vtbase = (size_t)bh * HS_ * T_;

    // preload rl once (2048 floats; 256 threads x 2 float4)
    {
        const float4* rp = (const float4*)(rl + (size_t)bh * T_);
        #pragma unroll
        for (int i = 0; i < 2; ++i)
            *(float4*)&rlAll[(tid * 2 + i) * 4] = rp[tid * 2 + i];
    }
    __syncthreads();

    #pragma unroll 1
    for (int half = 0; half < 2; ++half) {
        int qtile = half == 0 ? pair : 31 - pair;
        int q0 = qtile * 64 + w * 16;
        bf16x8 aq[2];
        {
            const short* qr = qg + qkbase + (size_t)(q0 + (lane & 15)) * HS_ + (lane >> 4) * 8;
            aq[0] = *(const bf16x8*)qr;
            aq[1] = *(const bf16x8*)(qr + 32);
        }
        f32x4 oacc[4] = {};
        int nstep = qtile + 1;   // 64-key steps

        // stage = EXACTLY 4 global_load_lds per thread (2 K + 2 V)
        #define STAGE64(bufi, stepi) do {                                         \
            int k0_ = (stepi) * 64;                                               \
            _Pragma("unroll")                                                     \
            for (int i_ = 0; i_ < 2; ++i_) {                                      \
                int c_ = w * 2 + i_;                                              \
                int o_ = c_ * 1024 + lane * 16;                                   \
                int row_ = o_ >> 7;                                               \
                int col_ = (o_ & 127) ^ ((row_ & 7) << 4);                        \
                const char* srcK_ = (const char*)(kg + qkbase                     \
                    + (size_t)(k0_ + row_) * HS_) + col_;                         \
                __builtin_amdgcn_global_load_lds(                                 \
                    (const __attribute__((address_space(1))) void*)srcK_,         \
                    (__attribute__((address_space(3))) void*)(Kb[bufi] + c_ * 1024), \
                    16, 0, 0);                                                    \
                const char* srcV_ = (const char*)(vt + vtbase                     \
                    + (size_t)row_ * T_ + k0_) + col_;                            \
                __builtin_amdgcn_global_load_lds(                                 \
                    (const __attribute__((address_space(1))) void*)srcV_,         \
                    (__attribute__((address_space(3))) void*)(Vb[bufi] + c_ * 1024), \
                    16, 0, 0);                                                    \
            }                                                                     \
        } while (0)

        STAGE64(0, 0);
        for (int st = 0; st < nstep; ++st) {
            int cur = st & 1;
            if (st + 1 < nstep) {
                STAGE64(cur ^ 1, st + 1);
                asm volatile("s_waitcnt vmcnt(4)" ::: "memory");   // cur resident, next in flight
            } else {
                asm volatile("s_waitcnt vmcnt(0)" ::: "memory");
            }
            __builtin_amdgcn_s_barrier();
            int kbase = st * 64;
            bool diag = (st == qtile);
            int qgl = q0 + (lane & 15);
            int ql = w * 16 + (lane & 15);
            int swz = (ql & 7) << 4;
            #pragma unroll
            for (int sub = 0; sub < 4; ++sub) {
                int krow = sub * 16 + (lane & 15);
                f32x4 c = {0.f, 0.f, 0.f, 0.f};
                #pragma unroll
                for (int kk = 0; kk < 2; ++kk) {
                    int off = (kk * 64 + (lane >> 4) * 16) ^ ((krow & 7) << 4);
                    bf16x8 bk = *(const bf16x8*)(Kb[cur] + krow * 128 + off);
                    // SWAPPED: A = K fragment, B = Q fragment -> c = S^T
                    c = __builtin_amdgcn_mfma_f32_16x16x32_bf16(bk, aq[kk], c, 0, 0, 0);
                }
                int kloc0 = sub * 16 + (lane >> 4) * 4;
                f32x4 lg4 = *(const f32x4*)&rlAll[kbase + kloc0];
                float wv[4];
                #pragma unroll
                for (int j = 0; j < 4; ++j) {
                    float t = exp2f(fmaf(c[j], C2_, lg4[j]));
                    int keyg = kbase + kloc0 + j;
                    wv[j] = (diag && qgl < keyg) ? 0.0f : t;
                }
                unsigned p01, p23;
                asm("v_cvt_pk_bf16_f32 %0, %1, %2" : "=v"(p01) : "v"(wv[0]), "v"(wv[1]));
                asm("v_cvt_pk_bf16_f32 %0, %1, %2" : "=v"(p23) : "v"(wv[2]), "v"(wv[3]));
                *(unsigned*)(Ps + ql * 128 + ((kloc0 * 2) ^ swz)) = p01;
                *(unsigned*)(Ps + ql * 128 + ((kloc0 * 2 + 4) ^ swz)) = p23;
            }
            bf16x8 ap[2];
            #pragma unroll
            for (int kk = 0; kk < 2; ++kk) {
                int off = (kk * 64 + (lane >> 4) * 16) ^ swz;
                ap[kk] = *(const bf16x8*)(Ps + ql * 128 + off);
            }
            #pragma unroll
            for (int es = 0; es < 4; ++es) {
                int erow = es * 16 + (lane & 15);
                #pragma unroll
                for (int kk = 0; kk < 2; ++kk) {
                    int vcol = (kk * 64 + (lane >> 4) * 16) ^ ((erow & 7) << 4);
                    bf16x8 bv = *(const bf16x8*)(Vb[cur] + erow * 128 + vcol);
                    oacc[es] = __builtin_amdgcn_mfma_f32_16x16x32_bf16(
                        ap[kk], bv, oacc[es], 0, 0, 0);
                }
            }
            __builtin_amdgcn_s_barrier();   // all waves done reading buf[cur]
        }
        #undef STAGE64
        #pragma unroll
        for (int es = 0; es < 4; ++es) {
            #pragma unroll
            for (int j = 0; j < 4; ++j) {
                int qgl = q0 + (lane >> 4) * 4 + j;
                int e = es * 16 + (lane & 15);
                attnb[((size_t)(bb * T_ + qgl)) * D_ + hh * HS_ + e] = f2bf(oacc[es][j]);
            }
        }
        // trailing s_barrier of the last step protects LDS before next half
    }
}

extern "C" void kernel_launch(void* const* d_in, const int* in_sizes, int n_in,
                              void* d_out, int out_size, void* d_ws, size_t ws_size,
                              hipStream_t stream) {
    const float* x     = (const float*)d_in[0];
    const float* Wq    = (const float*)d_in[1];
    const float* Wk    = (const float*)d_in[2];
    const float* Wv    = (const float*)d_in[3];
    const float* Wproj = (const float*)d_in[4];
    const float* bproj = (const float*)d_in[5];
    const float* W1    = (const float*)d_in[6];
    const float* b1    = (const float*)d_in[7];
    const float* W2    = (const float*)d_in[8];
    const float* b2    = (const float*)d_in[9];
    const float* ln1g  = (const float*)d_in[10];
    const float* ln1b  = (const float*)d_in[11];
    const float* ln2g  = (const float*)d_in[12];
    const float* ln2b  = (const float*)d_in[13];
    float* out = (float*)d_out;

    const size_t MB = 1u << 20;
    char* ws = (char*)d_ws;
    float* xn    = (float*)(ws + 0 * MB);     // 16MB
    short* xnb   = (short*)(ws + 16 * MB);    // 8MB
    short* qbh   = (short*)(ws + 24 * MB);    // 8MB  [bh][T][HS] bf16
    short* kbh   = (short*)(ws + 32 * MB);    // 8MB  [bh][T][HS] bf16
    short* vtb   = (short*)(ws + 40 * MB);    // 8MB  [bh][HS][T] bf16 (transposed)
    short* attnb = (short*)(ws + 48 * MB);    // 8MB
    float* x1    = (float*)(ws + 56 * MB);    // 16MB
    float* x1n   = (float*)(ws + 72 * MB);    // 16MB
    short* x1nb  = (short*)(ws + 88 * MB);    // 8MB
    short* hb    = (short*)(ws + 96 * MB);    // 32MB
    short* wqkv  = (short*)(ws + 128 * MB);   // 6MB  [3072][1024]
    short* wprjt = (short*)(ws + 134 * MB);   // 2MB  [1024][1024]
    short* w1t   = (short*)(ws + 136 * MB);   // 8MB  [4096][1024]
    short* w2t   = (short*)(ws + 144 * MB);   // 8MB  [1024][4096]
    float* lpart = (float*)(ws + 152 * MB);   // 1MB  [4][32][2048]
    float* rl    = (float*)(ws + 153 * MB);   // 256KB [32][2048]
    // Split-K partials: CONTIGUOUS 32MB (xn + xnb/qbh regions, dead by FFN2)
    float* partP = (float*)(ws + 0 * MB);
    float* part0 = (float*)(ws + 0 * MB);
    float* part1 = (float*)(ws + 16 * MB);

    // 0. weight transpose+convert
    transpose_cvt<<<dim3(2, 32, 16), 256, 0, stream>>>(Wq, wqkv + (size_t)0 * 1048576, 1024, 64);
    transpose_cvt<<<dim3(2, 32, 16), 256, 0, stream>>>(Wk, wqkv + (size_t)1 * 1048576, 1024, 64);
    transpose_cvt<<<dim3(2, 32, 16), 256, 0, stream>>>(Wv, wqkv + (size_t)2 * 1048576, 1024, 64);
    transpose_cvt<<<dim3(32, 32, 1), 256, 0, stream>>>(Wproj, wprjt, 1024, 1024);
    transpose_cvt<<<dim3(128, 32, 1), 256, 0, stream>>>(W1, w1t, 1024, 4096);
    transpose_cvt<<<dim3(32, 128, 1), 256, 0, stream>>>(W2, w2t, 4096, 1024);

    // 1. LN1 -> xn (fp32) + xnb (bf16)
    ln_kernel<<<dim3(BT_), 256, 0, stream>>>(x, ln1g, ln1b, xn, xnb);
    // 2. QKV fused GEMM (128x64, 1536 blocks) -> q,k bf16; v bf16 transposed
    gemm_qkv<<<dim3(48, 32), 256, 0, stream>>>(
        xnb, wqkv, qbh, kbh, vtb, BT_, 3072, 1024);
    // 3. column sums (no max): partials then -log2
    attn_pass1_mfma<<<dim3(16, 4, 32), 256, 0, stream>>>(qbh, kbh, lpart);
    lreduce<<<dim3(32 * T_ / 256), 256, 0, stream>>>(lpart, rl);
    // 4. attention output (MFMA, paired halves, counted-vmcnt dbuf)
    attn_pass2_mfma<<<dim3(16, 32), 256, 0, stream>>>(qbh, kbh, vtb, rl, attnb);
    // 5. proj + bias + residual(xn) -> x1  (128x64, 512 blocks)
    gemm_12864<true, true, false, false><<<dim3(16, 32), 256, 0, stream>>>(
        attnb, wprjt, bproj, xn, x1, nullptr, BT_, 1024, 1024);
    // 6. LN2 -> x1n + x1nb
    ln_kernel<<<dim3(BT_), 256, 0, stream>>>(x1, ln2g, ln2b, x1n, x1nb);
    // 7. FFN1: relu(x1n @ W1 + b1) -> hb (bf16)  (256x256 coarse-dbuf)
    gemm256_2p<true, true, true><<<dim3(16, 16), 512, 0, stream>>>(
        x1nb, w1t, b1, nullptr, hb, BT_, 4096, 1024);
    // 8. FFN2 split-K=2: contiguous partials at ws+0 / ws+16MB
    gemm128_sk<<<dim3(8, 32, 2), 256, 0, stream>>>(
        hb, w2t, partP, BT_, 1024, 2048, 4096);
    // 9. out = part0 + part1 + b2 + x1n
    addreduce<<<dim3(BT_ * D_ / 4 / 256), 256, 0, stream>>>(
        part0, part1, b2, x1n, out);
    (void)in_sizes; (void)n_in; (void)out_size; (void)ws_size;
}

// Round 19
// 280.040 us; speedup vs baseline: 1.1631x; 1.0545x over previous
//
#include <hip/hip_runtime.h>
#include <math.h>

#define B_ 2
#define T_ 2048
#define D_ 1024
#define H_ 16
#define HS_ 64
#define BT_ (B_*T_)
#define EPS_ 1e-5f
#define SCALE_ 0.03125f  // D^-0.5 = 1/32
#define C2_ (0.03125f * 1.44269504088896f)   // SCALE * log2(e)

typedef __attribute__((ext_vector_type(4))) float f32x4;
typedef __attribute__((ext_vector_type(8))) __bf16 bf16x8;

__device__ __forceinline__ short f2bf(float f) {
    union { float f; unsigned u; } cv; cv.f = f;
    unsigned u = cv.u;
    return (short)((u + 0x7fffu + ((u >> 16) & 1u)) >> 16);  // RTNE
}

// ---------------- LayerNorm: one block per row; fp32 + bf16 outputs --------
__global__ __launch_bounds__(256) void ln_kernel(const float* __restrict__ x,
        const float* __restrict__ g, const float* __restrict__ b,
        float* __restrict__ out, short* __restrict__ outb) {
    int row = blockIdx.x;
    int tid = threadIdx.x;
    const float* xr = x + (size_t)row * D_;
    float4 v = *(const float4*)(xr + tid * 4);
    __shared__ float red[256];
    red[tid] = v.x + v.y + v.z + v.w;
    __syncthreads();
    for (int st = 128; st > 0; st >>= 1) {
        if (tid < st) red[tid] += red[tid + st];
        __syncthreads();
    }
    float mean = red[0] * (1.0f / D_);
    __syncthreads();
    float dx = v.x - mean, dy = v.y - mean, dz = v.z - mean, dw = v.w - mean;
    red[tid] = dx*dx + dy*dy + dz*dz + dw*dw;
    __syncthreads();
    for (int st = 128; st > 0; st >>= 1) {
        if (tid < st) red[tid] += red[tid + st];
        __syncthreads();
    }
    float rstd = rsqrtf(red[0] * (1.0f / D_) + EPS_);
    float4 gv = *(const float4*)(g + tid * 4);
    float4 bv = *(const float4*)(b + tid * 4);
    float4 o;
    o.x = dx * rstd * gv.x + bv.x;
    o.y = dy * rstd * gv.y + bv.y;
    o.z = dz * rstd * gv.z + bv.z;
    o.w = dw * rstd * gv.w + bv.w;
    *(float4*)(out + (size_t)row * D_ + tid * 4) = o;
    short4 ob = make_short4(f2bf(o.x), f2bf(o.y), f2bf(o.z), f2bf(o.w));
    *(short4*)(outb + (size_t)row * D_ + tid * 4) = ob;
}

// ---------------- fp32 [R][C] -> bf16 [C][R] transpose+convert (batched) ---
__global__ __launch_bounds__(256) void transpose_cvt(const float* __restrict__ in,
        short* __restrict__ out, int R, int C) {
    __shared__ float t[32][33];
    int c0 = blockIdx.x * 32, r0 = blockIdx.y * 32;
    const float* inb = in + (size_t)blockIdx.z * R * C;
    short* outb = out + (size_t)blockIdx.z * R * C;
    int tx = threadIdx.x & 31, ty = threadIdx.x >> 5;   // 32 x 8
    #pragma unroll
    for (int i = 0; i < 32; i += 8)
        t[ty + i][tx] = inb[(size_t)(r0 + ty + i) * C + c0 + tx];
    __syncthreads();
    #pragma unroll
    for (int i = 0; i < 32; i += 8)
        outb[(size_t)(c0 + ty + i) * R + r0 + tx] = f2bf(t[tx][ty + i]);
}

// ---------------- bf16 MFMA GEMM 128x64 (QKV) ------------------------------
__global__ __launch_bounds__(256) void gemm_qkv(
        const short* __restrict__ A, const short* __restrict__ Bt,
        short* __restrict__ qo, short* __restrict__ ko, short* __restrict__ vo,
        int M, int N, int K) {
    __shared__ char As[2][16384];   // [128 rows][128B], XOR-swizzled
    __shared__ char Bs[2][8192];    // [64 rows][128B]
    int tid = threadIdx.x, lane = tid & 63, w = tid >> 6;

    int orig = blockIdx.y * gridDim.x + blockIdx.x;
    int cpx = (gridDim.x * gridDim.y) >> 3;
    int wgid = (orig & 7) * cpx + (orig >> 3);
    int m0 = (wgid / gridDim.x) * 128;
    int n0 = (wgid % gridDim.x) * 64;

    const size_t Kb = (size_t)K * 2;
    int rowA[4], cbA[4], rowB[2], cbB[2];
    #pragma unroll
    for (int i = 0; i < 4; ++i) {
        int o = (w * 4 + i) * 1024 + lane * 16;
        rowA[i] = o >> 7;
        cbA[i] = (o & 127) ^ ((rowA[i] & 7) << 4);
    }
    #pragma unroll
    for (int i = 0; i < 2; ++i) {
        int o = (w * 2 + i) * 1024 + lane * 16;
        rowB[i] = o >> 7;
        cbB[i] = (o & 127) ^ ((rowB[i] & 7) << 4);
    }

    #define STAGE_Q(buf, kt) do {                                              \
        _Pragma("unroll")                                                      \
        for (int i_ = 0; i_ < 4; ++i_) {                                       \
            const char* ga_ = (const char*)A + (size_t)(m0 + rowA[i_]) * Kb    \
                              + (size_t)(kt) * 2 + cbA[i_];                    \
            __builtin_amdgcn_global_load_lds(                                  \
                (const __attribute__((address_space(1))) void*)ga_,            \
                (__attribute__((address_space(3))) void*)(As[buf] + (w * 4 + i_) * 1024),\
                16, 0, 0);                                                     \
        }                                                                      \
        _Pragma("unroll")                                                      \
        for (int i_ = 0; i_ < 2; ++i_) {                                       \
            const char* gb_ = (const char*)Bt + (size_t)(n0 + rowB[i_]) * Kb   \
                              + (size_t)(kt) * 2 + cbB[i_];                    \
            __builtin_amdgcn_global_load_lds(                                  \
                (const __attribute__((address_space(1))) void*)gb_,            \
                (__attribute__((address_space(3))) void*)(Bs[buf] + (w * 2 + i_) * 1024),\
                16, 0, 0);                                                     \
        }                                                                      \
    } while (0)

    f32x4 acc[2][4] = {};
    int nt = K >> 6;
    STAGE_Q(0, 0);
    for (int t = 0; t < nt; ++t) {
        int cur = t & 1;
        if (t + 1 < nt) {
            STAGE_Q(cur ^ 1, (t + 1) * 64);
            asm volatile("s_waitcnt vmcnt(6)" ::: "memory");
        } else {
            asm volatile("s_waitcnt vmcnt(0)" ::: "memory");
        }
        __builtin_amdgcn_s_barrier();
        __builtin_amdgcn_s_setprio(1);
        #pragma unroll
        for (int kk = 0; kk < 2; ++kk) {
            int kbyte = kk * 64 + (lane >> 4) * 16;
            bf16x8 bf[4], af[2];
            #pragma unroll
            for (int ni = 0; ni < 4; ++ni) {
                int row = ni * 16 + (lane & 15);
                bf[ni] = *(const bf16x8*)(Bs[cur] + row * 128 + (kbyte ^ ((row & 7) << 4)));
            }
            #pragma unroll
            for (int mi = 0; mi < 2; ++mi) {
                int row = w * 32 + mi * 16 + (lane & 15);
                af[mi] = *(const bf16x8*)(As[cur] + row * 128 + (kbyte ^ ((row & 7) << 4)));
            }
            #pragma unroll
            for (int mi = 0; mi < 2; ++mi)
                #pragma unroll
                for (int ni = 0; ni < 4; ++ni)
                    acc[mi][ni] = __builtin_amdgcn_mfma_f32_16x16x32_bf16(
                        af[mi], bf[ni], acc[mi][ni], 0, 0, 0);
        }
        __builtin_amdgcn_s_setprio(0);
        __builtin_amdgcn_s_barrier();
    }
    #undef STAGE_Q

    int sel = n0 >> 10, hh = (n0 & 1023) >> 6;
    #pragma unroll
    for (int mi = 0; mi < 2; ++mi) {
        #pragma unroll
        for (int j = 0; j < 4; ++j) {
            int row = m0 + w * 32 + mi * 16 + (lane >> 4) * 4 + j;
            int bb = row >> 11, tt = row & 2047;
            #pragma unroll
            for (int ni = 0; ni < 4; ++ni) {
                int e = ni * 16 + (lane & 15);
                short bv = f2bf(acc[mi][ni][j]);
                if (sel == 0)
                    qo[(((size_t)(bb * H_ + hh)) * T_ + tt) * HS_ + e] = bv;
                else if (sel == 1)
                    ko[(((size_t)(bb * H_ + hh)) * T_ + tt) * HS_ + e] = bv;
                else  // V stored TRANSPOSED: [bh][e][T]
                    vo[(((size_t)(bb * H_ + hh)) * HS_ + e) * T_ + tt] = bv;
            }
        }
    }
}

// ---------------- bf16 MFMA GEMM 128x128, SPLIT-K (FFN2) -------------------
__global__ __launch_bounds__(256) void gemm128_sk(
        const short* __restrict__ A, const short* __restrict__ Bt,
        float* __restrict__ P, int M, int N, int Ksl, int Ktot) {
    __shared__ char As[2][16384];
    __shared__ char Bs[2][16384];
    int tid = threadIdx.x;
    int lane = tid & 63, w = tid >> 6;
    int wr = w >> 1, wc = w & 1;

    int orig = blockIdx.y * gridDim.x + blockIdx.x;
    int cpx = (gridDim.x * gridDim.y) >> 3;
    int wgid = (orig & 7) * cpx + (orig >> 3);
    int m0 = (wgid / gridDim.x) * 128;
    int n0 = (wgid % gridDim.x) * 128;
    int k0 = blockIdx.z * Ksl;
    float* Pz = P + (size_t)blockIdx.z * M * N;

    f32x4 acc[4][4] = {};

    int rowS[4], kbS[4];
    #pragma unroll
    for (int i = 0; i < 4; ++i) {
        int o = (w * 4 + i) * 1024 + lane * 16;
        rowS[i] = o >> 7;
        kbS[i] = (o & 127) ^ ((rowS[i] & 7) << 4);
    }
    const size_t Kb = (size_t)Ktot * 2;

    #define STAGE_K(buf, kt) do {                                              \
        _Pragma("unroll")                                                      \
        for (int i_ = 0; i_ < 4; ++i_) {                                       \
            int c_ = w * 4 + i_;                                               \
            const char* ga_ = (const char*)A + (size_t)(m0 + rowS[i_]) * Kb    \
                              + (size_t)(k0 + (kt)) * 2 + kbS[i_];             \
            __builtin_amdgcn_global_load_lds(                                  \
                (const __attribute__((address_space(1))) void*)ga_,            \
                (__attribute__((address_space(3))) void*)(As[buf] + c_ * 1024),\
                16, 0, 0);                                                     \
            const char* gb_ = (const char*)Bt + (size_t)(n0 + rowS[i_]) * Kb   \
                              + (size_t)(k0 + (kt)) * 2 + kbS[i_];             \
            __builtin_amdgcn_global_load_lds(                                  \
                (const __attribute__((address_space(1))) void*)gb_,            \
                (__attribute__((address_space(3))) void*)(Bs[buf] + c_ * 1024),\
                16, 0, 0);                                                     \
        }                                                                      \
    } while (0)

    int nt = Ksl >> 6;
    STAGE_K(0, 0);
    for (int t = 0; t < nt; ++t) {
        int cur = t & 1;
        if (t + 1 < nt) {
            STAGE_K(cur ^ 1, (t + 1) * 64);
            asm volatile("s_waitcnt vmcnt(8)" ::: "memory");
        } else {
            asm volatile("s_waitcnt vmcnt(0)" ::: "memory");
        }
        __builtin_amdgcn_s_barrier();
        __builtin_amdgcn_s_setprio(1);
        #pragma unroll
        for (int kk = 0; kk < 2; ++kk) {
            int kbyte = kk * 64 + (lane >> 4) * 16;
            bf16x8 af[4], bf[4];
            #pragma unroll
            for (int mi = 0; mi < 4; ++mi) {
                int row = wr * 64 + mi * 16 + (lane & 15);
                af[mi] = *(const bf16x8*)(As[cur] + row * 128 + (kbyte ^ ((row & 7) << 4)));
            }
            #pragma unroll
            for (int ni = 0; ni < 4; ++ni) {
                int row = wc * 64 + ni * 16 + (lane & 15);
                bf[ni] = *(const bf16x8*)(Bs[cur] + row * 128 + (kbyte ^ ((row & 7) << 4)));
            }
            #pragma unroll
            for (int mi = 0; mi < 4; ++mi)
                #pragma unroll
                for (int ni = 0; ni < 4; ++ni)
                    acc[mi][ni] = __builtin_amdgcn_mfma_f32_16x16x32_bf16(
                        af[mi], bf[ni], acc[mi][ni], 0, 0, 0);
        }
        __builtin_amdgcn_s_setprio(0);
        __builtin_amdgcn_s_barrier();
    }
    #undef STAGE_K

    #pragma unroll
    for (int mi = 0; mi < 4; ++mi) {
        #pragma unroll
        for (int j = 0; j < 4; ++j) {
            int row = m0 + wr * 64 + mi * 16 + (lane >> 4) * 4 + j;
            #pragma unroll
            for (int ni = 0; ni < 4; ++ni) {
                int col = n0 + wc * 64 + ni * 16 + (lane & 15);
                Pz[(size_t)row * N + col] = acc[mi][ni][j];
            }
        }
    }
}

// ---------------- split-K reduce: out = p0 + p1 + bias + res ---------------
__global__ __launch_bounds__(256) void addreduce(const float* __restrict__ p0,
        const float* __restrict__ p1, const float* __restrict__ bias,
        const float* __restrict__ res, float* __restrict__ out) {
    int i = blockIdx.x * 256 + threadIdx.x;   // float4 index; N=1024 cols
    float4 a = ((const float4*)p0)[i];
    float4 b = ((const float4*)p1)[i];
    float4 r = ((const float4*)res)[i];
    float4 bs = ((const float4*)bias)[i & 255];
    float4 o;
    o.x = a.x + b.x + r.x + bs.x;
    o.y = a.y + b.y + r.y + bs.y;
    o.z = a.z + b.z + r.z + bs.z;
    o.w = a.w + b.w + r.w + bs.w;
    ((float4*)out)[i] = o;
}

// ---------------- bf16 MFMA GEMM 128x64 (proj) -----------------------------
template<bool BIAS, bool RES, bool RELU, bool BF16OUT>
__global__ __launch_bounds__(256) void gemm_12864(
        const short* __restrict__ A, const short* __restrict__ Bt,
        const float* __restrict__ bias, const float* __restrict__ res,
        float* __restrict__ C, short* __restrict__ Cb,
        int M, int N, int K) {
    __shared__ char As[2][16384];   // [128 rows][128B], XOR-swizzled
    __shared__ char Bs[2][8192];    // [64 rows][128B]
    int tid = threadIdx.x, lane = tid & 63, w = tid >> 6;

    int orig = blockIdx.y * gridDim.x + blockIdx.x;
    int cpx = (gridDim.x * gridDim.y) >> 3;
    int wgid = (orig & 7) * cpx + (orig >> 3);
    int m0 = (wgid / gridDim.x) * 128;
    int n0 = (wgid % gridDim.x) * 64;

    const size_t Kb = (size_t)K * 2;
    int rowA[4], cbA[4], rowB[2], cbB[2];
    #pragma unroll
    for (int i = 0; i < 4; ++i) {
        int o = (w * 4 + i) * 1024 + lane * 16;
        rowA[i] = o >> 7;
        cbA[i] = (o & 127) ^ ((rowA[i] & 7) << 4);
    }
    #pragma unroll
    for (int i = 0; i < 2; ++i) {
        int o = (w * 2 + i) * 1024 + lane * 16;
        rowB[i] = o >> 7;
        cbB[i] = (o & 127) ^ ((rowB[i] & 7) << 4);
    }

    #define STAGE_S(buf, kt) do {                                              \
        _Pragma("unroll")                                                      \
        for (int i_ = 0; i_ < 4; ++i_) {                                       \
            const char* ga_ = (const char*)A + (size_t)(m0 + rowA[i_]) * Kb    \
                              + (size_t)(kt) * 2 + cbA[i_];                    \
            __builtin_amdgcn_global_load_lds(                                  \
                (const __attribute__((address_space(1))) void*)ga_,            \
                (__attribute__((address_space(3))) void*)(As[buf] + (w * 4 + i_) * 1024),\
                16, 0, 0);                                                     \
        }                                                                      \
        _Pragma("unroll")                                                      \
        for (int i_ = 0; i_ < 2; ++i_) {                                       \
            const char* gb_ = (const char*)Bt + (size_t)(n0 + rowB[i_]) * Kb   \
                              + (size_t)(kt) * 2 + cbB[i_];                    \
            __builtin_amdgcn_global_load_lds(                                  \
                (const __attribute__((address_space(1))) void*)gb_,            \
                (__attribute__((address_space(3))) void*)(Bs[buf] + (w * 2 + i_) * 1024),\
                16, 0, 0);                                                     \
        }                                                                      \
    } while (0)

    f32x4 acc[2][4] = {};
    int nt = K >> 6;
    STAGE_S(0, 0);
    for (int t = 0; t < nt; ++t) {
        int cur = t & 1;
        if (t + 1 < nt) {
            STAGE_S(cur ^ 1, (t + 1) * 64);
            asm volatile("s_waitcnt vmcnt(6)" ::: "memory");
        } else {
            asm volatile("s_waitcnt vmcnt(0)" ::: "memory");
        }
        __builtin_amdgcn_s_barrier();
        __builtin_amdgcn_s_setprio(1);
        #pragma unroll
        for (int kk = 0; kk < 2; ++kk) {
            int kbyte = kk * 64 + (lane >> 4) * 16;
            bf16x8 bf[4], af[2];
            #pragma unroll
            for (int ni = 0; ni < 4; ++ni) {
                int row = ni * 16 + (lane & 15);
                bf[ni] = *(const bf16x8*)(Bs[cur] + row * 128 + (kbyte ^ ((row & 7) << 4)));
            }
            #pragma unroll
            for (int mi = 0; mi < 2; ++mi) {
                int row = w * 32 + mi * 16 + (lane & 15);
                af[mi] = *(const bf16x8*)(As[cur] + row * 128 + (kbyte ^ ((row & 7) << 4)));
            }
            #pragma unroll
            for (int mi = 0; mi < 2; ++mi)
                #pragma unroll
                for (int ni = 0; ni < 4; ++ni)
                    acc[mi][ni] = __builtin_amdgcn_mfma_f32_16x16x32_bf16(
                        af[mi], bf[ni], acc[mi][ni], 0, 0, 0);
        }
        __builtin_amdgcn_s_setprio(0);
        __builtin_amdgcn_s_barrier();
    }
    #undef STAGE_S

    #pragma unroll
    for (int mi = 0; mi < 2; ++mi) {
        #pragma unroll
        for (int j = 0; j < 4; ++j) {
            int row = m0 + w * 32 + mi * 16 + (lane >> 4) * 4 + j;
            #pragma unroll
            for (int ni = 0; ni < 4; ++ni) {
                int col = n0 + ni * 16 + (lane & 15);
                float vv = acc[mi][ni][j];
                if (BIAS) vv += bias[col];
                if (RES)  vv += res[(size_t)row * N + col];
                if (RELU) vv = fmaxf(vv, 0.0f);
                if (BF16OUT) Cb[(size_t)row * N + col] = f2bf(vv);
                else         C[(size_t)row * N + col] = vv;
            }
        }
    }
}

// ============ 256x256 coarse-dbuf MFMA GEMM (FFN1) =========================
template<bool BIAS, bool RELU, bool BF16OUT>
__global__ __launch_bounds__(512, 2) void gemm256_2p(
        const short* __restrict__ A, const short* __restrict__ Bt,
        const float* __restrict__ bias,
        float* __restrict__ C, short* __restrict__ Cb,
        int M, int N, int K) {
    __shared__ char As[2][32768];   // [256 rows][128B], XOR-swizzled
    __shared__ char Bs[2][32768];
    int tid = threadIdx.x, lane = tid & 63, w = tid >> 6;
    int wr = w >> 2, wc = w & 3;

    int nwg = gridDim.x * gridDim.y;
    int orig = blockIdx.y * gridDim.x + blockIdx.x;
    int cpx = nwg >> 3;
    int wgid = (orig & 7) * cpx + (orig >> 3);
    int m0 = (wgid / gridDim.x) * 256;
    int n0 = (wgid % gridDim.x) * 256;

    const size_t Kb = (size_t)K * 2;
    int rowS[4], cbS[4];
    #pragma unroll
    for (int i = 0; i < 4; ++i) {
        int o = (i * 8 + w) * 1024 + lane * 16;
        rowS[i] = o >> 7;                               // 0..255
        cbS[i] = (o & 127) ^ ((rowS[i] & 7) << 4);
    }

    #define STAGE_256(buf, kt) do {                                           \
        _Pragma("unroll")                                                     \
        for (int i_ = 0; i_ < 4; ++i_) {                                      \
            int c_ = i_ * 8 + w;                                              \
            const char* ga_ = (const char*)A + (size_t)(m0 + rowS[i_]) * Kb   \
                              + (size_t)(kt) * 2 + cbS[i_];                   \
            __builtin_amdgcn_global_load_lds(                                 \
                (const __attribute__((address_space(1))) void*)ga_,           \
                (__attribute__((address_space(3))) void*)(As[buf] + c_ * 1024),\
                16, 0, 0);                                                    \
            const char* gb_ = (const char*)Bt + (size_t)(n0 + rowS[i_]) * Kb  \
                              + (size_t)(kt) * 2 + cbS[i_];                   \
            __builtin_amdgcn_global_load_lds(                                 \
                (const __attribute__((address_space(1))) void*)gb_,           \
                (__attribute__((address_space(3))) void*)(Bs[buf] + c_ * 1024),\
                16, 0, 0);                                                    \
        }                                                                     \
    } while (0)

    f32x4 acc[8][4] = {};
    int nt = K >> 6;
    STAGE_256(0, 0);
    for (int t = 0; t < nt; ++t) {
        int cur = t & 1;
        if (t + 1 < nt) {
            STAGE_256(cur ^ 1, (t + 1) * 64);
            asm volatile("s_waitcnt vmcnt(8)" ::: "memory");
        } else {
            asm volatile("s_waitcnt vmcnt(0)" ::: "memory");
        }
        __builtin_amdgcn_s_barrier();
        __builtin_amdgcn_s_setprio(1);
        #pragma unroll
        for (int kk = 0; kk < 2; ++kk) {
            int kbyte = kk * 64 + (lane >> 4) * 16;
            bf16x8 bfr[4];
            #pragma unroll
            for (int ni = 0; ni < 4; ++ni) {
                int row = wc * 64 + ni * 16 + (lane & 15);
                bfr[ni] = *(const bf16x8*)(Bs[cur] + row * 128 + (kbyte ^ ((row & 7) << 4)));
            }
            #pragma unroll
            for (int mi = 0; mi < 8; ++mi) {
                int row = wr * 128 + mi * 16 + (lane & 15);
                bf16x8 afr = *(const bf16x8*)(As[cur] + row * 128 + (kbyte ^ ((row & 7) << 4)));
                #pragma unroll
                for (int ni = 0; ni < 4; ++ni)
                    acc[mi][ni] = __builtin_amdgcn_mfma_f32_16x16x32_bf16(
                        afr, bfr[ni], acc[mi][ni], 0, 0, 0);
            }
        }
        __builtin_amdgcn_s_setprio(0);
        __builtin_amdgcn_s_barrier();
    }
    #undef STAGE_256

    #pragma unroll
    for (int mi = 0; mi < 8; ++mi) {
        #pragma unroll
        for (int j = 0; j < 4; ++j) {
            int row = m0 + wr * 128 + mi * 16 + (lane >> 4) * 4 + j;
            #pragma unroll
            for (int ni = 0; ni < 4; ++ni) {
                int col = n0 + wc * 64 + ni * 16 + (lane & 15);
                float vv = acc[mi][ni][j];
                if (BIAS) vv += bias[col];
                if (RELU) vv = fmaxf(vv, 0.0f);
                if (BF16OUT) Cb[(size_t)row * N + col] = f2bf(vv);
                else         C[(size_t)row * N + col] = vv;
            }
        }
    }
}

// ---------------- pass 1: per-key column sums (NO max tracking) ------------
// XCD-swizzled so all blocks of one bh land on one XCD (KV L2-resident).
__global__ __launch_bounds__(256) void attn_pass1_mfma(
        const short* __restrict__ qg, const short* __restrict__ kg,
        float* __restrict__ lpart) {
    int orig = (blockIdx.z * 4 + blockIdx.y) * 16 + blockIdx.x;   // 2048 blocks
    int wgid = (orig & 7) * 256 + (orig >> 3);
    int kt = wgid & 15;          // 128-key tile, 0..15
    int chunk = (wgid >> 4) & 3; // 0..3
    int bh = wgid >> 6;          // XCD c owns bh in [4c, 4c+4)
    int tid = threadIdx.x, lane = tid & 63, w = tid >> 6;
    __shared__ char Qs[8192];
    const size_t base = (size_t)bh * T_ * HS_;
    int kb0 = kt * 128;
    bf16x8 af[2][2];
    #pragma unroll
    for (int s2 = 0; s2 < 2; ++s2) {
        const short* kr = kg + base
            + (size_t)(kb0 + s2 * 64 + w * 16 + (lane & 15)) * HS_ + (lane >> 4) * 8;
        af[s2][0] = *(const bf16x8*)kr;
        af[s2][1] = *(const bf16x8*)(kr + 32);
    }
    int baseT = kt * 2;
    int R = 32 - baseT;
    int cnt = (R + 3) >> 2;
    int qs = baseT + chunk * cnt;
    int qe = qs + cnt; if (qe > 32) qe = 32;
    float psum[2][4] = {};
    for (int qt = qs; qt < qe; ++qt) {
        __syncthreads();
        #pragma unroll
        for (int it = 0; it < 2; ++it) {
            int o = it * 4096 + w * 1024 + lane * 16;
            int row = o >> 7;
            int col = (o & 127) ^ ((row & 7) << 4);
            const char* src = (const char*)(qg + base + (size_t)(qt * 64 + row) * HS_) + col;
            __builtin_amdgcn_global_load_lds(
                (const __attribute__((address_space(1))) void*)src,
                (__attribute__((address_space(3))) void*)(Qs + it * 4096 + w * 1024), 16, 0, 0);
        }
        __syncthreads();
        #pragma unroll
        for (int sub = 0; sub < 4; ++sub) {
            int qrow = sub * 16 + (lane & 15);
            bf16x8 bq[2];
            #pragma unroll
            for (int kk = 0; kk < 2; ++kk) {
                int off = (kk * 64 + (lane >> 4) * 16) ^ ((qrow & 7) << 4);
                bq[kk] = *(const bf16x8*)(Qs + qrow * 128 + off);
            }
            int qglob = qt * 64 + qrow;
            #pragma unroll
            for (int s2 = 0; s2 < 2; ++s2) {
                f32x4 c = {0.f, 0.f, 0.f, 0.f};
                c = __builtin_amdgcn_mfma_f32_16x16x32_bf16(af[s2][0], bq[0], c, 0, 0, 0);
                c = __builtin_amdgcn_mfma_f32_16x16x32_bf16(af[s2][1], bq[1], c, 0, 0, 0);
                #pragma unroll
                for (int j = 0; j < 4; ++j) {
                    int kglob = kb0 + s2 * 64 + w * 16 + (lane >> 4) * 4 + j;
                    float pe = exp2f(c[j] * C2_);
                    psum[s2][j] += (qglob >= kglob) ? pe : 0.0f;
                }
            }
        }
    }
    #pragma unroll
    for (int s2 = 0; s2 < 2; ++s2)
        #pragma unroll
        for (int j = 0; j < 4; ++j) {
            float v = psum[s2][j];
            v += __shfl_xor(v, 1); v += __shfl_xor(v, 2);
            v += __shfl_xor(v, 4); v += __shfl_xor(v, 8);
            psum[s2][j] = v;
        }
    if ((lane & 15) == 0) {
        #pragma unroll
        for (int s2 = 0; s2 < 2; ++s2)
            #pragma unroll
            for (int j = 0; j < 4; ++j)
                lpart[((size_t)chunk * 32 + bh) * T_
                      + kb0 + s2 * 64 + w * 16 + (lane >> 4) * 4 + j] = psum[s2][j];
    }
}

// ---------------- reduce partials -> NEGATIVE LOG2 of column sum -----------
__global__ __launch_bounds__(256) void lreduce(const float* __restrict__ lpart,
        float* __restrict__ rl) {
    int i = blockIdx.x * 256 + threadIdx.x;   // i < 32*2048
    const int S = 32 * T_;
    float s = lpart[i] + lpart[S + i] + lpart[2 * S + i] + lpart[3 * S + i];
    rl[i] = -log2f(s);
}

// ---------------- pass 2: O = sum_k exp2(t + lg_k) * V[k] ------------------
// Triangle-paired halves, counted-vmcnt dbuf, rl in LDS, plus XCD swizzle so
// the 16 pair-blocks of each bh share one XCD's L2 (KV fetched once/XCD).
__global__ __launch_bounds__(256) void attn_pass2_mfma(
        const short* __restrict__ qg, const short* __restrict__ kg,
        const short* __restrict__ vt, const float* __restrict__ rl,
        short* __restrict__ attnb) {
    int orig = blockIdx.y * 16 + blockIdx.x;      // 512 blocks
    int wgid = (orig & 7) * 64 + (orig >> 3);
    int pair = wgid & 15;
    int bh = wgid >> 4;                           // XCD c owns bh in [4c, 4c+4)
    int bb = bh >> 4, hh = bh & 15;
    int tid = threadIdx.x, lane = tid & 63, w = tid >> 6;   // 4 waves
    __shared__ char Kb[2][8192];    // [64 keys][128B], swizzled
    __shared__ char Vb[2][8192];    // [64 e][128B = 64 keys], swizzled
    __shared__ char Ps[8192];       // [64 q][128B], wave-private rows
    __shared__ float rlAll[2048];   // full -log2(l) row for this bh (8KB)
    const size_t qkbase = (size_t)bh * T_ * HS_;
    const size_t vtbase = (size_t)bh * HS_ * T_;

    // preload rl once (2048 floats; 256 threads x 2 float4)
    {
        const float4* rp = (const float4*)(rl + (size_t)bh * T_);
        #pragma unroll
        for (int i = 0; i < 2; ++i)
            *(float4*)&rlAll[(tid * 2 + i) * 4] = rp[tid * 2 + i];
    }
    __syncthreads();

    #pragma unroll 1
    for (int half = 0; half < 2; ++half) {
        int qtile = half == 0 ? pair : 31 - pair;
        int q0 = qtile * 64 + w * 16;
        bf16x8 aq[2];
        {
            const short* qr = qg + qkbase + (size_t)(q0 + (lane & 15)) * HS_ + (lane >> 4) * 8;
            aq[0] = *(const bf16x8*)qr;
            aq[1] = *(const bf16x8*)(qr + 32);
        }
        f32x4 oacc[4] = {};
        int nstep = qtile + 1;   // 64-key steps

        // stage = EXACTLY 4 global_load_lds per thread (2 K + 2 V)
        #define STAGE64(bufi, stepi) do {                                         \
            int k0_ = (stepi) * 64;                                               \
            _Pragma("unroll")                                                     \
            for (int i_ = 0; i_ < 2; ++i_) {                                      \
                int c_ = w * 2 + i_;                                              \
                int o_ = c_ * 1024 + lane * 16;                                   \
                int row_ = o_ >> 7;                                               \
                int col_ = (o_ & 127) ^ ((row_ & 7) << 4);                        \
                const char* srcK_ = (const char*)(kg + qkbase                     \
                    + (size_t)(k0_ + row_) * HS_) + col_;                         \
                __builtin_amdgcn_global_load_lds(                                 \
                    (const __attribute__((address_space(1))) void*)srcK_,         \
                    (__attribute__((address_space(3))) void*)(Kb[bufi] + c_ * 1024), \
                    16, 0, 0);                                                    \
                const char* srcV_ = (const char*)(vt + vtbase                     \
                    + (size_t)row_ * T_ + k0_) + col_;                            \
                __builtin_amdgcn_global_load_lds(                                 \
                    (const __attribute__((address_space(1))) void*)srcV_,         \
                    (__attribute__((address_space(3))) void*)(Vb[bufi] + c_ * 1024), \
                    16, 0, 0);                                                    \
            }                                                                     \
        } while (0)

        STAGE64(0, 0);
        for (int st = 0; st < nstep; ++st) {
            int cur = st & 1;
            if (st + 1 < nstep) {
                STAGE64(cur ^ 1, st + 1);
                asm volatile("s_waitcnt vmcnt(4)" ::: "memory");   // cur resident
            } else {
                asm volatile("s_waitcnt vmcnt(0)" ::: "memory");
            }
            __builtin_amdgcn_s_barrier();
            int kbase = st * 64;
            bool diag = (st == qtile);
            int qgl = q0 + (lane & 15);
            int ql = w * 16 + (lane & 15);
            int swz = (ql & 7) << 4;
            #pragma unroll
            for (int sub = 0; sub < 4; ++sub) {
                int krow = sub * 16 + (lane & 15);
                f32x4 c = {0.f, 0.f, 0.f, 0.f};
                #pragma unroll
                for (int kk = 0; kk < 2; ++kk) {
                    int off = (kk * 64 + (lane >> 4) * 16) ^ ((krow & 7) << 4);
                    bf16x8 bk = *(const bf16x8*)(Kb[cur] + krow * 128 + off);
                    // SWAPPED: A = K fragment, B = Q fragment -> c = S^T
                    c = __builtin_amdgcn_mfma_f32_16x16x32_bf16(bk, aq[kk], c, 0, 0, 0);
                }
                int kloc0 = sub * 16 + (lane >> 4) * 4;
                f32x4 lg4 = *(const f32x4*)&rlAll[kbase + kloc0];
                float wv[4];
                #pragma unroll
                for (int j = 0; j < 4; ++j) {
                    float t = exp2f(fmaf(c[j], C2_, lg4[j]));
                    int keyg = kbase + kloc0 + j;
                    wv[j] = (diag && qgl < keyg) ? 0.0f : t;
                }
                unsigned p01, p23;
                asm("v_cvt_pk_bf16_f32 %0, %1, %2" : "=v"(p01) : "v"(wv[0]), "v"(wv[1]));
                asm("v_cvt_pk_bf16_f32 %0, %1, %2" : "=v"(p23) : "v"(wv[2]), "v"(wv[3]));
                *(unsigned*)(Ps + ql * 128 + ((kloc0 * 2) ^ swz)) = p01;
                *(unsigned*)(Ps + ql * 128 + ((kloc0 * 2 + 4) ^ swz)) = p23;
            }
            bf16x8 ap[2];
            #pragma unroll
            for (int kk = 0; kk < 2; ++kk) {
                int off = (kk * 64 + (lane >> 4) * 16) ^ swz;
                ap[kk] = *(const bf16x8*)(Ps + ql * 128 + off);
            }
            #pragma unroll
            for (int es = 0; es < 4; ++es) {
                int erow = es * 16 + (lane & 15);
                #pragma unroll
                for (int kk = 0; kk < 2; ++kk) {
                    int vcol = (kk * 64 + (lane >> 4) * 16) ^ ((erow & 7) << 4);
                    bf16x8 bv = *(const bf16x8*)(Vb[cur] + erow * 128 + vcol);
                    oacc[es] = __builtin_amdgcn_mfma_f32_16x16x32_bf16(
                        ap[kk], bv, oacc[es], 0, 0, 0);
                }
            }
            __builtin_amdgcn_s_barrier();   // all waves done reading buf[cur]
        }
        #undef STAGE64
        #pragma unroll
        for (int es = 0; es < 4; ++es) {
            #pragma unroll
            for (int j = 0; j < 4; ++j) {
                int qgl = q0 + (lane >> 4) * 4 + j;
                int e = es * 16 + (lane & 15);
                attnb[((size_t)(bb * T_ + qgl)) * D_ + hh * HS_ + e] = f2bf(oacc[es][j]);
            }
        }
        // trailing s_barrier of the last step protects LDS before next half
    }
}

extern "C" void kernel_launch(void* const* d_in, const int* in_sizes, int n_in,
                              void* d_out, int out_size, void* d_ws, size_t ws_size,
                              hipStream_t stream) {
    const float* x     = (const float*)d_in[0];
    const float* Wq    = (const float*)d_in[1];
    const float* Wk    = (const float*)d_in[2];
    const float* Wv    = (const float*)d_in[3];
    const float* Wproj = (const float*)d_in[4];
    const float* bproj = (const float*)d_in[5];
    const float* W1    = (const float*)d_in[6];
    const float* b1    = (const float*)d_in[7];
    const float* W2    = (const float*)d_in[8];
    const float* b2    = (const float*)d_in[9];
    const float* ln1g  = (const float*)d_in[10];
    const float* ln1b  = (const float*)d_in[11];
    const float* ln2g  = (const float*)d_in[12];
    const float* ln2b  = (const float*)d_in[13];
    float* out = (float*)d_out;

    const size_t MB = 1u << 20;
    char* ws = (char*)d_ws;
    float* xn    = (float*)(ws + 0 * MB);     // 16MB
    short* xnb   = (short*)(ws + 16 * MB);    // 8MB
    short* qbh   = (short*)(ws + 24 * MB);    // 8MB  [bh][T][HS] bf16
    short* kbh   = (short*)(ws + 32 * MB);    // 8MB  [bh][T][HS] bf16
    short* vtb   = (short*)(ws + 40 * MB);    // 8MB  [bh][HS][T] bf16 (transposed)
    short* attnb = (short*)(ws + 48 * MB);    // 8MB
    float* x1    = (float*)(ws + 56 * MB);    // 16MB
    float* x1n   = (float*)(ws + 72 * MB);    // 16MB
    short* x1nb  = (short*)(ws + 88 * MB);    // 8MB
    short* hb    = (short*)(ws + 96 * MB);    // 32MB
    short* wqkv  = (short*)(ws + 128 * MB);   // 6MB  [3072][1024]
    short* wprjt = (short*)(ws + 134 * MB);   // 2MB  [1024][1024]
    short* w1t   = (short*)(ws + 136 * MB);   // 8MB  [4096][1024]
    short* w2t   = (short*)(ws + 144 * MB);   // 8MB  [1024][4096]
    float* lpart = (float*)(ws + 152 * MB);   // 1MB  [4][32][2048]
    float* rl    = (float*)(ws + 153 * MB);   // 256KB [32][2048]
    // Split-K partials: CONTIGUOUS 32MB (xn + xnb/qbh regions, dead by FFN2)
    float* partP = (float*)(ws + 0 * MB);
    float* part0 = (float*)(ws + 0 * MB);
    float* part1 = (float*)(ws + 16 * MB);

    // 0. weight transpose+convert
    transpose_cvt<<<dim3(2, 32, 16), 256, 0, stream>>>(Wq, wqkv + (size_t)0 * 1048576, 1024, 64);
    transpose_cvt<<<dim3(2, 32, 16), 256, 0, stream>>>(Wk, wqkv + (size_t)1 * 1048576, 1024, 64);
    transpose_cvt<<<dim3(2, 32, 16), 256, 0, stream>>>(Wv, wqkv + (size_t)2 * 1048576, 1024, 64);
    transpose_cvt<<<dim3(32, 32, 1), 256, 0, stream>>>(Wproj, wprjt, 1024, 1024);
    transpose_cvt<<<dim3(128, 32, 1), 256, 0, stream>>>(W1, w1t, 1024, 4096);
    transpose_cvt<<<dim3(32, 128, 1), 256, 0, stream>>>(W2, w2t, 4096, 1024);

    // 1. LN1 -> xn (fp32) + xnb (bf16)
    ln_kernel<<<dim3(BT_), 256, 0, stream>>>(x, ln1g, ln1b, xn, xnb);
    // 2. QKV fused GEMM (128x64, 1536 blocks) -> q,k bf16; v bf16 transposed
    gemm_qkv<<<dim3(48, 32), 256, 0, stream>>>(
        xnb, wqkv, qbh, kbh, vtb, BT_, 3072, 1024);
    // 3. column sums (no max): partials then -log2 (XCD-swizzled)
    attn_pass1_mfma<<<dim3(16, 4, 32), 256, 0, stream>>>(qbh, kbh, lpart);
    lreduce<<<dim3(32 * T_ / 256), 256, 0, stream>>>(lpart, rl);
    // 4. attention output (MFMA, paired halves, counted-vmcnt dbuf, XCD swz)
    attn_pass2_mfma<<<dim3(16, 32), 256, 0, stream>>>(qbh, kbh, vtb, rl, attnb);
    // 5. proj + bias + residual(xn) -> x1  (128x64, 512 blocks)
    gemm_12864<true, true, false, false><<<dim3(16, 32), 256, 0, stream>>>(
        attnb, wprjt, bproj, xn, x1, nullptr, BT_, 1024, 1024);
    // 6. LN2 -> x1n + x1nb
    ln_kernel<<<dim3(BT_), 256, 0, stream>>>(x1, ln2g, ln2b, x1n, x1nb);
    // 7. FFN1: relu(x1n @ W1 + b1) -> hb (bf16)  (256x256 coarse-dbuf)
    gemm256_2p<true, true, true><<<dim3(16, 16), 512, 0, stream>>>(
        x1nb, w1t, b1, nullptr, hb, BT_, 4096, 1024);
    // 8. FFN2 split-K=2: contiguous partials at ws+0 / ws+16MB
    gemm128_sk<<<dim3(8, 32, 2), 256, 0, stream>>>(
        hb, w2t, partP, BT_, 1024, 2048, 4096);
    // 9. out = part0 + part1 + b2 + x1n
    addreduce<<<dim3(BT_ * D_ / 4 / 256), 256, 0, stream>>>(
        part0, part1, b2, x1n, out);
    (void)in_sizes; (void)n_in; (void)out_size; (void)ws_size;
}

// Round 20
// 278.427 us; speedup vs baseline: 1.1699x; 1.0058x over previous
//
#include <hip/hip_runtime.h>
#include <math.h>

#define B_ 2
#define T_ 2048
#define D_ 1024
#define H_ 16
#define HS_ 64
#define BT_ (B_*T_)
#define EPS_ 1e-5f
#define SCALE_ 0.03125f  // D^-0.5 = 1/32
#define C2_ (0.03125f * 1.44269504088896f)   // SCALE * log2(e)

typedef __attribute__((ext_vector_type(4))) float f32x4;
typedef __attribute__((ext_vector_type(8))) __bf16 bf16x8;

__device__ __forceinline__ short f2bf(float f) {
    union { float f; unsigned u; } cv; cv.f = f;
    unsigned u = cv.u;
    return (short)((u + 0x7fffu + ((u >> 16) & 1u)) >> 16);  // RTNE
}

// ---------------- LayerNorm: one block per row; fp32 + bf16 outputs --------
__global__ __launch_bounds__(256) void ln_kernel(const float* __restrict__ x,
        const float* __restrict__ g, const float* __restrict__ b,
        float* __restrict__ out, short* __restrict__ outb) {
    int row = blockIdx.x;
    int tid = threadIdx.x;
    const float* xr = x + (size_t)row * D_;
    float4 v = *(const float4*)(xr + tid * 4);
    __shared__ float red[256];
    red[tid] = v.x + v.y + v.z + v.w;
    __syncthreads();
    for (int st = 128; st > 0; st >>= 1) {
        if (tid < st) red[tid] += red[tid + st];
        __syncthreads();
    }
    float mean = red[0] * (1.0f / D_);
    __syncthreads();
    float dx = v.x - mean, dy = v.y - mean, dz = v.z - mean, dw = v.w - mean;
    red[tid] = dx*dx + dy*dy + dz*dz + dw*dw;
    __syncthreads();
    for (int st = 128; st > 0; st >>= 1) {
        if (tid < st) red[tid] += red[tid + st];
        __syncthreads();
    }
    float rstd = rsqrtf(red[0] * (1.0f / D_) + EPS_);
    float4 gv = *(const float4*)(g + tid * 4);
    float4 bv = *(const float4*)(b + tid * 4);
    float4 o;
    o.x = dx * rstd * gv.x + bv.x;
    o.y = dy * rstd * gv.y + bv.y;
    o.z = dz * rstd * gv.z + bv.z;
    o.w = dw * rstd * gv.w + bv.w;
    *(float4*)(out + (size_t)row * D_ + tid * 4) = o;
    short4 ob = make_short4(f2bf(o.x), f2bf(o.y), f2bf(o.z), f2bf(o.w));
    *(short4*)(outb + (size_t)row * D_ + tid * 4) = ob;
}

// ---------------- fp32 [R][C] -> bf16 [C][R] transpose+convert (batched) ---
__global__ __launch_bounds__(256) void transpose_cvt(const float* __restrict__ in,
        short* __restrict__ out, int R, int C) {
    __shared__ float t[32][33];
    int c0 = blockIdx.x * 32, r0 = blockIdx.y * 32;
    const float* inb = in + (size_t)blockIdx.z * R * C;
    short* outb = out + (size_t)blockIdx.z * R * C;
    int tx = threadIdx.x & 31, ty = threadIdx.x >> 5;   // 32 x 8
    #pragma unroll
    for (int i = 0; i < 32; i += 8)
        t[ty + i][tx] = inb[(size_t)(r0 + ty + i) * C + c0 + tx];
    __syncthreads();
    #pragma unroll
    for (int i = 0; i < 32; i += 8)
        outb[(size_t)(c0 + ty + i) * R + r0 + tx] = f2bf(t[tx][ty + i]);
}

// ---------------- bf16 MFMA GEMM 128x64 (QKV) ------------------------------
__global__ __launch_bounds__(256) void gemm_qkv(
        const short* __restrict__ A, const short* __restrict__ Bt,
        short* __restrict__ qo, short* __restrict__ ko, short* __restrict__ vo,
        int M, int N, int K) {
    __shared__ char As[2][16384];   // [128 rows][128B], XOR-swizzled
    __shared__ char Bs[2][8192];    // [64 rows][128B]
    int tid = threadIdx.x, lane = tid & 63, w = tid >> 6;

    int orig = blockIdx.y * gridDim.x + blockIdx.x;
    int cpx = (gridDim.x * gridDim.y) >> 3;
    int wgid = (orig & 7) * cpx + (orig >> 3);
    int m0 = (wgid / gridDim.x) * 128;
    int n0 = (wgid % gridDim.x) * 64;

    const size_t Kb = (size_t)K * 2;
    int rowA[4], cbA[4], rowB[2], cbB[2];
    #pragma unroll
    for (int i = 0; i < 4; ++i) {
        int o = (w * 4 + i) * 1024 + lane * 16;
        rowA[i] = o >> 7;
        cbA[i] = (o & 127) ^ ((rowA[i] & 7) << 4);
    }
    #pragma unroll
    for (int i = 0; i < 2; ++i) {
        int o = (w * 2 + i) * 1024 + lane * 16;
        rowB[i] = o >> 7;
        cbB[i] = (o & 127) ^ ((rowB[i] & 7) << 4);
    }

    #define STAGE_Q(buf, kt) do {                                              \
        _Pragma("unroll")                                                      \
        for (int i_ = 0; i_ < 4; ++i_) {                                       \
            const char* ga_ = (const char*)A + (size_t)(m0 + rowA[i_]) * Kb    \
                              + (size_t)(kt) * 2 + cbA[i_];                    \
            __builtin_amdgcn_global_load_lds(                                  \
                (const __attribute__((address_space(1))) void*)ga_,            \
                (__attribute__((address_space(3))) void*)(As[buf] + (w * 4 + i_) * 1024),\
                16, 0, 0);                                                     \
        }                                                                      \
        _Pragma("unroll")                                                      \
        for (int i_ = 0; i_ < 2; ++i_) {                                       \
            const char* gb_ = (const char*)Bt + (size_t)(n0 + rowB[i_]) * Kb   \
                              + (size_t)(kt) * 2 + cbB[i_];                    \
            __builtin_amdgcn_global_load_lds(                                  \
                (const __attribute__((address_space(1))) void*)gb_,            \
                (__attribute__((address_space(3))) void*)(Bs[buf] + (w * 2 + i_) * 1024),\
                16, 0, 0);                                                     \
        }                                                                      \
    } while (0)

    f32x4 acc[2][4] = {};
    int nt = K >> 6;
    STAGE_Q(0, 0);
    for (int t = 0; t < nt; ++t) {
        int cur = t & 1;
        if (t + 1 < nt) {
            STAGE_Q(cur ^ 1, (t + 1) * 64);
            asm volatile("s_waitcnt vmcnt(6)" ::: "memory");
        } else {
            asm volatile("s_waitcnt vmcnt(0)" ::: "memory");
        }
        __builtin_amdgcn_s_barrier();
        __builtin_amdgcn_s_setprio(1);
        #pragma unroll
        for (int kk = 0; kk < 2; ++kk) {
            int kbyte = kk * 64 + (lane >> 4) * 16;
            bf16x8 bf[4], af[2];
            #pragma unroll
            for (int ni = 0; ni < 4; ++ni) {
                int row = ni * 16 + (lane & 15);
                bf[ni] = *(const bf16x8*)(Bs[cur] + row * 128 + (kbyte ^ ((row & 7) << 4)));
            }
            #pragma unroll
            for (int mi = 0; mi < 2; ++mi) {
                int row = w * 32 + mi * 16 + (lane & 15);
                af[mi] = *(const bf16x8*)(As[cur] + row * 128 + (kbyte ^ ((row & 7) << 4)));
            }
            #pragma unroll
            for (int mi = 0; mi < 2; ++mi)
                #pragma unroll
                for (int ni = 0; ni < 4; ++ni)
                    acc[mi][ni] = __builtin_amdgcn_mfma_f32_16x16x32_bf16(
                        af[mi], bf[ni], acc[mi][ni], 0, 0, 0);
        }
        __builtin_amdgcn_s_setprio(0);
        __builtin_amdgcn_s_barrier();
    }
    #undef STAGE_Q

    int sel = n0 >> 10, hh = (n0 & 1023) >> 6;
    #pragma unroll
    for (int mi = 0; mi < 2; ++mi) {
        #pragma unroll
        for (int j = 0; j < 4; ++j) {
            int row = m0 + w * 32 + mi * 16 + (lane >> 4) * 4 + j;
            int bb = row >> 11, tt = row & 2047;
            #pragma unroll
            for (int ni = 0; ni < 4; ++ni) {
                int e = ni * 16 + (lane & 15);
                short bv = f2bf(acc[mi][ni][j]);
                if (sel == 0)
                    qo[(((size_t)(bb * H_ + hh)) * T_ + tt) * HS_ + e] = bv;
                else if (sel == 1)
                    ko[(((size_t)(bb * H_ + hh)) * T_ + tt) * HS_ + e] = bv;
                else  // V stored TRANSPOSED: [bh][e][T]
                    vo[(((size_t)(bb * H_ + hh)) * HS_ + e) * T_ + tt] = bv;
            }
        }
    }
}

// ---------------- bf16 MFMA GEMM 128x128, SPLIT-K (FFN2) -------------------
__global__ __launch_bounds__(256) void gemm128_sk(
        const short* __restrict__ A, const short* __restrict__ Bt,
        float* __restrict__ P, int M, int N, int Ksl, int Ktot) {
    __shared__ char As[2][16384];
    __shared__ char Bs[2][16384];
    int tid = threadIdx.x;
    int lane = tid & 63, w = tid >> 6;
    int wr = w >> 1, wc = w & 1;

    int orig = blockIdx.y * gridDim.x + blockIdx.x;
    int cpx = (gridDim.x * gridDim.y) >> 3;
    int wgid = (orig & 7) * cpx + (orig >> 3);
    int m0 = (wgid / gridDim.x) * 128;
    int n0 = (wgid % gridDim.x) * 128;
    int k0 = blockIdx.z * Ksl;
    float* Pz = P + (size_t)blockIdx.z * M * N;

    f32x4 acc[4][4] = {};

    int rowS[4], kbS[4];
    #pragma unroll
    for (int i = 0; i < 4; ++i) {
        int o = (w * 4 + i) * 1024 + lane * 16;
        rowS[i] = o >> 7;
        kbS[i] = (o & 127) ^ ((rowS[i] & 7) << 4);
    }
    const size_t Kb = (size_t)Ktot * 2;

    #define STAGE_K(buf, kt) do {                                              \
        _Pragma("unroll")                                                      \
        for (int i_ = 0; i_ < 4; ++i_) {                                       \
            int c_ = w * 4 + i_;                                               \
            const char* ga_ = (const char*)A + (size_t)(m0 + rowS[i_]) * Kb    \
                              + (size_t)(k0 + (kt)) * 2 + kbS[i_];             \
            __builtin_amdgcn_global_load_lds(                                  \
                (const __attribute__((address_space(1))) void*)ga_,            \
                (__attribute__((address_space(3))) void*)(As[buf] + c_ * 1024),\
                16, 0, 0);                                                     \
            const char* gb_ = (const char*)Bt + (size_t)(n0 + rowS[i_]) * Kb   \
                              + (size_t)(k0 + (kt)) * 2 + kbS[i_];             \
            __builtin_amdgcn_global_load_lds(                                  \
                (const __attribute__((address_space(1))) void*)gb_,            \
                (__attribute__((address_space(3))) void*)(Bs[buf] + c_ * 1024),\
                16, 0, 0);                                                     \
        }                                                                      \
    } while (0)

    int nt = Ksl >> 6;
    STAGE_K(0, 0);
    for (int t = 0; t < nt; ++t) {
        int cur = t & 1;
        if (t + 1 < nt) {
            STAGE_K(cur ^ 1, (t + 1) * 64);
            asm volatile("s_waitcnt vmcnt(8)" ::: "memory");
        } else {
            asm volatile("s_waitcnt vmcnt(0)" ::: "memory");
        }
        __builtin_amdgcn_s_barrier();
        __builtin_amdgcn_s_setprio(1);
        #pragma unroll
        for (int kk = 0; kk < 2; ++kk) {
            int kbyte = kk * 64 + (lane >> 4) * 16;
            bf16x8 af[4], bf[4];
            #pragma unroll
            for (int mi = 0; mi < 4; ++mi) {
                int row = wr * 64 + mi * 16 + (lane & 15);
                af[mi] = *(const bf16x8*)(As[cur] + row * 128 + (kbyte ^ ((row & 7) << 4)));
            }
            #pragma unroll
            for (int ni = 0; ni < 4; ++ni) {
                int row = wc * 64 + ni * 16 + (lane & 15);
                bf[ni] = *(const bf16x8*)(Bs[cur] + row * 128 + (kbyte ^ ((row & 7) << 4)));
            }
            #pragma unroll
            for (int mi = 0; mi < 4; ++mi)
                #pragma unroll
                for (int ni = 0; ni < 4; ++ni)
                    acc[mi][ni] = __builtin_amdgcn_mfma_f32_16x16x32_bf16(
                        af[mi], bf[ni], acc[mi][ni], 0, 0, 0);
        }
        __builtin_amdgcn_s_setprio(0);
        __builtin_amdgcn_s_barrier();
    }
    #undef STAGE_K

    #pragma unroll
    for (int mi = 0; mi < 4; ++mi) {
        #pragma unroll
        for (int j = 0; j < 4; ++j) {
            int row = m0 + wr * 64 + mi * 16 + (lane >> 4) * 4 + j;
            #pragma unroll
            for (int ni = 0; ni < 4; ++ni) {
                int col = n0 + wc * 64 + ni * 16 + (lane & 15);
                Pz[(size_t)row * N + col] = acc[mi][ni][j];
            }
        }
    }
}

// ---------------- split-K reduce: out = p0 + p1 + bias + res ---------------
__global__ __launch_bounds__(256) void addreduce(const float* __restrict__ p0,
        const float* __restrict__ p1, const float* __restrict__ bias,
        const float* __restrict__ res, float* __restrict__ out) {
    int i = blockIdx.x * 256 + threadIdx.x;   // float4 index; N=1024 cols
    float4 a = ((const float4*)p0)[i];
    float4 b = ((const float4*)p1)[i];
    float4 r = ((const float4*)res)[i];
    float4 bs = ((const float4*)bias)[i & 255];
    float4 o;
    o.x = a.x + b.x + r.x + bs.x;
    o.y = a.y + b.y + r.y + bs.y;
    o.z = a.z + b.z + r.z + bs.z;
    o.w = a.w + b.w + r.w + bs.w;
    ((float4*)out)[i] = o;
}

// ---------------- bf16 MFMA GEMM 128x64 (proj) -----------------------------
template<bool BIAS, bool RES, bool RELU, bool BF16OUT>
__global__ __launch_bounds__(256) void gemm_12864(
        const short* __restrict__ A, const short* __restrict__ Bt,
        const float* __restrict__ bias, const float* __restrict__ res,
        float* __restrict__ C, short* __restrict__ Cb,
        int M, int N, int K) {
    __shared__ char As[2][16384];   // [128 rows][128B], XOR-swizzled
    __shared__ char Bs[2][8192];    // [64 rows][128B]
    int tid = threadIdx.x, lane = tid & 63, w = tid >> 6;

    int orig = blockIdx.y * gridDim.x + blockIdx.x;
    int cpx = (gridDim.x * gridDim.y) >> 3;
    int wgid = (orig & 7) * cpx + (orig >> 3);
    int m0 = (wgid / gridDim.x) * 128;
    int n0 = (wgid % gridDim.x) * 64;

    const size_t Kb = (size_t)K * 2;
    int rowA[4], cbA[4], rowB[2], cbB[2];
    #pragma unroll
    for (int i = 0; i < 4; ++i) {
        int o = (w * 4 + i) * 1024 + lane * 16;
        rowA[i] = o >> 7;
        cbA[i] = (o & 127) ^ ((rowA[i] & 7) << 4);
    }
    #pragma unroll
    for (int i = 0; i < 2; ++i) {
        int o = (w * 2 + i) * 1024 + lane * 16;
        rowB[i] = o >> 7;
        cbB[i] = (o & 127) ^ ((rowB[i] & 7) << 4);
    }

    #define STAGE_S(buf, kt) do {                                              \
        _Pragma("unroll")                                                      \
        for (int i_ = 0; i_ < 4; ++i_) {                                       \
            const char* ga_ = (const char*)A + (size_t)(m0 + rowA[i_]) * Kb    \
                              + (size_t)(kt) * 2 + cbA[i_];                    \
            __builtin_amdgcn_global_load_lds(                                  \
                (const __attribute__((address_space(1))) void*)ga_,            \
                (__attribute__((address_space(3))) void*)(As[buf] + (w * 4 + i_) * 1024),\
                16, 0, 0);                                                     \
        }                                                                      \
        _Pragma("unroll")                                                      \
        for (int i_ = 0; i_ < 2; ++i_) {                                       \
            const char* gb_ = (const char*)Bt + (size_t)(n0 + rowB[i_]) * Kb   \
                              + (size_t)(kt) * 2 + cbB[i_];                    \
            __builtin_amdgcn_global_load_lds(                                  \
                (const __attribute__((address_space(1))) void*)gb_,            \
                (__attribute__((address_space(3))) void*)(Bs[buf] + (w * 2 + i_) * 1024),\
                16, 0, 0);                                                     \
        }                                                                      \
    } while (0)

    f32x4 acc[2][4] = {};
    int nt = K >> 6;
    STAGE_S(0, 0);
    for (int t = 0; t < nt; ++t) {
        int cur = t & 1;
        if (t + 1 < nt) {
            STAGE_S(cur ^ 1, (t + 1) * 64);
            asm volatile("s_waitcnt vmcnt(6)" ::: "memory");
        } else {
            asm volatile("s_waitcnt vmcnt(0)" ::: "memory");
        }
        __builtin_amdgcn_s_barrier();
        __builtin_amdgcn_s_setprio(1);
        #pragma unroll
        for (int kk = 0; kk < 2; ++kk) {
            int kbyte = kk * 64 + (lane >> 4) * 16;
            bf16x8 bf[4], af[2];
            #pragma unroll
            for (int ni = 0; ni < 4; ++ni) {
                int row = ni * 16 + (lane & 15);
                bf[ni] = *(const bf16x8*)(Bs[cur] + row * 128 + (kbyte ^ ((row & 7) << 4)));
            }
            #pragma unroll
            for (int mi = 0; mi < 2; ++mi) {
                int row = w * 32 + mi * 16 + (lane & 15);
                af[mi] = *(const bf16x8*)(As[cur] + row * 128 + (kbyte ^ ((row & 7) << 4)));
            }
            #pragma unroll
            for (int mi = 0; mi < 2; ++mi)
                #pragma unroll
                for (int ni = 0; ni < 4; ++ni)
                    acc[mi][ni] = __builtin_amdgcn_mfma_f32_16x16x32_bf16(
                        af[mi], bf[ni], acc[mi][ni], 0, 0, 0);
        }
        __builtin_amdgcn_s_setprio(0);
        __builtin_amdgcn_s_barrier();
    }
    #undef STAGE_S

    #pragma unroll
    for (int mi = 0; mi < 2; ++mi) {
        #pragma unroll
        for (int j = 0; j < 4; ++j) {
            int row = m0 + w * 32 + mi * 16 + (lane >> 4) * 4 + j;
            #pragma unroll
            for (int ni = 0; ni < 4; ++ni) {
                int col = n0 + ni * 16 + (lane & 15);
                float vv = acc[mi][ni][j];
                if (BIAS) vv += bias[col];
                if (RES)  vv += res[(size_t)row * N + col];
                if (RELU) vv = fmaxf(vv, 0.0f);
                if (BF16OUT) Cb[(size_t)row * N + col] = f2bf(vv);
                else         C[(size_t)row * N + col] = vv;
            }
        }
    }
}

// ============ 256x256 coarse-dbuf MFMA GEMM (FFN1) =========================
template<bool BIAS, bool RELU, bool BF16OUT>
__global__ __launch_bounds__(512, 2) void gemm256_2p(
        const short* __restrict__ A, const short* __restrict__ Bt,
        const float* __restrict__ bias,
        float* __restrict__ C, short* __restrict__ Cb,
        int M, int N, int K) {
    __shared__ char As[2][32768];   // [256 rows][128B], XOR-swizzled
    __shared__ char Bs[2][32768];
    int tid = threadIdx.x, lane = tid & 63, w = tid >> 6;
    int wr = w >> 2, wc = w & 3;

    int nwg = gridDim.x * gridDim.y;
    int orig = blockIdx.y * gridDim.x + blockIdx.x;
    int cpx = nwg >> 3;
    int wgid = (orig & 7) * cpx + (orig >> 3);
    int m0 = (wgid / gridDim.x) * 256;
    int n0 = (wgid % gridDim.x) * 256;

    const size_t Kb = (size_t)K * 2;
    int rowS[4], cbS[4];
    #pragma unroll
    for (int i = 0; i < 4; ++i) {
        int o = (i * 8 + w) * 1024 + lane * 16;
        rowS[i] = o >> 7;                               // 0..255
        cbS[i] = (o & 127) ^ ((rowS[i] & 7) << 4);
    }

    #define STAGE_256(buf, kt) do {                                           \
        _Pragma("unroll")                                                     \
        for (int i_ = 0; i_ < 4; ++i_) {                                      \
            int c_ = i_ * 8 + w;                                              \
            const char* ga_ = (const char*)A + (size_t)(m0 + rowS[i_]) * Kb   \
                              + (size_t)(kt) * 2 + cbS[i_];                   \
            __builtin_amdgcn_global_load_lds(                                 \
                (const __attribute__((address_space(1))) void*)ga_,           \
                (__attribute__((address_space(3))) void*)(As[buf] + c_ * 1024),\
                16, 0, 0);                                                    \
            const char* gb_ = (const char*)Bt + (size_t)(n0 + rowS[i_]) * Kb  \
                              + (size_t)(kt) * 2 + cbS[i_];                   \
            __builtin_amdgcn_global_load_lds(                                 \
                (const __attribute__((address_space(1))) void*)gb_,           \
                (__attribute__((address_space(3))) void*)(Bs[buf] + c_ * 1024),\
                16, 0, 0);                                                    \
        }                                                                     \
    } while (0)

    f32x4 acc[8][4] = {};
    int nt = K >> 6;
    STAGE_256(0, 0);
    for (int t = 0; t < nt; ++t) {
        int cur = t & 1;
        if (t + 1 < nt) {
            STAGE_256(cur ^ 1, (t + 1) * 64);
            asm volatile("s_waitcnt vmcnt(8)" ::: "memory");
        } else {
            asm volatile("s_waitcnt vmcnt(0)" ::: "memory");
        }
        __builtin_amdgcn_s_barrier();
        __builtin_amdgcn_s_setprio(1);
        #pragma unroll
        for (int kk = 0; kk < 2; ++kk) {
            int kbyte = kk * 64 + (lane >> 4) * 16;
            bf16x8 bfr[4];
            #pragma unroll
            for (int ni = 0; ni < 4; ++ni) {
                int row = wc * 64 + ni * 16 + (lane & 15);
                bfr[ni] = *(const bf16x8*)(Bs[cur] + row * 128 + (kbyte ^ ((row & 7) << 4)));
            }
            #pragma unroll
            for (int mi = 0; mi < 8; ++mi) {
                int row = wr * 128 + mi * 16 + (lane & 15);
                bf16x8 afr = *(const bf16x8*)(As[cur] + row * 128 + (kbyte ^ ((row & 7) << 4)));
                #pragma unroll
                for (int ni = 0; ni < 4; ++ni)
                    acc[mi][ni] = __builtin_amdgcn_mfma_f32_16x16x32_bf16(
                        afr, bfr[ni], acc[mi][ni], 0, 0, 0);
            }
        }
        __builtin_amdgcn_s_setprio(0);
        __builtin_amdgcn_s_barrier();
    }
    #undef STAGE_256

    #pragma unroll
    for (int mi = 0; mi < 8; ++mi) {
        #pragma unroll
        for (int j = 0; j < 4; ++j) {
            int row = m0 + wr * 128 + mi * 16 + (lane >> 4) * 4 + j;
            #pragma unroll
            for (int ni = 0; ni < 4; ++ni) {
                int col = n0 + wc * 64 + ni * 16 + (lane & 15);
                float vv = acc[mi][ni][j];
                if (BIAS) vv += bias[col];
                if (RELU) vv = fmaxf(vv, 0.0f);
                if (BF16OUT) Cb[(size_t)row * N + col] = f2bf(vv);
                else         C[(size_t)row * N + col] = vv;
            }
        }
    }
}

// ---------------- pass 1: per-key column sums (NO max tracking) ------------
// XCD-swizzled; mask computed only on the two diagonal q-tiles.
__global__ __launch_bounds__(256) void attn_pass1_mfma(
        const short* __restrict__ qg, const short* __restrict__ kg,
        float* __restrict__ lpart) {
    int orig = (blockIdx.z * 4 + blockIdx.y) * 16 + blockIdx.x;   // 2048 blocks
    int wgid = (orig & 7) * 256 + (orig >> 3);
    int kt = wgid & 15;          // 128-key tile, 0..15
    int chunk = (wgid >> 4) & 3; // 0..3
    int bh = wgid >> 6;          // XCD c owns bh in [4c, 4c+4)
    int tid = threadIdx.x, lane = tid & 63, w = tid >> 6;
    __shared__ char Qs[8192];
    const size_t base = (size_t)bh * T_ * HS_;
    int kb0 = kt * 128;
    bf16x8 af[2][2];
    #pragma unroll
    for (int s2 = 0; s2 < 2; ++s2) {
        const short* kr = kg + base
            + (size_t)(kb0 + s2 * 64 + w * 16 + (lane & 15)) * HS_ + (lane >> 4) * 8;
        af[s2][0] = *(const bf16x8*)kr;
        af[s2][1] = *(const bf16x8*)(kr + 32);
    }
    int baseT = kt * 2;
    int R = 32 - baseT;
    int cnt = (R + 3) >> 2;
    int qs = baseT + chunk * cnt;
    int qe = qs + cnt; if (qe > 32) qe = 32;
    float psum[2][4] = {};
    for (int qt = qs; qt < qe; ++qt) {
        __syncthreads();
        #pragma unroll
        for (int it = 0; it < 2; ++it) {
            int o = it * 4096 + w * 1024 + lane * 16;
            int row = o >> 7;
            int col = (o & 127) ^ ((row & 7) << 4);
            const char* src = (const char*)(qg + base + (size_t)(qt * 64 + row) * HS_) + col;
            __builtin_amdgcn_global_load_lds(
                (const __attribute__((address_space(1))) void*)src,
                (__attribute__((address_space(3))) void*)(Qs + it * 4096 + w * 1024), 16, 0, 0);
        }
        __syncthreads();
        bool anymask = (qt < baseT + 2);   // only the 2 diagonal q-tiles
        #pragma unroll
        for (int sub = 0; sub < 4; ++sub) {
            int qrow = sub * 16 + (lane & 15);
            bf16x8 bq[2];
            #pragma unroll
            for (int kk = 0; kk < 2; ++kk) {
                int off = (kk * 64 + (lane >> 4) * 16) ^ ((qrow & 7) << 4);
                bq[kk] = *(const bf16x8*)(Qs + qrow * 128 + off);
            }
            int qglob = qt * 64 + qrow;
            #pragma unroll
            for (int s2 = 0; s2 < 2; ++s2) {
                f32x4 c = {0.f, 0.f, 0.f, 0.f};
                c = __builtin_amdgcn_mfma_f32_16x16x32_bf16(af[s2][0], bq[0], c, 0, 0, 0);
                c = __builtin_amdgcn_mfma_f32_16x16x32_bf16(af[s2][1], bq[1], c, 0, 0, 0);
                if (anymask) {
                    #pragma unroll
                    for (int j = 0; j < 4; ++j) {
                        int kglob = kb0 + s2 * 64 + w * 16 + (lane >> 4) * 4 + j;
                        float pe = exp2f(c[j] * C2_);
                        psum[s2][j] += (qglob >= kglob) ? pe : 0.0f;
                    }
                } else {
                    #pragma unroll
                    for (int j = 0; j < 4; ++j)
                        psum[s2][j] += exp2f(c[j] * C2_);
                }
            }
        }
    }
    #pragma unroll
    for (int s2 = 0; s2 < 2; ++s2)
        #pragma unroll
        for (int j = 0; j < 4; ++j) {
            float v = psum[s2][j];
            v += __shfl_xor(v, 1); v += __shfl_xor(v, 2);
            v += __shfl_xor(v, 4); v += __shfl_xor(v, 8);
            psum[s2][j] = v;
        }
    if ((lane & 15) == 0) {
        #pragma unroll
        for (int s2 = 0; s2 < 2; ++s2)
            #pragma unroll
            for (int j = 0; j < 4; ++j)
                lpart[((size_t)chunk * 32 + bh) * T_
                      + kb0 + s2 * 64 + w * 16 + (lane >> 4) * 4 + j] = psum[s2][j];
    }
}

// ---------------- reduce partials -> NEGATIVE LOG2 of column sum -----------
__global__ __launch_bounds__(256) void lreduce(const float* __restrict__ lpart,
        float* __restrict__ rl) {
    int i = blockIdx.x * 256 + threadIdx.x;   // i < 32*2048
    const int S = 32 * T_;
    float s = lpart[i] + lpart[S + i] + lpart[2 * S + i] + lpart[3 * S + i];
    rl[i] = -log2f(s);
}

// ---------------- pass 2: O = sum_k exp2(t + lg_k) * V[k] ------------------
// Paired halves, counted-vmcnt dbuf, rl in LDS, XCD swizzle, mask-split
// (uniform fast path off-diagonal), setprio on PV MFMA cluster.
__global__ __launch_bounds__(256) void attn_pass2_mfma(
        const short* __restrict__ qg, const short* __restrict__ kg,
        const short* __restrict__ vt, const float* __restrict__ rl,
        short* __restrict__ attnb) {
    int orig = blockIdx.y * 16 + blockIdx.x;      // 512 blocks
    int wgid = (orig & 7) * 64 + (orig >> 3);
    int pair = wgid & 15;
    int bh = wgid >> 4;                           // XCD c owns bh in [4c, 4c+4)
    int bb = bh >> 4, hh = bh & 15;
    int tid = threadIdx.x, lane = tid & 63, w = tid >> 6;   // 4 waves
    __shared__ char Kb[2][8192];    // [64 keys][128B], swizzled
    __shared__ char Vb[2][8192];    // [64 e][128B = 64 keys], swizzled
    __shared__ char Ps[8192];       // [64 q][128B], wave-private rows
    __shared__ float rlAll[2048];   // full -log2(l) row for this bh (8KB)
    const size_t qkbase = (size_t)bh * T_ * HS_;
    const size_t vtbase = (size_t)bh * HS_ * T_;

    // preload rl once (2048 floats; 256 threads x 2 float4)
    {
        const float4* rp = (const float4*)(rl + (size_t)bh * T_);
        #pragma unroll
        for (int i = 0; i < 2; ++i)
            *(float4*)&rlAll[(tid * 2 + i) * 4] = rp[tid * 2 + i];
    }
    __syncthreads();

    #pragma unroll 1
    for (int half = 0; half < 2; ++half) {
        int qtile = half == 0 ? pair : 31 - pair;
        int q0 = qtile * 64 + w * 16;
        bf16x8 aq[2];
        {
            const short* qr = qg + qkbase + (size_t)(q0 + (lane & 15)) * HS_ + (lane >> 4) * 8;
            aq[0] = *(const bf16x8*)qr;
            aq[1] = *(const bf16x8*)(qr + 32);
        }
        f32x4 oacc[4] = {};
        int nstep = qtile + 1;   // 64-key steps

        // stage = EXACTLY 4 global_load_lds per thread (2 K + 2 V)
        #define STAGE64(bufi, stepi) do {                                         \
            int k0_ = (stepi) * 64;                                               \
            _Pragma("unroll")                                                     \
            for (int i_ = 0; i_ < 2; ++i_) {                                      \
                int c_ = w * 2 + i_;                                              \
                int o_ = c_ * 1024 + lane * 16;                                   \
                int row_ = o_ >> 7;                                               \
                int col_ = (o_ & 127) ^ ((row_ & 7) << 4);                        \
                const char* srcK_ = (const char*)(kg + qkbase                     \
                    + (size_t)(k0_ + row_) * HS_) + col_;                         \
                __builtin_amdgcn_global_load_lds(                                 \
                    (const __attribute__((address_space(1))) void*)srcK_,         \
                    (__attribute__((address_space(3))) void*)(Kb[bufi] + c_ * 1024), \
                    16, 0, 0);                                                    \
                const char* srcV_ = (const char*)(vt + vtbase                     \
                    + (size_t)row_ * T_ + k0_) + col_;                            \
                __builtin_amdgcn_global_load_lds(                                 \
                    (const __attribute__((address_space(1))) void*)srcV_,         \
                    (__attribute__((address_space(3))) void*)(Vb[bufi] + c_ * 1024), \
                    16, 0, 0);                                                    \
            }                                                                     \
        } while (0)

        STAGE64(0, 0);
        for (int st = 0; st < nstep; ++st) {
            int cur = st & 1;
            if (st + 1 < nstep) {
                STAGE64(cur ^ 1, st + 1);
                asm volatile("s_waitcnt vmcnt(4)" ::: "memory");   // cur resident
            } else {
                asm volatile("s_waitcnt vmcnt(0)" ::: "memory");
            }
            __builtin_amdgcn_s_barrier();
            int kbase = st * 64;
            bool diag = (st == qtile);
            int qgl = q0 + (lane & 15);
            int ql = w * 16 + (lane & 15);
            int swz = (ql & 7) << 4;
            #pragma unroll
            for (int sub = 0; sub < 4; ++sub) {
                int krow = sub * 16 + (lane & 15);
                f32x4 c = {0.f, 0.f, 0.f, 0.f};
                #pragma unroll
                for (int kk = 0; kk < 2; ++kk) {
                    int off = (kk * 64 + (lane >> 4) * 16) ^ ((krow & 7) << 4);
                    bf16x8 bk = *(const bf16x8*)(Kb[cur] + krow * 128 + off);
                    // SWAPPED: A = K fragment, B = Q fragment -> c = S^T
                    c = __builtin_amdgcn_mfma_f32_16x16x32_bf16(bk, aq[kk], c, 0, 0, 0);
                }
                int kloc0 = sub * 16 + (lane >> 4) * 4;
                f32x4 lg4 = *(const f32x4*)&rlAll[kbase + kloc0];
                float wv[4];
                if (!diag) {   // uniform branch: off-diagonal fast path
                    #pragma unroll
                    for (int j = 0; j < 4; ++j)
                        wv[j] = exp2f(fmaf(c[j], C2_, lg4[j]));
                } else {
                    #pragma unroll
                    for (int j = 0; j < 4; ++j) {
                        float t = exp2f(fmaf(c[j], C2_, lg4[j]));
                        int keyg = kbase + kloc0 + j;
                        wv[j] = (qgl < keyg) ? 0.0f : t;
                    }
                }
                unsigned p01, p23;
                asm("v_cvt_pk_bf16_f32 %0, %1, %2" : "=v"(p01) : "v"(wv[0]), "v"(wv[1]));
                asm("v_cvt_pk_bf16_f32 %0, %1, %2" : "=v"(p23) : "v"(wv[2]), "v"(wv[3]));
                *(unsigned*)(Ps + ql * 128 + ((kloc0 * 2) ^ swz)) = p01;
                *(unsigned*)(Ps + ql * 128 + ((kloc0 * 2 + 4) ^ swz)) = p23;
            }
            bf16x8 ap[2];
            #pragma unroll
            for (int kk = 0; kk < 2; ++kk) {
                int off = (kk * 64 + (lane >> 4) * 16) ^ swz;
                ap[kk] = *(const bf16x8*)(Ps + ql * 128 + off);
            }
            __builtin_amdgcn_s_setprio(1);
            #pragma unroll
            for (int es = 0; es < 4; ++es) {
                int erow = es * 16 + (lane & 15);
                #pragma unroll
                for (int kk = 0; kk < 2; ++kk) {
                    int vcol = (kk * 64 + (lane >> 4) * 16) ^ ((erow & 7) << 4);
                    bf16x8 bv = *(const bf16x8*)(Vb[cur] + erow * 128 + vcol);
                    oacc[es] = __builtin_amdgcn_mfma_f32_16x16x32_bf16(
                        ap[kk], bv, oacc[es], 0, 0, 0);
                }
            }
            __builtin_amdgcn_s_setprio(0);
            __builtin_amdgcn_s_barrier();   // all waves done reading buf[cur]
        }
        #undef STAGE64
        #pragma unroll
        for (int es = 0; es < 4; ++es) {
            #pragma unroll
            for (int j = 0; j < 4; ++j) {
                int qgl = q0 + (lane >> 4) * 4 + j;
                int e = es * 16 + (lane & 15);
                attnb[((size_t)(bb * T_ + qgl)) * D_ + hh * HS_ + e] = f2bf(oacc[es][j]);
            }
        }
        // trailing s_barrier of the last step protects LDS before next half
    }
}

extern "C" void kernel_launch(void* const* d_in, const int* in_sizes, int n_in,
                              void* d_out, int out_size, void* d_ws, size_t ws_size,
                              hipStream_t stream) {
    const float* x     = (const float*)d_in[0];
    const float* Wq    = (const float*)d_in[1];
    const float* Wk    = (const float*)d_in[2];
    const float* Wv    = (const float*)d_in[3];
    const float* Wproj = (const float*)d_in[4];
    const float* bproj = (const float*)d_in[5];
    const float* W1    = (const float*)d_in[6];
    const float* b1    = (const float*)d_in[7];
    const float* W2    = (const float*)d_in[8];
    const float* b2    = (const float*)d_in[9];
    const float* ln1g  = (const float*)d_in[10];
    const float* ln1b  = (const float*)d_in[11];
    const float* ln2g  = (const float*)d_in[12];
    const float* ln2b  = (const float*)d_in[13];
    float* out = (float*)d_out;

    const size_t MB = 1u << 20;
    char* ws = (char*)d_ws;
    float* xn    = (float*)(ws + 0 * MB);     // 16MB
    short* xnb   = (short*)(ws + 16 * MB);    // 8MB
    short* qbh   = (short*)(ws + 24 * MB);    // 8MB  [bh][T][HS] bf16
    short* kbh   = (short*)(ws + 32 * MB);    // 8MB  [bh][T][HS] bf16
    short* vtb   = (short*)(ws + 40 * MB);    // 8MB  [bh][HS][T] bf16 (transposed)
    short* attnb = (short*)(ws + 48 * MB);    // 8MB
    float* x1    = (float*)(ws + 56 * MB);    // 16MB
    float* x1n   = (float*)(ws + 72 * MB);    // 16MB
    short* x1nb  = (short*)(ws + 88 * MB);    // 8MB
    short* hb    = (short*)(ws + 96 * MB);    // 32MB
    short* wqkv  = (short*)(ws + 128 * MB);   // 6MB  [3072][1024]
    short* wprjt = (short*)(ws + 134 * MB);   // 2MB  [1024][1024]
    short* w1t   = (short*)(ws + 136 * MB);   // 8MB  [4096][1024]
    short* w2t   = (short*)(ws + 144 * MB);   // 8MB  [1024][4096]
    float* lpart = (float*)(ws + 152 * MB);   // 1MB  [4][32][2048]
    float* rl    = (float*)(ws + 153 * MB);   // 256KB [32][2048]
    // Split-K partials: CONTIGUOUS 32MB (xn + xnb/qbh regions, dead by FFN2)
    float* partP = (float*)(ws + 0 * MB);
    float* part0 = (float*)(ws + 0 * MB);
    float* part1 = (float*)(ws + 16 * MB);

    // 0. weight transpose+convert
    transpose_cvt<<<dim3(2, 32, 16), 256, 0, stream>>>(Wq, wqkv + (size_t)0 * 1048576, 1024, 64);
    transpose_cvt<<<dim3(2, 32, 16), 256, 0, stream>>>(Wk, wqkv + (size_t)1 * 1048576, 1024, 64);
    transpose_cvt<<<dim3(2, 32, 16), 256, 0, stream>>>(Wv, wqkv + (size_t)2 * 1048576, 1024, 64);
    transpose_cvt<<<dim3(32, 32, 1), 256, 0, stream>>>(Wproj, wprjt, 1024, 1024);
    transpose_cvt<<<dim3(128, 32, 1), 256, 0, stream>>>(W1, w1t, 1024, 4096);
    transpose_cvt<<<dim3(32, 128, 1), 256, 0, stream>>>(W2, w2t, 4096, 1024);

    // 1. LN1 -> xn (fp32) + xnb (bf16)
    ln_kernel<<<dim3(BT_), 256, 0, stream>>>(x, ln1g, ln1b, xn, xnb);
    // 2. QKV fused GEMM (128x64, 1536 blocks) -> q,k bf16; v bf16 transposed
    gemm_qkv<<<dim3(48, 32), 256, 0, stream>>>(
        xnb, wqkv, qbh, kbh, vtb, BT_, 3072, 1024);
    // 3. column sums (no max): partials then -log2 (XCD-swizzled, mask-split)
    attn_pass1_mfma<<<dim3(16, 4, 32), 256, 0, stream>>>(qbh, kbh, lpart);
    lreduce<<<dim3(32 * T_ / 256), 256, 0, stream>>>(lpart, rl);
    // 4. attention output (paired halves, counted-vmcnt, XCD swz, mask-split)
    attn_pass2_mfma<<<dim3(16, 32), 256, 0, stream>>>(qbh, kbh, vtb, rl, attnb);
    // 5. proj + bias + residual(xn) -> x1  (128x64, 512 blocks)
    gemm_12864<true, true, false, false><<<dim3(16, 32), 256, 0, stream>>>(
        attnb, wprjt, bproj, xn, x1, nullptr, BT_, 1024, 1024);
    // 6. LN2 -> x1n + x1nb
    ln_kernel<<<dim3(BT_), 256, 0, stream>>>(x1, ln2g, ln2b, x1n, x1nb);
    // 7. FFN1: relu(x1n @ W1 + b1) -> hb (bf16)  (256x256 coarse-dbuf)
    gemm256_2p<true, true, true><<<dim3(16, 16), 512, 0, stream>>>(
        x1nb, w1t, b1, nullptr, hb, BT_, 4096, 1024);
    // 8. FFN2 split-K=2: contiguous partials at ws+0 / ws+16MB
    gemm128_sk<<<dim3(8, 32, 2), 256, 0, stream>>>(
        hb, w2t, partP, BT_, 1024, 2048, 4096);
    // 9. out = part0 + part1 + b2 + x1n
    addreduce<<<dim3(BT_ * D_ / 4 / 256), 256, 0, stream>>>(
        part0, part1, b2, x1n, out);
    (void)in_sizes; (void)n_in; (void)out_size; (void)ws_size;
}

// Round 21
// 264.401 us; speedup vs baseline: 1.2319x; 1.0530x over previous
//
#include <hip/hip_runtime.h>
#include <math.h>

#define B_ 2
#define T_ 2048
#define D_ 1024
#define H_ 16
#define HS_ 64
#define BT_ (B_*T_)
#define EPS_ 1e-5f
#define SCALE_ 0.03125f  // D^-0.5 = 1/32
#define C2_ (0.03125f * 1.44269504088896f)   // SCALE * log2(e)

typedef __attribute__((ext_vector_type(4))) float f32x4;
typedef __attribute__((ext_vector_type(8))) __bf16 bf16x8;

__device__ __forceinline__ short f2bf(float f) {
    union { float f; unsigned u; } cv; cv.f = f;
    unsigned u = cv.u;
    return (short)((u + 0x7fffu + ((u >> 16) & 1u)) >> 16);  // RTNE
}
__device__ __forceinline__ float bf2f(short s) {
    union { unsigned u; float f; } cv;
    cv.u = ((unsigned)(unsigned short)s) << 16;
    return cv.f;
}

// ---------------- LayerNorm: one block per row; bf16 output ----------------
__global__ __launch_bounds__(256) void ln_kernel(const float* __restrict__ x,
        const float* __restrict__ g, const float* __restrict__ b,
        short* __restrict__ outb) {
    int row = blockIdx.x;
    int tid = threadIdx.x;
    const float* xr = x + (size_t)row * D_;
    float4 v = *(const float4*)(xr + tid * 4);
    __shared__ float red[256];
    red[tid] = v.x + v.y + v.z + v.w;
    __syncthreads();
    for (int st = 128; st > 0; st >>= 1) {
        if (tid < st) red[tid] += red[tid + st];
        __syncthreads();
    }
    float mean = red[0] * (1.0f / D_);
    __syncthreads();
    float dx = v.x - mean, dy = v.y - mean, dz = v.z - mean, dw = v.w - mean;
    red[tid] = dx*dx + dy*dy + dz*dz + dw*dw;
    __syncthreads();
    for (int st = 128; st > 0; st >>= 1) {
        if (tid < st) red[tid] += red[tid + st];
        __syncthreads();
    }
    float rstd = rsqrtf(red[0] * (1.0f / D_) + EPS_);
    float4 gv = *(const float4*)(g + tid * 4);
    float4 bv = *(const float4*)(b + tid * 4);
    short4 ob = make_short4(
        f2bf(dx * rstd * gv.x + bv.x),
        f2bf(dy * rstd * gv.y + bv.y),
        f2bf(dz * rstd * gv.z + bv.z),
        f2bf(dw * rstd * gv.w + bv.w));
    *(short4*)(outb + (size_t)row * D_ + tid * 4) = ob;
}

// ---------------- fused weight transpose+convert (all 6 jobs) --------------
// fp32 [R][C] -> bf16 [C][R]; flat blockIdx decodes job + tile.
__global__ __launch_bounds__(256) void transpose_all(
        const float* __restrict__ Wq, const float* __restrict__ Wk,
        const float* __restrict__ Wv, const float* __restrict__ Wproj,
        const float* __restrict__ W1, const float* __restrict__ W2,
        short* __restrict__ wqkv, short* __restrict__ wprjt,
        short* __restrict__ w1t, short* __restrict__ w2t) {
    int flat = blockIdx.x;
    const float* in; short* out; int R, C, c0, r0;
    if (flat < 3072) {             // Wq/Wk/Wv: [16][1024][64] per-head, 1024 tiles each
        int job = flat >> 10, rem = flat & 1023;
        const float* src = job == 0 ? Wq : (job == 1 ? Wk : Wv);
        in  = src + (size_t)(rem >> 6) * 65536;
        out = wqkv + (size_t)job * 1048576 + (size_t)(rem >> 6) * 65536;
        R = 1024; C = 64;
        c0 = (rem & 1) * 32; r0 = ((rem >> 1) & 31) * 32;
    } else if (flat < 4096) {      // Wproj 1024x1024
        int rem = flat - 3072;
        in = Wproj; out = wprjt; R = 1024; C = 1024;
        c0 = (rem & 31) * 32; r0 = (rem >> 5) * 32;
    } else if (flat < 8192) {      // W1 1024x4096
        int rem = flat - 4096;
        in = W1; out = w1t; R = 1024; C = 4096;
        c0 = (rem & 127) * 32; r0 = (rem >> 7) * 32;
    } else {                        // W2 4096x1024
        int rem = flat - 8192;
        in = W2; out = w2t; R = 4096; C = 1024;
        c0 = (rem & 31) * 32; r0 = (rem >> 5) * 32;
    }
    __shared__ float t[32][33];
    int tx = threadIdx.x & 31, ty = threadIdx.x >> 5;
    #pragma unroll
    for (int i = 0; i < 32; i += 8)
        t[ty + i][tx] = in[(size_t)(r0 + ty + i) * C + c0 + tx];
    __syncthreads();
    #pragma unroll
    for (int i = 0; i < 32; i += 8)
        out[(size_t)(c0 + ty + i) * R + r0 + tx] = f2bf(t[tx][ty + i]);
}

// ---------------- bf16 MFMA GEMM 128x64 (QKV) ------------------------------
__global__ __launch_bounds__(256) void gemm_qkv(
        const short* __restrict__ A, const short* __restrict__ Bt,
        short* __restrict__ qo, short* __restrict__ ko, short* __restrict__ vo,
        int M, int N, int K) {
    __shared__ char As[2][16384];   // [128 rows][128B], XOR-swizzled
    __shared__ char Bs[2][8192];    // [64 rows][128B]
    int tid = threadIdx.x, lane = tid & 63, w = tid >> 6;

    int orig = blockIdx.y * gridDim.x + blockIdx.x;
    int cpx = (gridDim.x * gridDim.y) >> 3;
    int wgid = (orig & 7) * cpx + (orig >> 3);
    int m0 = (wgid / gridDim.x) * 128;
    int n0 = (wgid % gridDim.x) * 64;

    const size_t Kb = (size_t)K * 2;
    int rowA[4], cbA[4], rowB[2], cbB[2];
    #pragma unroll
    for (int i = 0; i < 4; ++i) {
        int o = (w * 4 + i) * 1024 + lane * 16;
        rowA[i] = o >> 7;
        cbA[i] = (o & 127) ^ ((rowA[i] & 7) << 4);
    }
    #pragma unroll
    for (int i = 0; i < 2; ++i) {
        int o = (w * 2 + i) * 1024 + lane * 16;
        rowB[i] = o >> 7;
        cbB[i] = (o & 127) ^ ((rowB[i] & 7) << 4);
    }

    #define STAGE_Q(buf, kt) do {                                              \
        _Pragma("unroll")                                                      \
        for (int i_ = 0; i_ < 4; ++i_) {                                       \
            const char* ga_ = (const char*)A + (size_t)(m0 + rowA[i_]) * Kb    \
                              + (size_t)(kt) * 2 + cbA[i_];                    \
            __builtin_amdgcn_global_load_lds(                                  \
                (const __attribute__((address_space(1))) void*)ga_,            \
                (__attribute__((address_space(3))) void*)(As[buf] + (w * 4 + i_) * 1024),\
                16, 0, 0);                                                     \
        }                                                                      \
        _Pragma("unroll")                                                      \
        for (int i_ = 0; i_ < 2; ++i_) {                                       \
            const char* gb_ = (const char*)Bt + (size_t)(n0 + rowB[i_]) * Kb   \
                              + (size_t)(kt) * 2 + cbB[i_];                    \
            __builtin_amdgcn_global_load_lds(                                  \
                (const __attribute__((address_space(1))) void*)gb_,            \
                (__attribute__((address_space(3))) void*)(Bs[buf] + (w * 2 + i_) * 1024),\
                16, 0, 0);                                                     \
        }                                                                      \
    } while (0)

    f32x4 acc[2][4] = {};
    int nt = K >> 6;
    STAGE_Q(0, 0);
    for (int t = 0; t < nt; ++t) {
        int cur = t & 1;
        if (t + 1 < nt) {
            STAGE_Q(cur ^ 1, (t + 1) * 64);
            asm volatile("s_waitcnt vmcnt(6)" ::: "memory");
        } else {
            asm volatile("s_waitcnt vmcnt(0)" ::: "memory");
        }
        __builtin_amdgcn_s_barrier();
        __builtin_amdgcn_s_setprio(1);
        #pragma unroll
        for (int kk = 0; kk < 2; ++kk) {
            int kbyte = kk * 64 + (lane >> 4) * 16;
            bf16x8 bf[4], af[2];
            #pragma unroll
            for (int ni = 0; ni < 4; ++ni) {
                int row = ni * 16 + (lane & 15);
                bf[ni] = *(const bf16x8*)(Bs[cur] + row * 128 + (kbyte ^ ((row & 7) << 4)));
            }
            #pragma unroll
            for (int mi = 0; mi < 2; ++mi) {
                int row = w * 32 + mi * 16 + (lane & 15);
                af[mi] = *(const bf16x8*)(As[cur] + row * 128 + (kbyte ^ ((row & 7) << 4)));
            }
            #pragma unroll
            for (int mi = 0; mi < 2; ++mi)
                #pragma unroll
                for (int ni = 0; ni < 4; ++ni)
                    acc[mi][ni] = __builtin_amdgcn_mfma_f32_16x16x32_bf16(
                        af[mi], bf[ni], acc[mi][ni], 0, 0, 0);
        }
        __builtin_amdgcn_s_setprio(0);
        __builtin_amdgcn_s_barrier();
    }
    #undef STAGE_Q

    int sel = n0 >> 10, hh = (n0 & 1023) >> 6;
    #pragma unroll
    for (int mi = 0; mi < 2; ++mi) {
        #pragma unroll
        for (int j = 0; j < 4; ++j) {
            int row = m0 + w * 32 + mi * 16 + (lane >> 4) * 4 + j;
            int bb = row >> 11, tt = row & 2047;
            #pragma unroll
            for (int ni = 0; ni < 4; ++ni) {
                int e = ni * 16 + (lane & 15);
                short bv = f2bf(acc[mi][ni][j]);
                if (sel == 0)
                    qo[(((size_t)(bb * H_ + hh)) * T_ + tt) * HS_ + e] = bv;
                else if (sel == 1)
                    ko[(((size_t)(bb * H_ + hh)) * T_ + tt) * HS_ + e] = bv;
                else  // V stored TRANSPOSED: [bh][e][T]
                    vo[(((size_t)(bb * H_ + hh)) * HS_ + e) * T_ + tt] = bv;
            }
        }
    }
}

// ---------------- bf16 MFMA GEMM 128x128, SPLIT-K (FFN2) -------------------
__global__ __launch_bounds__(256) void gemm128_sk(
        const short* __restrict__ A, const short* __restrict__ Bt,
        float* __restrict__ P, int M, int N, int Ksl, int Ktot) {
    __shared__ char As[2][16384];
    __shared__ char Bs[2][16384];
    int tid = threadIdx.x;
    int lane = tid & 63, w = tid >> 6;
    int wr = w >> 1, wc = w & 1;

    int orig = blockIdx.y * gridDim.x + blockIdx.x;
    int cpx = (gridDim.x * gridDim.y) >> 3;
    int wgid = (orig & 7) * cpx + (orig >> 3);
    int m0 = (wgid / gridDim.x) * 128;
    int n0 = (wgid % gridDim.x) * 128;
    int k0 = blockIdx.z * Ksl;
    float* Pz = P + (size_t)blockIdx.z * M * N;

    f32x4 acc[4][4] = {};

    int rowS[4], kbS[4];
    #pragma unroll
    for (int i = 0; i < 4; ++i) {
        int o = (w * 4 + i) * 1024 + lane * 16;
        rowS[i] = o >> 7;
        kbS[i] = (o & 127) ^ ((rowS[i] & 7) << 4);
    }
    const size_t Kb = (size_t)Ktot * 2;

    #define STAGE_K(buf, kt) do {                                              \
        _Pragma("unroll")                                                      \
        for (int i_ = 0; i_ < 4; ++i_) {                                       \
            int c_ = w * 4 + i_;                                               \
            const char* ga_ = (const char*)A + (size_t)(m0 + rowS[i_]) * Kb    \
                              + (size_t)(k0 + (kt)) * 2 + kbS[i_];             \
            __builtin_amdgcn_global_load_lds(                                  \
                (const __attribute__((address_space(1))) void*)ga_,            \
                (__attribute__((address_space(3))) void*)(As[buf] + c_ * 1024),\
                16, 0, 0);                                                     \
            const char* gb_ = (const char*)Bt + (size_t)(n0 + rowS[i_]) * Kb   \
                              + (size_t)(k0 + (kt)) * 2 + kbS[i_];             \
            __builtin_amdgcn_global_load_lds(                                  \
                (const __attribute__((address_space(1))) void*)gb_,            \
                (__attribute__((address_space(3))) void*)(Bs[buf] + c_ * 1024),\
                16, 0, 0);                                                     \
        }                                                                      \
    } while (0)

    int nt = Ksl >> 6;
    STAGE_K(0, 0);
    for (int t = 0; t < nt; ++t) {
        int cur = t & 1;
        if (t + 1 < nt) {
            STAGE_K(cur ^ 1, (t + 1) * 64);
            asm volatile("s_waitcnt vmcnt(8)" ::: "memory");
        } else {
            asm volatile("s_waitcnt vmcnt(0)" ::: "memory");
        }
        __builtin_amdgcn_s_barrier();
        __builtin_amdgcn_s_setprio(1);
        #pragma unroll
        for (int kk = 0; kk < 2; ++kk) {
            int kbyte = kk * 64 + (lane >> 4) * 16;
            bf16x8 af[4], bf[4];
            #pragma unroll
            for (int mi = 0; mi < 4; ++mi) {
                int row = wr * 64 + mi * 16 + (lane & 15);
                af[mi] = *(const bf16x8*)(As[cur] + row * 128 + (kbyte ^ ((row & 7) << 4)));
            }
            #pragma unroll
            for (int ni = 0; ni < 4; ++ni) {
                int row = wc * 64 + ni * 16 + (lane & 15);
                bf[ni] = *(const bf16x8*)(Bs[cur] + row * 128 + (kbyte ^ ((row & 7) << 4)));
            }
            #pragma unroll
            for (int mi = 0; mi < 4; ++mi)
                #pragma unroll
                for (int ni = 0; ni < 4; ++ni)
                    acc[mi][ni] = __builtin_amdgcn_mfma_f32_16x16x32_bf16(
                        af[mi], bf[ni], acc[mi][ni], 0, 0, 0);
        }
        __builtin_amdgcn_s_setprio(0);
        __builtin_amdgcn_s_barrier();
    }
    #undef STAGE_K

    #pragma unroll
    for (int mi = 0; mi < 4; ++mi) {
        #pragma unroll
        for (int j = 0; j < 4; ++j) {
            int row = m0 + wr * 64 + mi * 16 + (lane >> 4) * 4 + j;
            #pragma unroll
            for (int ni = 0; ni < 4; ++ni) {
                int col = n0 + wc * 64 + ni * 16 + (lane & 15);
                Pz[(size_t)row * N + col] = acc[mi][ni][j];
            }
        }
    }
}

// ---------------- split-K reduce: out = p0 + p1 + bias + bf16 res ----------
__global__ __launch_bounds__(256) void addreduce(const float* __restrict__ p0,
        const float* __restrict__ p1, const float* __restrict__ bias,
        const short* __restrict__ resb, float* __restrict__ out) {
    int i = blockIdx.x * 256 + threadIdx.x;   // float4 index; N=1024 cols
    float4 a = ((const float4*)p0)[i];
    float4 b = ((const float4*)p1)[i];
    short4 rs = ((const short4*)resb)[i];
    float4 bs = ((const float4*)bias)[i & 255];
    float4 o;
    o.x = a.x + b.x + bf2f(rs.x) + bs.x;
    o.y = a.y + b.y + bf2f(rs.y) + bs.y;
    o.z = a.z + b.z + bf2f(rs.z) + bs.z;
    o.w = a.w + b.w + bf2f(rs.w) + bs.w;
    ((float4*)out)[i] = o;
}

// ---------------- bf16 MFMA GEMM 128x64 (proj; bf16 residual) --------------
template<bool BIAS, bool RES, bool RELU, bool BF16OUT>
__global__ __launch_bounds__(256) void gemm_12864(
        const short* __restrict__ A, const short* __restrict__ Bt,
        const float* __restrict__ bias, const short* __restrict__ resb,
        float* __restrict__ C, short* __restrict__ Cb,
        int M, int N, int K) {
    __shared__ char As[2][16384];   // [128 rows][128B], XOR-swizzled
    __shared__ char Bs[2][8192];    // [64 rows][128B]
    int tid = threadIdx.x, lane = tid & 63, w = tid >> 6;

    int orig = blockIdx.y * gridDim.x + blockIdx.x;
    int cpx = (gridDim.x * gridDim.y) >> 3;
    int wgid = (orig & 7) * cpx + (orig >> 3);
    int m0 = (wgid / gridDim.x) * 128;
    int n0 = (wgid % gridDim.x) * 64;

    const size_t Kb = (size_t)K * 2;
    int rowA[4], cbA[4], rowB[2], cbB[2];
    #pragma unroll
    for (int i = 0; i < 4; ++i) {
        int o = (w * 4 + i) * 1024 + lane * 16;
        rowA[i] = o >> 7;
        cbA[i] = (o & 127) ^ ((rowA[i] & 7) << 4);
    }
    #pragma unroll
    for (int i = 0; i < 2; ++i) {
        int o = (w * 2 + i) * 1024 + lane * 16;
        rowB[i] = o >> 7;
        cbB[i] = (o & 127) ^ ((rowB[i] & 7) << 4);
    }

    #define STAGE_S(buf, kt) do {                                              \
        _Pragma("unroll")                                                      \
        for (int i_ = 0; i_ < 4; ++i_) {                                       \
            const char* ga_ = (const char*)A + (size_t)(m0 + rowA[i_]) * Kb    \
                              + (size_t)(kt) * 2 + cbA[i_];                    \
            __builtin_amdgcn_global_load_lds(                                  \
                (const __attribute__((address_space(1))) void*)ga_,            \
                (__attribute__((address_space(3))) void*)(As[buf] + (w * 4 + i_) * 1024),\
                16, 0, 0);                                                     \
        }                                                                      \
        _Pragma("unroll")                                                      \
        for (int i_ = 0; i_ < 2; ++i_) {                                       \
            const char* gb_ = (const char*)Bt + (size_t)(n0 + rowB[i_]) * Kb   \
                              + (size_t)(kt) * 2 + cbB[i_];                    \
            __builtin_amdgcn_global_load_lds(                                  \
                (const __attribute__((address_space(1))) void*)gb_,            \
                (__attribute__((address_space(3))) void*)(Bs[buf] + (w * 2 + i_) * 1024),\
                16, 0, 0);                                                     \
        }                                                                      \
    } while (0)

    f32x4 acc[2][4] = {};
    int nt = K >> 6;
    STAGE_S(0, 0);
    for (int t = 0; t < nt; ++t) {
        int cur = t & 1;
        if (t + 1 < nt) {
            STAGE_S(cur ^ 1, (t + 1) * 64);
            asm volatile("s_waitcnt vmcnt(6)" ::: "memory");
        } else {
            asm volatile("s_waitcnt vmcnt(0)" ::: "memory");
        }
        __builtin_amdgcn_s_barrier();
        __builtin_amdgcn_s_setprio(1);
        #pragma unroll
        for (int kk = 0; kk < 2; ++kk) {
            int kbyte = kk * 64 + (lane >> 4) * 16;
            bf16x8 bf[4], af[2];
            #pragma unroll
            for (int ni = 0; ni < 4; ++ni) {
                int row = ni * 16 + (lane & 15);
                bf[ni] = *(const bf16x8*)(Bs[cur] + row * 128 + (kbyte ^ ((row & 7) << 4)));
            }
            #pragma unroll
            for (int mi = 0; mi < 2; ++mi) {
                int row = w * 32 + mi * 16 + (lane & 15);
                af[mi] = *(const bf16x8*)(As[cur] + row * 128 + (kbyte ^ ((row & 7) << 4)));
            }
            #pragma unroll
            for (int mi = 0; mi < 2; ++mi)
                #pragma unroll
                for (int ni = 0; ni < 4; ++ni)
                    acc[mi][ni] = __builtin_amdgcn_mfma_f32_16x16x32_bf16(
                        af[mi], bf[ni], acc[mi][ni], 0, 0, 0);
        }
        __builtin_amdgcn_s_setprio(0);
        __builtin_amdgcn_s_barrier();
    }
    #undef STAGE_S

    #pragma unroll
    for (int mi = 0; mi < 2; ++mi) {
        #pragma unroll
        for (int j = 0; j < 4; ++j) {
            int row = m0 + w * 32 + mi * 16 + (lane >> 4) * 4 + j;
            #pragma unroll
            for (int ni = 0; ni < 4; ++ni) {
                int col = n0 + ni * 16 + (lane & 15);
                float vv = acc[mi][ni][j];
                if (BIAS) vv += bias[col];
                if (RES)  vv += bf2f(resb[(size_t)row * N + col]);
                if (RELU) vv = fmaxf(vv, 0.0f);
                if (BF16OUT) Cb[(size_t)row * N + col] = f2bf(vv);
                else         C[(size_t)row * N + col] = vv;
            }
        }
    }
}

// ============ 256x256 coarse-dbuf MFMA GEMM (FFN1) =========================
template<bool BIAS, bool RELU, bool BF16OUT>
__global__ __launch_bounds__(512, 2) void gemm256_2p(
        const short* __restrict__ A, const short* __restrict__ Bt,
        const float* __restrict__ bias,
        float* __restrict__ C, short* __restrict__ Cb,
        int M, int N, int K) {
    __shared__ char As[2][32768];   // [256 rows][128B], XOR-swizzled
    __shared__ char Bs[2][32768];
    int tid = threadIdx.x, lane = tid & 63, w = tid >> 6;
    int wr = w >> 2, wc = w & 3;

    int nwg = gridDim.x * gridDim.y;
    int orig = blockIdx.y * gridDim.x + blockIdx.x;
    int cpx = nwg >> 3;
    int wgid = (orig & 7) * cpx + (orig >> 3);
    int m0 = (wgid / gridDim.x) * 256;
    int n0 = (wgid % gridDim.x) * 256;

    const size_t Kb = (size_t)K * 2;
    int rowS[4], cbS[4];
    #pragma unroll
    for (int i = 0; i < 4; ++i) {
        int o = (i * 8 + w) * 1024 + lane * 16;
        rowS[i] = o >> 7;                               // 0..255
        cbS[i] = (o & 127) ^ ((rowS[i] & 7) << 4);
    }

    #define STAGE_256(buf, kt) do {                                           \
        _Pragma("unroll")                                                     \
        for (int i_ = 0; i_ < 4; ++i_) {                                      \
            int c_ = i_ * 8 + w;                                              \
            const char* ga_ = (const char*)A + (size_t)(m0 + rowS[i_]) * Kb   \
                              + (size_t)(kt) * 2 + cbS[i_];                   \
            __builtin_amdgcn_global_load_lds(                                 \
                (const __attribute__((address_space(1))) void*)ga_,           \
                (__attribute__((address_space(3))) void*)(As[buf] + c_ * 1024),\
                16, 0, 0);                                                    \
            const char* gb_ = (const char*)Bt + (size_t)(n0 + rowS[i_]) * Kb  \
                              + (size_t)(kt) * 2 + cbS[i_];                   \
            __builtin_amdgcn_global_load_lds(                                 \
                (const __attribute__((address_space(1))) void*)gb_,           \
                (__attribute__((address_space(3))) void*)(Bs[buf] + c_ * 1024),\
                16, 0, 0);                                                    \
        }                                                                     \
    } while (0)

    f32x4 acc[8][4] = {};
    int nt = K >> 6;
    STAGE_256(0, 0);
    for (int t = 0; t < nt; ++t) {
        int cur = t & 1;
        if (t + 1 < nt) {
            STAGE_256(cur ^ 1, (t + 1) * 64);
            asm volatile("s_waitcnt vmcnt(8)" ::: "memory");
        } else {
            asm volatile("s_waitcnt vmcnt(0)" ::: "memory");
        }
        __builtin_amdgcn_s_barrier();
        __builtin_amdgcn_s_setprio(1);
        #pragma unroll
        for (int kk = 0; kk < 2; ++kk) {
            int kbyte = kk * 64 + (lane >> 4) * 16;
            bf16x8 bfr[4];
            #pragma unroll
            for (int ni = 0; ni < 4; ++ni) {
                int row = wc * 64 + ni * 16 + (lane & 15);
                bfr[ni] = *(const bf16x8*)(Bs[cur] + row * 128 + (kbyte ^ ((row & 7) << 4)));
            }
            #pragma unroll
            for (int mi = 0; mi < 8; ++mi) {
                int row = wr * 128 + mi * 16 + (lane & 15);
                bf16x8 afr = *(const bf16x8*)(As[cur] + row * 128 + (kbyte ^ ((row & 7) << 4)));
                #pragma unroll
                for (int ni = 0; ni < 4; ++ni)
                    acc[mi][ni] = __builtin_amdgcn_mfma_f32_16x16x32_bf16(
                        afr, bfr[ni], acc[mi][ni], 0, 0, 0);
            }
        }
        __builtin_amdgcn_s_setprio(0);
        __builtin_amdgcn_s_barrier();
    }
    #undef STAGE_256

    #pragma unroll
    for (int mi = 0; mi < 8; ++mi) {
        #pragma unroll
        for (int j = 0; j < 4; ++j) {
            int row = m0 + wr * 128 + mi * 16 + (lane >> 4) * 4 + j;
            #pragma unroll
            for (int ni = 0; ni < 4; ++ni) {
                int col = n0 + wc * 64 + ni * 16 + (lane & 15);
                float vv = acc[mi][ni][j];
                if (BIAS) vv += bias[col];
                if (RELU) vv = fmaxf(vv, 0.0f);
                if (BF16OUT) Cb[(size_t)row * N + col] = f2bf(vv);
                else         C[(size_t)row * N + col] = vv;
            }
        }
    }
}

// ---------------- pass 1: per-key column sums (NO max tracking) ------------
// XCD-swizzled; mask computed only on the two diagonal q-tiles.
__global__ __launch_bounds__(256) void attn_pass1_mfma(
        const short* __restrict__ qg, const short* __restrict__ kg,
        float* __restrict__ lpart) {
    int orig = (blockIdx.z * 4 + blockIdx.y) * 16 + blockIdx.x;   // 2048 blocks
    int wgid = (orig & 7) * 256 + (orig >> 3);
    int kt = wgid & 15;          // 128-key tile, 0..15
    int chunk = (wgid >> 4) & 3; // 0..3
    int bh = wgid >> 6;          // XCD c owns bh in [4c, 4c+4)
    int tid = threadIdx.x, lane = tid & 63, w = tid >> 6;
    __shared__ char Qs[8192];
    const size_t base = (size_t)bh * T_ * HS_;
    int kb0 = kt * 128;
    bf16x8 af[2][2];
    #pragma unroll
    for (int s2 = 0; s2 < 2; ++s2) {
        const short* kr = kg + base
            + (size_t)(kb0 + s2 * 64 + w * 16 + (lane & 15)) * HS_ + (lane >> 4) * 8;
        af[s2][0] = *(const bf16x8*)kr;
        af[s2][1] = *(const bf16x8*)(kr + 32);
    }
    int baseT = kt * 2;
    int R = 32 - baseT;
    int cnt = (R + 3) >> 2;
    int qs = baseT + chunk * cnt;
    int qe = qs + cnt; if (qe > 32) qe = 32;
    float psum[2][4] = {};
    for (int qt = qs; qt < qe; ++qt) {
        __syncthreads();
        #pragma unroll
        for (int it = 0; it < 2; ++it) {
            int o = it * 4096 + w * 1024 + lane * 16;
            int row = o >> 7;
            int col = (o & 127) ^ ((row & 7) << 4);
            const char* src = (const char*)(qg + base + (size_t)(qt * 64 + row) * HS_) + col;
            __builtin_amdgcn_global_load_lds(
                (const __attribute__((address_space(1))) void*)src,
                (__attribute__((address_space(3))) void*)(Qs + it * 4096 + w * 1024), 16, 0, 0);
        }
        __syncthreads();
        bool anymask = (qt < baseT + 2);   // only the 2 diagonal q-tiles
        #pragma unroll
        for (int sub = 0; sub < 4; ++sub) {
            int qrow = sub * 16 + (lane & 15);
            bf16x8 bq[2];
            #pragma unroll
            for (int kk = 0; kk < 2; ++kk) {
                int off = (kk * 64 + (lane >> 4) * 16) ^ ((qrow & 7) << 4);
                bq[kk] = *(const bf16x8*)(Qs + qrow * 128 + off);
            }
            int qglob = qt * 64 + qrow;
            #pragma unroll
            for (int s2 = 0; s2 < 2; ++s2) {
                f32x4 c = {0.f, 0.f, 0.f, 0.f};
                c = __builtin_amdgcn_mfma_f32_16x16x32_bf16(af[s2][0], bq[0], c, 0, 0, 0);
                c = __builtin_amdgcn_mfma_f32_16x16x32_bf16(af[s2][1], bq[1], c, 0, 0, 0);
                if (anymask) {
                    #pragma unroll
                    for (int j = 0; j < 4; ++j) {
                        int kglob = kb0 + s2 * 64 + w * 16 + (lane >> 4) * 4 + j;
                        float pe = exp2f(c[j] * C2_);
                        psum[s2][j] += (qglob >= kglob) ? pe : 0.0f;
                    }
                } else {
                    #pragma unroll
                    for (int j = 0; j < 4; ++j)
                        psum[s2][j] += exp2f(c[j] * C2_);
                }
            }
        }
    }
    #pragma unroll
    for (int s2 = 0; s2 < 2; ++s2)
        #pragma unroll
        for (int j = 0; j < 4; ++j) {
            float v = psum[s2][j];
            v += __shfl_xor(v, 1); v += __shfl_xor(v, 2);
            v += __shfl_xor(v, 4); v += __shfl_xor(v, 8);
            psum[s2][j] = v;
        }
    if ((lane & 15) == 0) {
        #pragma unroll
        for (int s2 = 0; s2 < 2; ++s2)
            #pragma unroll
            for (int j = 0; j < 4; ++j)
                lpart[((size_t)chunk * 32 + bh) * T_
                      + kb0 + s2 * 64 + w * 16 + (lane >> 4) * 4 + j] = psum[s2][j];
    }
}

// ---------------- reduce partials -> NEGATIVE LOG2 of column sum -----------
__global__ __launch_bounds__(256) void lreduce(const float* __restrict__ lpart,
        float* __restrict__ rl) {
    int i = blockIdx.x * 256 + threadIdx.x;   // i < 32*2048
    const int S = 32 * T_;
    float s = lpart[i] + lpart[S + i] + lpart[2 * S + i] + lpart[3 * S + i];
    rl[i] = -log2f(s);
}

// ---------------- pass 2: O = sum_k exp2(t + lg_k) * V[k] ------------------
// Paired halves, counted-vmcnt dbuf, rl in LDS, XCD swizzle, mask-split,
// setprio on PV MFMA cluster.
__global__ __launch_bounds__(256) void attn_pass2_mfma(
        const short* __restrict__ qg, const short* __restrict__ kg,
        const short* __restrict__ vt, const float* __restrict__ rl,
        short* __restrict__ attnb) {
    int orig = blockIdx.y * 16 + blockIdx.x;      // 512 blocks
    int wgid = (orig & 7) * 64 + (orig >> 3);
    int pair = wgid & 15;
    int bh = wgid >> 4;                           // XCD c owns bh in [4c, 4c+4)
    int bb = bh >> 4, hh = bh & 15;
    int tid = threadIdx.x, lane = tid & 63, w = tid >> 6;   // 4 waves
    __shared__ char Kb[2][8192];    // [64 keys][128B], swizzled
    __shared__ char Vb[2][8192];    // [64 e][128B = 64 keys], swizzled
    __shared__ char Ps[8192];       // [64 q][128B], wave-private rows
    __shared__ float rlAll[2048];   // full -log2(l) row for this bh (8KB)
    const size_t qkbase = (size_t)bh * T_ * HS_;
    const size_t vtbase = (size_t)bh * HS_ * T_;

    // preload rl once (2048 floats; 256 threads x 2 float4)
    {
        const float4* rp = (const float4*)(rl + (size_t)bh * T_);
        #pragma unroll
        for (int i = 0; i < 2; ++i)
            *(float4*)&rlAll[(tid * 2 + i) * 4] = rp[tid * 2 + i];
    }
    __syncthreads();

    #pragma unroll 1
    for (int half = 0; half < 2; ++half) {
        int qtile = half == 0 ? pair : 31 - pair;
        int q0 = qtile * 64 + w * 16;
        bf16x8 aq[2];
        {
            const short* qr = qg + qkbase + (size_t)(q0 + (lane & 15)) * HS_ + (lane >> 4) * 8;
            aq[0] = *(const bf16x8*)qr;
            aq[1] = *(const bf16x8*)(qr + 32);
        }
        f32x4 oacc[4] = {};
        int nstep = qtile + 1;   // 64-key steps

        // stage = EXACTLY 4 global_load_lds per thread (2 K + 2 V)
        #define STAGE64(bufi, stepi) do {                                         \
            int k0_ = (stepi) * 64;                                               \
            _Pragma("unroll")                                                     \
            for (int i_ = 0; i_ < 2; ++i_) {                                      \
                int c_ = w * 2 + i_;                                              \
                int o_ = c_ * 1024 + lane * 16;                                   \
                int row_ = o_ >> 7;                                               \
                int col_ = (o_ & 127) ^ ((row_ & 7) << 4);                        \
                const char* srcK_ = (const char*)(kg + qkbase                     \
                    + (size_t)(k0_ + row_) * HS_) + col_;                         \
                __builtin_amdgcn_global_load_lds(                                 \
                    (const __attribute__((address_space(1))) void*)srcK_,         \
                    (__attribute__((address_space(3))) void*)(Kb[bufi] + c_ * 1024), \
                    16, 0, 0);                                                    \
                const char* srcV_ = (const char*)(vt + vtbase                     \
                    + (size_t)row_ * T_ + k0_) + col_;                            \
                __builtin_amdgcn_global_load_lds(                                 \
                    (const __attribute__((address_space(1))) void*)srcV_,         \
                    (__attribute__((address_space(3))) void*)(Vb[bufi] + c_ * 1024), \
                    16, 0, 0);                                                    \
            }                                                                     \
        } while (0)

        STAGE64(0, 0);
        for (int st = 0; st < nstep; ++st) {
            int cur = st & 1;
            if (st + 1 < nstep) {
                STAGE64(cur ^ 1, st + 1);
                asm volatile("s_waitcnt vmcnt(4)" ::: "memory");   // cur resident
            } else {
                asm volatile("s_waitcnt vmcnt(0)" ::: "memory");
            }
            __builtin_amdgcn_s_barrier();
            int kbase = st * 64;
            bool diag = (st == qtile);
            int qgl = q0 + (lane & 15);
            int ql = w * 16 + (lane & 15);
            int swz = (ql & 7) << 4;
            #pragma unroll
            for (int sub = 0; sub < 4; ++sub) {
                int krow = sub * 16 + (lane & 15);
                f32x4 c = {0.f, 0.f, 0.f, 0.f};
                #pragma unroll
                for (int kk = 0; kk < 2; ++kk) {
                    int off = (kk * 64 + (lane >> 4) * 16) ^ ((krow & 7) << 4);
                    bf16x8 bk = *(const bf16x8*)(Kb[cur] + krow * 128 + off);
                    // SWAPPED: A = K fragment, B = Q fragment -> c = S^T
                    c = __builtin_amdgcn_mfma_f32_16x16x32_bf16(bk, aq[kk], c, 0, 0, 0);
                }
                int kloc0 = sub * 16 + (lane >> 4) * 4;
                f32x4 lg4 = *(const f32x4*)&rlAll[kbase + kloc0];
                float wv[4];
                if (!diag) {   // uniform branch: off-diagonal fast path
                    #pragma unroll
                    for (int j = 0; j < 4; ++j)
                        wv[j] = exp2f(fmaf(c[j], C2_, lg4[j]));
                } else {
                    #pragma unroll
                    for (int j = 0; j < 4; ++j) {
                        float t = exp2f(fmaf(c[j], C2_, lg4[j]));
                        int keyg = kbase + kloc0 + j;
                        wv[j] = (qgl < keyg) ? 0.0f : t;
                    }
                }
                unsigned p01, p23;
                asm("v_cvt_pk_bf16_f32 %0, %1, %2" : "=v"(p01) : "v"(wv[0]), "v"(wv[1]));
                asm("v_cvt_pk_bf16_f32 %0, %1, %2" : "=v"(p23) : "v"(wv[2]), "v"(wv[3]));
                *(unsigned*)(Ps + ql * 128 + ((kloc0 * 2) ^ swz)) = p01;
                *(unsigned*)(Ps + ql * 128 + ((kloc0 * 2 + 4) ^ swz)) = p23;
            }
            bf16x8 ap[2];
            #pragma unroll
            for (int kk = 0; kk < 2; ++kk) {
                int off = (kk * 64 + (lane >> 4) * 16) ^ swz;
                ap[kk] = *(const bf16x8*)(Ps + ql * 128 + off);
            }
            __builtin_amdgcn_s_setprio(1);
            #pragma unroll
            for (int es = 0; es < 4; ++es) {
                int erow = es * 16 + (lane & 15);
                #pragma unroll
                for (int kk = 0; kk < 2; ++kk) {
                    int vcol = (kk * 64 + (lane >> 4) * 16) ^ ((erow & 7) << 4);
                    bf16x8 bv = *(const bf16x8*)(Vb[cur] + erow * 128 + vcol);
                    oacc[es] = __builtin_amdgcn_mfma_f32_16x16x32_bf16(
                        ap[kk], bv, oacc[es], 0, 0, 0);
                }
            }
            __builtin_amdgcn_s_setprio(0);
            __builtin_amdgcn_s_barrier();   // all waves done reading buf[cur]
        }
        #undef STAGE64
        #pragma unroll
        for (int es = 0; es < 4; ++es) {
            #pragma unroll
            for (int j = 0; j < 4; ++j) {
                int qgl = q0 + (lane >> 4) * 4 + j;
                int e = es * 16 + (lane & 15);
                attnb[((size_t)(bb * T_ + qgl)) * D_ + hh * HS_ + e] = f2bf(oacc[es][j]);
            }
        }
        // trailing s_barrier of the last step protects LDS before next half
    }
}

extern "C" void kernel_launch(void* const* d_in, const int* in_sizes, int n_in,
                              void* d_out, int out_size, void* d_ws, size_t ws_size,
                              hipStream_t stream) {
    const float* x     = (const float*)d_in[0];
    const float* Wq    = (const float*)d_in[1];
    const float* Wk    = (const float*)d_in[2];
    const float* Wv    = (const float*)d_in[3];
    const float* Wproj = (const float*)d_in[4];
    const float* bproj = (const float*)d_in[5];
    const float* W1    = (const float*)d_in[6];
    const float* b1    = (const float*)d_in[7];
    const float* W2    = (const float*)d_in[8];
    const float* b2    = (const float*)d_in[9];
    const float* ln1g  = (const float*)d_in[10];
    const float* ln1b  = (const float*)d_in[11];
    const float* ln2g  = (const float*)d_in[12];
    const float* ln2b  = (const float*)d_in[13];
    float* out = (float*)d_out;

    const size_t MB = 1u << 20;
    char* ws = (char*)d_ws;
    short* xnb   = (short*)(ws + 16 * MB);    // 8MB  (LN1 bf16; also proj residual)
    short* qbh   = (short*)(ws + 24 * MB);    // 8MB  [bh][T][HS] bf16
    short* kbh   = (short*)(ws + 32 * MB);    // 8MB  [bh][T][HS] bf16
    short* vtb   = (short*)(ws + 40 * MB);    // 8MB  [bh][HS][T] bf16 (transposed)
    short* attnb = (short*)(ws + 48 * MB);    // 8MB
    float* x1    = (float*)(ws + 56 * MB);    // 16MB (proj out fp32, LN2 in)
    short* x1nb  = (short*)(ws + 88 * MB);    // 8MB  (LN2 bf16; also FFN2 residual)
    short* hb    = (short*)(ws + 96 * MB);    // 32MB
    short* wqkv  = (short*)(ws + 128 * MB);   // 6MB  [3072][1024]
    short* wprjt = (short*)(ws + 134 * MB);   // 2MB  [1024][1024]
    short* w1t   = (short*)(ws + 136 * MB);   // 8MB  [4096][1024]
    short* w2t   = (short*)(ws + 144 * MB);   // 8MB  [1024][4096]
    float* lpart = (float*)(ws + 152 * MB);   // 1MB  [4][32][2048]
    float* rl    = (float*)(ws + 153 * MB);   // 256KB [32][2048]
    // Split-K partials: CONTIGUOUS 32MB at ws+0 (xnb/qbh at 16-32MB are dead
    // by FFN2 time... xnb needed through proj (step 5) - FFN2 is step 8; qbh
    // dead after pass2). P[0] at +0MB, P[1] at +16MB.
    float* partP = (float*)(ws + 0 * MB);
    float* part0 = (float*)(ws + 0 * MB);
    float* part1 = (float*)(ws + 16 * MB);

    // 0. all weight transposes in ONE kernel (12288 tiles)
    transpose_all<<<dim3(12288), 256, 0, stream>>>(
        Wq, Wk, Wv, Wproj, W1, W2, wqkv, wprjt, w1t, w2t);

    // 1. LN1 -> xnb (bf16 only)
    ln_kernel<<<dim3(BT_), 256, 0, stream>>>(x, ln1g, ln1b, xnb);
    // 2. QKV fused GEMM (128x64, 1536 blocks) -> q,k bf16; v bf16 transposed
    gemm_qkv<<<dim3(48, 32), 256, 0, stream>>>(
        xnb, wqkv, qbh, kbh, vtb, BT_, 3072, 1024);
    // 3. column sums (no max): partials then -log2 (XCD-swizzled, mask-split)
    attn_pass1_mfma<<<dim3(16, 4, 32), 256, 0, stream>>>(qbh, kbh, lpart);
    lreduce<<<dim3(32 * T_ / 256), 256, 0, stream>>>(lpart, rl);
    // 4. attention output (paired halves, counted-vmcnt, XCD swz, mask-split)
    attn_pass2_mfma<<<dim3(16, 32), 256, 0, stream>>>(qbh, kbh, vtb, rl, attnb);
    // 5. proj + bias + bf16 residual(xnb) -> x1 fp32 (128x64, 512 blocks)
    gemm_12864<true, true, false, false><<<dim3(16, 32), 256, 0, stream>>>(
        attnb, wprjt, bproj, xnb, x1, nullptr, BT_, 1024, 1024);
    // 6. LN2 -> x1nb (bf16 only)
    ln_kernel<<<dim3(BT_), 256, 0, stream>>>(x1, ln2g, ln2b, x1nb);
    // 7. FFN1: relu(x1nb @ W1 + b1) -> hb (bf16)  (256x256 coarse-dbuf)
    gemm256_2p<true, true, true><<<dim3(16, 16), 512, 0, stream>>>(
        x1nb, w1t, b1, nullptr, hb, BT_, 4096, 1024);
    // 8. FFN2 split-K=2: contiguous partials at ws+0 / ws+16MB
    gemm128_sk<<<dim3(8, 32, 2), 256, 0, stream>>>(
        hb, w2t, partP, BT_, 1024, 2048, 4096);
    // 9. out = part0 + part1 + b2 + bf16(x1nb)
    addreduce<<<dim3(BT_ * D_ / 4 / 256), 256, 0, stream>>>(
        part0, part1, b2, x1nb, out);
    (void)in_sizes; (void)n_in; (void)out_size; (void)ws_size;
}